// Round 9
// baseline (811.098 us; speedup 1.0000x reference)
//
#include <hip/hip_runtime.h>

#define TPB 256
static inline int nblk(long n) { return (int)((n + TPB - 1) / TPB); }

#define FINF 3.402823466e38f

// ---------------- fused input transposes: verts (B,3,V)->(B,V,3) + d1..d4 w^T ----------------
__global__ __launch_bounds__(TPB) void transpose_all_kernel(const float* __restrict__ vin, float* __restrict__ verts,
                                                            const float* __restrict__ d1, const float* __restrict__ d2,
                                                            const float* __restrict__ d3, const float* __restrict__ d4,
                                                            float* __restrict__ o1, float* __restrict__ o2,
                                                            float* __restrict__ o3, float* __restrict__ o4) {
    int t = blockIdx.x * blockDim.x + threadIdx.x;
    if (t < 32768) { // verts: B=32, V=1024
        int b = t >> 10, i = t & 1023;
        const float* p = vin + (size_t)b * 3072;
        float* o = verts + (size_t)t * 3;
        o[0] = p[i]; o[1] = p[1024 + i]; o[2] = p[2048 + i];
        return;
    }
    int t1 = t - 32768;
    if (t1 < 2048) { int r = t1 / 32, c = t1 % 32; o1[c * 64 + r] = d1[t1]; return; }
    int t2 = t1 - 2048;
    if (t2 < 8192) { int r = t2 / 64, c = t2 % 64; o2[c * 128 + r] = d2[t2]; return; }
    int t3 = t2 - 8192;
    if (t3 < 32768) { int r = t3 / 128, c = t3 % 128; o3[c * 256 + r] = d3[t3]; return; }
    int t4 = t3 - 32768;
    if (t4 < 262144) { int r = t4 / 256, c = t4 % 256; o4[c * 1024 + r] = d4[t4]; }
}

// ---------------- exact K-th smallest via hybrid interpolation/bisection search ----------------
// invariant: cnt(lo) < K <= cnt(hi), cnt(m) = #{ud < m}. Interpolation probes use
// the (value, count) pairs at both brackets; alternating bisection bounds worst case.
template <int NS>
__device__ __forceinline__ unsigned kth_thresh(const unsigned* ud, int K,
                                               unsigned lo, unsigned hi, int chi_seed) {
    int clo = 0, chi = chi_seed, iter = 0;
    while (hi - lo > 1u) {
        unsigned mid;
        if (iter & 1) {
            mid = lo + ((hi - lo) >> 1);
        } else {
            float flo = __uint_as_float(lo), fhi = __uint_as_float(hi);
            float t = (float)(K - clo) / (float)(chi - clo);
            unsigned g = __float_as_uint(flo + (fhi - flo) * t);
            mid = g <= lo ? lo + 1u : (g >= hi ? hi - 1u : g);
        }
        int cnt = 0;
#pragma unroll
        for (int s = 0; s < NS; ++s)
            cnt += __popcll(__ballot(ud[s] < mid));
        if (cnt >= K) { hi = mid; chi = cnt; } else { lo = mid; clo = cnt; }
        ++iter;
    }
    return lo;
}

// ---------------- KNN radix-select, fused epilogues ----------------
// Wave-per-vertex. WDIR: write normalized neighbor dirs. CSURF: also compute
// conv_surface fm0. K2>0: vertices i<V2 additionally emit their K2-NN indices
// (for the pooling stage) from the SAME distance set - no duplicate pass.
template <int K, int NS, bool WDIR, bool CSURF, int K2>
__global__ __launch_bounds__(TPB, 1) void knn_radix_kernel(const float* __restrict__ verts,
                                                           int* __restrict__ knn, float* __restrict__ ndir,
                                                           int V_out, const float* __restrict__ c0dir,
                                                           float* __restrict__ fm0,
                                                           int V2, int* __restrict__ knn4) {
    constexpr int VF = NS * 64;
    __shared__ float4 pts[VF]; // (x, y, z, |p|^2)
    __shared__ int sidx[4][K];
    __shared__ float sdir[4][K][3];
    int b = blockIdx.y;
    const float* vb = verts + (size_t)b * 1024 * 3;
    for (int j = threadIdx.x; j < VF; j += blockDim.x) {
        float x = vb[j * 3], y = vb[j * 3 + 1], z = vb[j * 3 + 2];
        pts[j] = make_float4(x, y, z, x * x + y * y + z * z);
    }
    __syncthreads();
    int lane = threadIdx.x & 63;
    int w = threadIdx.x >> 6;
    int i = blockIdx.x * 4 + w; // 4 waves/block, grid sized exactly
    if (i >= V_out) return;
    float4 pi = pts[i];
    unsigned ud[NS];
    unsigned lmin = 0xFFFFFFFFu;
#pragma unroll
    for (int s = 0; s < NS; ++s) {
        int j = s * 64 + lane;
        float4 pj = pts[j];
        float dist = pi.w + pj.w - 2.f * (pi.x * pj.x + pi.y * pj.y + pi.z * pj.z);
        dist = fmaxf(dist, 0.f); // keep bit-monotone (fp rounding can go < 0)
        unsigned v = (j == i) ? 0xFFFFFFFFu : __float_as_uint(dist);
        ud[s] = v;
        lmin = v < lmin ? v : lmin;
    }
    // pair-min upper bound: 32 disjoint lane-pair mins are all real candidates,
    // so their wave-max M has >=32 candidates <= M (valid hi for K<=32).
    unsigned pmin = lmin;
    {
        unsigned o = (unsigned)__shfl_xor((int)pmin, 1, 64);
        pmin = o < pmin ? o : pmin;
    }
    unsigned gmin = lmin, M = pmin;
#pragma unroll
    for (int off = 32; off > 1; off >>= 1) {
        unsigned on = (unsigned)__shfl_xor((int)gmin, off, 64);
        gmin = on < gmin ? on : gmin;
        unsigned om = (unsigned)__shfl_xor((int)M, off, 64);
        M = om > M ? om : M;
    }
    {
        unsigned on = (unsigned)__shfl_xor((int)gmin, 1, 64);
        gmin = on < gmin ? on : gmin;
    }
    unsigned T = kth_thresh<NS>(ud, K, gmin, M + 1u, 32);
    int* orow = knn + ((size_t)(b * V_out + i)) * K;
    unsigned long long lmask = (1ull << lane) - 1ull;
    int base = 0;
#pragma unroll
    for (int s = 0; s < NS; ++s) {
        unsigned long long m = __ballot(ud[s] < T);
        if (ud[s] < T) {
            int p = base + __popcll(m & lmask);
            sidx[w][p] = s * 64 + lane;
            orow[p] = s * 64 + lane;
        }
        base += __popcll(m);
    }
    int need = K - base; // >= 1 ties at T fill the rest, lowest index first
    int run = 0;
#pragma unroll
    for (int s = 0; s < NS; ++s) {
        unsigned long long m = __ballot(ud[s] == T);
        int r = run + __popcll(m & lmask);
        if (ud[s] == T && r < need) {
            sidx[w][base + r] = s * 64 + lane;
            orow[base + r] = s * 64 + lane;
        }
        run += __popcll(m);
    }
    // --- epilogues: wave-synchronous LDS reads (same wave wrote sidx[w]) ---
    if (WDIR) {
        if (lane < K) {
            int j = sidx[w][lane];
            float4 pj = pts[j];
            float dx = pj.x - pi.x, dy = pj.y - pi.y, dz = pj.z - pi.z;
            float inv = 1.f / fmaxf(sqrtf(dx * dx + dy * dy + dz * dz), 1e-12f);
            float* o = ndir + ((size_t)(b * V_out + i) * K + lane) * 3;
            float nx = dx * inv, ny = dy * inv, nz = dz * inv;
            o[0] = nx; o[1] = ny; o[2] = nz;
            if (CSURF) { sdir[w][lane][0] = nx; sdir[w][lane][1] = ny; sdir[w][lane][2] = nz; }
        }
        if (CSURF && lane < 32) {
            int c = lane;
            float d0 = c0dir[c], d1 = c0dir[32 + c], d2 = c0dir[64 + c];
            float inv = 1.f / fmaxf(sqrtf(d0 * d0 + d1 * d1 + d2 * d2), 1e-12f);
            d0 *= inv; d1 *= inv; d2 *= inv;
            float m = 0.f;
            for (int n = 0; n < K; ++n) {
                float th = sdir[w][n][0] * d0 + sdir[w][n][1] * d1 + sdir[w][n][2] * d2;
                m = fmaxf(m, th);
            }
            fm0[(size_t)(b * V_out + i) * 32 + c] = m; // relu(max) == max of relus
        }
    }
    if (K2 > 0 && i < V2) {
        // K2-NN from the same candidate set: search bounded by T (K2 <= K)
        unsigned T4 = kth_thresh<NS>(ud, K2, gmin, T + 1u, K);
        int* o4 = knn4 + ((size_t)(b * V2 + i)) * K2;
        int b4 = 0;
#pragma unroll
        for (int s = 0; s < NS; ++s) {
            unsigned long long m = __ballot(ud[s] < T4);
            if (ud[s] < T4) o4[b4 + __popcll(m & lmask)] = s * 64 + lane;
            b4 += __popcll(m);
        }
        int need4 = K2 - b4;
        int run4 = 0;
#pragma unroll
        for (int s = 0; s < NS; ++s) {
            unsigned long long m = __ballot(ud[s] == T4);
            int r = run4 + __popcll(m & lmask);
            if (ud[s] == T4 && r < need4) o4[b4 + r] = s * 64 + lane;
            run4 += __popcll(m);
        }
    }
}

// ---------------- LDS-tiled GEMM 64x64, BK=32 ----------------
// MODE 0: out = A@W + bias.  MODE 1: out = bnrelu(conv) + A@W, with BN stats
// finalized in-kernel from the partial buffer (mean/rsqrt per column slice).
template <int MODE>
__global__ __launch_bounds__(TPB) void gemm64_kernel(const float* __restrict__ A, const float* __restrict__ W,
                                                     const float* __restrict__ bias,
                                                     const float* __restrict__ conv, const float* __restrict__ partial,
                                                     float* __restrict__ out, int M, int N, int K, int nsplit) {
    __shared__ float As[64][36]; // padded rows (144 B, 16B-aligned)
    __shared__ float Bs[32][68]; // padded rows (272 B, 16B-aligned)
    __shared__ float smean[64], sinv[64];
    int t = threadIdx.x;
    int tx = t & 15, ty = t >> 4;
    int colbase = blockIdx.x * 64, rowbase = blockIdx.y * 64;
    int r0 = ty * 4, c0 = tx * 4;
    if (MODE == 1 && t < 64) {
        int c = colbase + t;
        double s = 0.0, ss = 0.0;
        for (int sp = 0; sp < nsplit; ++sp) {
            s += partial[(size_t)sp * 2 * N + c];
            ss += partial[(size_t)sp * 2 * N + N + c];
        }
        double mean = s / M;
        double var = ss / M - mean * mean;
        if (var < 0) var = 0;
        smean[t] = (float)mean;
        sinv[t] = rsqrtf((float)var + 1e-5f);
    }
    float4 acc0, acc1, acc2, acc3;
    if (MODE == 0) {
        float4 bv = *(const float4*)(bias + colbase + c0);
        acc0 = bv; acc1 = bv; acc2 = bv; acc3 = bv;
    } else {
        acc0 = make_float4(0.f, 0.f, 0.f, 0.f); acc1 = acc0; acc2 = acc0; acc3 = acc0;
    }
    for (int kt = 0; kt < K; kt += 32) {
#pragma unroll
        for (int l = 0; l < 2; ++l) {
            int lin = t + l * 256;
            int ar = lin >> 3, ak = (lin & 7) << 2;
            *(float4*)&As[ar][ak] = *(const float4*)(A + (size_t)(rowbase + ar) * K + kt + ak);
            int br = lin >> 4, bn = (lin & 15) << 2;
            *(float4*)&Bs[br][bn] = *(const float4*)(W + (size_t)(kt + br) * N + colbase + bn);
        }
        __syncthreads();
#pragma unroll 4
        for (int k = 0; k < 32; ++k) {
            float4 bv = *(const float4*)&Bs[k][c0];
            float a0 = As[r0][k], a1 = As[r0 + 1][k], a2 = As[r0 + 2][k], a3 = As[r0 + 3][k];
            acc0.x += a0 * bv.x; acc0.y += a0 * bv.y; acc0.z += a0 * bv.z; acc0.w += a0 * bv.w;
            acc1.x += a1 * bv.x; acc1.y += a1 * bv.y; acc1.z += a1 * bv.z; acc1.w += a1 * bv.w;
            acc2.x += a2 * bv.x; acc2.y += a2 * bv.y; acc2.z += a2 * bv.z; acc2.w += a2 * bv.w;
            acc3.x += a3 * bv.x; acc3.y += a3 * bv.y; acc3.z += a3 * bv.z; acc3.w += a3 * bv.w;
        }
        __syncthreads();
    }
    float4 accs[4] = {acc0, acc1, acc2, acc3};
    if (MODE == 1) {
        float4 mean = *(const float4*)&smean[c0];
        float4 inv = *(const float4*)&sinv[c0];
#pragma unroll
        for (int rr = 0; rr < 4; ++rr) {
            float4 cv = *(const float4*)(conv + (size_t)(rowbase + r0 + rr) * N + colbase + c0);
            accs[rr].x += fmaxf((cv.x - mean.x) * inv.x, 0.f);
            accs[rr].y += fmaxf((cv.y - mean.y) * inv.y, 0.f);
            accs[rr].z += fmaxf((cv.z - mean.z) * inv.z, 0.f);
            accs[rr].w += fmaxf((cv.w - mean.w) * inv.w, 0.f);
        }
    }
#pragma unroll
    for (int rr = 0; rr < 4; ++rr)
        *(float4*)(out + (size_t)(rowbase + r0 + rr) * N + colbase + c0) = accs[rr];
}

// ---------------- conv_layer: center + max_n(theta * support) ----------------
__global__ __launch_bounds__(TPB) void conv_act_kernel(const float* __restrict__ ndir, const int* __restrict__ knn,
                                const float* __restrict__ fout, const float* __restrict__ dir,
                                float* __restrict__ out, int B, int Vst, int K, int Cout) {
    int t = blockIdx.x * blockDim.x + threadIdx.x;
    if (t >= B * Vst * Cout) return;
    int row = t / Cout, c = t % Cout;
    int b = row / Vst;
    float d0 = dir[c], d1 = dir[Cout + c], d2 = dir[2 * Cout + c];
    float inv = 1.f / fmaxf(sqrtf(d0 * d0 + d1 * d1 + d2 * d2), 1e-12f);
    d0 *= inv; d1 *= inv; d2 *= inv;
    int Cw = 2 * Cout;
    float m = -FINF;
    const float* nd = ndir + (size_t)row * K * 3;
    const int* kr = knn + (size_t)row * K;
    for (int n = 0; n < K; ++n) {
        int j = kr[n];
        float th = fmaxf(nd[n * 3] * d0 + nd[n * 3 + 1] * d1 + nd[n * 3 + 2] * d2, 0.f);
        float s = fout[((size_t)(b * Vst + j)) * Cw + Cout + c];
        m = fmaxf(m, th * s);
    }
    out[t] = fout[(size_t)row * Cw + c] + m;
}

// ---------------- BN stats pass 1: coalesced float partials ----------------
__global__ __launch_bounds__(TPB) void bn_partial_kernel(const float* __restrict__ x, float* __restrict__ partial,
                                                         int rows, int C, int nsplit) {
    int t = blockIdx.x * blockDim.x + threadIdx.x;
    if (t >= C * nsplit) return;
    int c = t % C, sp = t / C;
    int chunk = rows / nsplit;
    int r0 = sp * chunk;
    float s = 0.f, ss = 0.f;
    for (int r = r0; r < r0 + chunk; ++r) {
        float v = x[(size_t)r * C + c];
        s += v; ss += v * v;
    }
    partial[(size_t)sp * 2 * C + c] = s;
    partial[(size_t)sp * 2 * C + C + c] = ss;
}

// ---------------- pool: max over 4 NN features ----------------
__global__ __launch_bounds__(TPB) void pool_max_kernel(const float* __restrict__ fm, const int* __restrict__ knn4,
                                float* __restrict__ out, int B, int Vin, int pn, int C) {
    int t = blockIdx.x * blockDim.x + threadIdx.x;
    if (t >= B * pn * C) return;
    int row = t / C, c = t % C;
    int b = row / pn;
    const int* kr = knn4 + (size_t)row * 4;
    float m = fmaxf(fmaxf(fm[((size_t)(b * Vin + kr[0])) * C + c], fm[((size_t)(b * Vin + kr[1])) * C + c]),
                    fmaxf(fm[((size_t)(b * Vin + kr[2])) * C + c], fm[((size_t)(b * Vin + kr[3])) * C + c]));
    out[t] = m;
}

// ---------------- g = max over vertices ----------------
__global__ __launch_bounds__(TPB) void rowmax_kernel(const float* __restrict__ fm, float* __restrict__ g,
                              int B, int V, int C) {
    int t = blockIdx.x * blockDim.x + threadIdx.x;
    if (t >= B * C) return;
    int b = t / C, c = t % C;
    float m = -FINF;
    for (int i = 0; i < V; ++i) m = fmaxf(m, fm[((size_t)(b * V + i)) * C + c]);
    g[t] = m;
}

// ---------------- wave-per-output: out[r,c] = in[r,:]@w[c,:] + bias[c] ----------------
__global__ __launch_bounds__(TPB, 1) void gemm_t_wave_kernel(const float* __restrict__ in, const float* __restrict__ w,
                                   const float* __restrict__ bias, float* __restrict__ out,
                                   int rows, int Cin, int Cout) {
    int wid = (blockIdx.x * blockDim.x + threadIdx.x) >> 6;
    int lane = threadIdx.x & 63;
    if (wid >= rows * Cout) return;
    int r = wid / Cout, c = wid % Cout;
    const float4* a = (const float4*)(in + (size_t)r * Cin);
    const float4* wr = (const float4*)(w + (size_t)c * Cin);
    int n4 = Cin >> 2;
    float acc = 0.f;
    for (int k = lane; k < n4; k += 64) {
        float4 av = a[k], wv = wr[k];
        acc += av.x * wv.x + av.y * wv.y + av.z * wv.z + av.w * wv.w;
    }
#pragma unroll
    for (int off = 32; off > 0; off >>= 1) acc += __shfl_xor(acc, off, 64);
    if (lane == 0) out[wid] = acc + bias[c];
}

// ---------------- classifier BN stats over batch (32) ----------------
__global__ __launch_bounds__(TPB) void cls_bn_stats_kernel(const float* __restrict__ h, float* __restrict__ stats) {
    int c = blockIdx.x * blockDim.x + threadIdx.x;
    if (c >= 256) return;
    float s = 0.f, ss = 0.f;
    for (int b = 0; b < 32; ++b) {
        float v = h[(size_t)b * 256 + c];
        s += v; ss += v * v;
    }
    float m = s / 32.f;
    float var = ss / 32.f - m * m;
    if (var < 0.f) var = 0.f;
    stats[c] = m;
    stats[256 + c] = rsqrtf(var + 1e-5f);
}

// ---------------- final: wave-per-output relu(bn(h)*g+beta) @ w2^T + b2 ----------------
__global__ __launch_bounds__(TPB, 1) void cls_final_wave_kernel(const float* __restrict__ h, const float* __restrict__ stats,
                                 const float* __restrict__ gam, const float* __restrict__ beta,
                                 const float* __restrict__ w2, const float* __restrict__ b2,
                                 float* __restrict__ out) {
    int wid = (blockIdx.x * blockDim.x + threadIdx.x) >> 6;
    int lane = threadIdx.x & 63;
    if (wid >= 32 * 40) return;
    int b = wid / 40, o = wid % 40;
    float acc = 0.f;
#pragma unroll
    for (int kk = 0; kk < 4; ++kk) {
        int c = lane + kk * 64;
        float v = fmaxf((h[b * 256 + c] - stats[c]) * stats[256 + c] * gam[c] + beta[c], 0.f);
        acc += v * w2[o * 256 + c];
    }
#pragma unroll
    for (int off = 32; off > 0; off >>= 1) acc += __shfl_xor(acc, off, 64);
    if (lane == 0) out[wid] = acc + b2[o];
}

extern "C" void kernel_launch(void* const* d_in, const int* in_sizes, int n_in,
                              void* d_out, int out_size, void* d_ws, size_t ws_size,
                              hipStream_t stream) {
    const float* vertices = (const float*)d_in[0];
    const float* c0_dir = (const float*)d_in[1];
    const float* c1_w  = (const float*)d_in[2];
    const float* c1_b  = (const float*)d_in[3];
    const float* c1_dir = (const float*)d_in[4];
    const float* d1_w  = (const float*)d_in[5];
    const float* c2_w  = (const float*)d_in[6];
    const float* c2_b  = (const float*)d_in[7];
    const float* c2_dir = (const float*)d_in[8];
    const float* d2_w  = (const float*)d_in[9];
    const float* c3_w  = (const float*)d_in[10];
    const float* c3_b  = (const float*)d_in[11];
    const float* c3_dir = (const float*)d_in[12];
    const float* d3_w  = (const float*)d_in[13];
    const float* c4_w  = (const float*)d_in[14];
    const float* c4_b  = (const float*)d_in[15];
    const float* c4_dir = (const float*)d_in[16];
    const float* d4_w  = (const float*)d_in[17];
    const float* cls_w1 = (const float*)d_in[18];
    const float* cls_b1 = (const float*)d_in[19];
    const float* cls_g  = (const float*)d_in[20];
    const float* cls_beta = (const float*)d_in[21];
    const float* cls_w2 = (const float*)d_in[22];
    const float* cls_b2 = (const float*)d_in[23];

    const int B = 32;
    float* ws = (float*)d_ws;
    size_t off = 0;
    auto alloc = [&](size_t n) { float* p = ws + off; off += n; return p; };
    float* verts = alloc(98304);            // B*1024*3
    int*   knn   = (int*)alloc(655360);     // max B*1024*20
    int*   knn4  = (int*)alloc(32768);      // max B*256*4
    float* ndir  = alloc(1966080);          // max B*1024*20*3
    float* fm0   = alloc(1048576);          // B*1024*32
    float* fm1   = alloc(2097152);          // B*1024*64
    float* fm1p  = alloc(524288);           // B*256*64
    float* fm2   = alloc(1048576);          // B*256*128
    float* fm3   = alloc(2097152);          // B*256*256
    float* fm3p  = alloc(524288);           // B*64*256
    float* fm4   = alloc(2097152);          // B*64*1024
    float* fout  = alloc(4194304);          // max fout sizes
    float* convp = alloc(2097152);          // pre-BN conv out
    float* gbuf  = alloc(32768);            // B*1024
    float* hbuf  = alloc(8192);             // B*256
    float* hstats = alloc(512);
    float* d1t   = alloc(2048);             // 32 x 64
    float* d2t   = alloc(8192);             // 64 x 128
    float* d3t   = alloc(32768);            // 128 x 256
    float* d4t   = alloc(262144);           // 256 x 1024
    float* partial = alloc(65536);          // bn partials, max 2*C*nsplit

    // ---- fused input transposes ----
    transpose_all_kernel<<<nblk(32768 + 2048 + 8192 + 32768 + 262144), TPB, 0, stream>>>(
        vertices, verts, d1_w, d2_w, d3_w, d4_w, d1t, d2t, d3t, d4t);

    // ---- stage 1 (V=1024) ----
    knn_radix_kernel<20, 16, true, true, 4><<<dim3(256, B), TPB, 0, stream>>>(
        verts, knn, ndir, 1024, c0_dir, fm0, 256, knn4);
    gemm64_kernel<0><<<dim3(2, 512), TPB, 0, stream>>>(fm0, c1_w, c1_b, nullptr, nullptr, fout, B * 1024, 128, 32, 0);
    conv_act_kernel<<<nblk((long)B * 1024 * 64), TPB, 0, stream>>>(ndir, knn, fout, c1_dir, convp, B, 1024, 20, 64);
    bn_partial_kernel<<<nblk(64 * 256), TPB, 0, stream>>>(convp, partial, B * 1024, 64, 256);
    gemm64_kernel<1><<<dim3(1, 512), TPB, 0, stream>>>(fm0, d1t, nullptr, convp, partial, fm1, B * 1024, 64, 32, 256);
    // pool 1024 -> 256 (indices precomputed in stage-1 knn)
    pool_max_kernel<<<nblk((long)B * 256 * 64), TPB, 0, stream>>>(fm1, knn4, fm1p, B, 1024, 256, 64);

    // ---- stage 2 (V=256) ----
    knn_radix_kernel<20, 4, true, false, 4><<<dim3(64, B), TPB, 0, stream>>>(
        verts, knn, ndir, 256, nullptr, nullptr, 64, knn4);
    gemm64_kernel<0><<<dim3(4, 128), TPB, 0, stream>>>(fm1p, c2_w, c2_b, nullptr, nullptr, fout, B * 256, 256, 64, 0);
    conv_act_kernel<<<nblk((long)B * 256 * 128), TPB, 0, stream>>>(ndir, knn, fout, c2_dir, convp, B, 256, 20, 128);
    bn_partial_kernel<<<nblk(128 * 128), TPB, 0, stream>>>(convp, partial, B * 256, 128, 128);
    gemm64_kernel<1><<<dim3(2, 128), TPB, 0, stream>>>(fm1p, d2t, nullptr, convp, partial, fm2, B * 256, 128, 64, 128);
    gemm64_kernel<0><<<dim3(8, 128), TPB, 0, stream>>>(fm2, c3_w, c3_b, nullptr, nullptr, fout, B * 256, 512, 128, 0);
    conv_act_kernel<<<nblk((long)B * 256 * 256), TPB, 0, stream>>>(ndir, knn, fout, c3_dir, convp, B, 256, 20, 256);
    bn_partial_kernel<<<nblk(256 * 128), TPB, 0, stream>>>(convp, partial, B * 256, 256, 128);
    gemm64_kernel<1><<<dim3(4, 128), TPB, 0, stream>>>(fm2, d3t, nullptr, convp, partial, fm3, B * 256, 256, 128, 128);
    // pool 256 -> 64 (indices precomputed in stage-2 knn)
    pool_max_kernel<<<nblk((long)B * 64 * 256), TPB, 0, stream>>>(fm3, knn4, fm3p, B, 256, 64, 256);

    // ---- stage 3 (V=64) ----
    knn_radix_kernel<20, 1, true, false, 0><<<dim3(16, B), TPB, 0, stream>>>(
        verts, knn, ndir, 64, nullptr, nullptr, 0, nullptr);
    gemm64_kernel<0><<<dim3(32, 32), TPB, 0, stream>>>(fm3p, c4_w, c4_b, nullptr, nullptr, fout, B * 64, 2048, 256, 0);
    conv_act_kernel<<<nblk((long)B * 64 * 1024), TPB, 0, stream>>>(ndir, knn, fout, c4_dir, convp, B, 64, 20, 1024);
    bn_partial_kernel<<<nblk(1024 * 32), TPB, 0, stream>>>(convp, partial, B * 64, 1024, 32);
    gemm64_kernel<1><<<dim3(16, 32), TPB, 0, stream>>>(fm3p, d4t, nullptr, convp, partial, fm4, B * 64, 1024, 256, 32);

    // ---- classifier ----
    rowmax_kernel<<<nblk((long)B * 1024), TPB, 0, stream>>>(fm4, gbuf, B, 64, 1024);
    gemm_t_wave_kernel<<<nblk((long)32 * 256 * 64), TPB, 0, stream>>>(gbuf, cls_w1, cls_b1, hbuf, 32, 1024, 256);
    cls_bn_stats_kernel<<<1, TPB, 0, stream>>>(hbuf, hstats);
    cls_final_wave_kernel<<<nblk((long)32 * 40 * 64), TPB, 0, stream>>>(hbuf, hstats, cls_g, cls_beta, cls_w2, cls_b2, (float*)d_out);
}

// Round 10
// 662.265 us; speedup vs baseline: 1.2247x; 1.2247x over previous
//
#include <hip/hip_runtime.h>

#define TPB 256
static inline int nblk(long n) { return (int)((n + TPB - 1) / TPB); }

#define FINF 3.402823466e38f

// ---------------- fused input transposes: verts (B,3,V)->(B,V,3) + d1..d4 w^T ----------------
__global__ __launch_bounds__(TPB) void transpose_all_kernel(const float* __restrict__ vin, float* __restrict__ verts,
                                                            const float* __restrict__ d1, const float* __restrict__ d2,
                                                            const float* __restrict__ d3, const float* __restrict__ d4,
                                                            float* __restrict__ o1, float* __restrict__ o2,
                                                            float* __restrict__ o3, float* __restrict__ o4) {
    int t = blockIdx.x * blockDim.x + threadIdx.x;
    if (t < 32768) { // verts: B=32, V=1024
        int b = t >> 10, i = t & 1023;
        const float* p = vin + (size_t)b * 3072;
        float* o = verts + (size_t)t * 3;
        o[0] = p[i]; o[1] = p[1024 + i]; o[2] = p[2048 + i];
        return;
    }
    int t1 = t - 32768;
    if (t1 < 2048) { int r = t1 / 32, c = t1 % 32; o1[c * 64 + r] = d1[t1]; return; }
    int t2 = t1 - 2048;
    if (t2 < 8192) { int r = t2 / 64, c = t2 % 64; o2[c * 128 + r] = d2[t2]; return; }
    int t3 = t2 - 8192;
    if (t3 < 32768) { int r = t3 / 128, c = t3 % 128; o3[c * 256 + r] = d3[t3]; return; }
    int t4 = t3 - 32768;
    if (t4 < 262144) { int r = t4 / 256, c = t4 % 256; o4[c * 1024 + r] = d4[t4]; }
}

// ---------------- KNN radix-select, fused epilogues ----------------
// Wave-per-vertex. Exact K-th smallest via pure bisection on float bit patterns
// (ballot counting; measured best — interpolation probes regressed, r9).
// WDIR: write normalized neighbor dirs. CSURF: also compute conv_surface fm0.
// K2>0: vertices i<V2 also emit their K2-NN indices for pooling, selected by
// exact rank among the K candidates already in sidx (shfl rank, no re-search).
template <int K, int NS, bool WDIR, bool CSURF, int K2>
__global__ __launch_bounds__(TPB, 1) void knn_radix_kernel(const float* __restrict__ verts,
                                                           int* __restrict__ knn, float* __restrict__ ndir,
                                                           int V_out, const float* __restrict__ c0dir,
                                                           float* __restrict__ fm0,
                                                           int V2, int* __restrict__ knn4) {
    constexpr int VF = NS * 64;
    __shared__ float4 pts[VF]; // (x, y, z, |p|^2)
    __shared__ int sidx[4][K];
    __shared__ float sdir[4][K][3];
    int b = blockIdx.y;
    const float* vb = verts + (size_t)b * 1024 * 3;
    for (int j = threadIdx.x; j < VF; j += blockDim.x) {
        float x = vb[j * 3], y = vb[j * 3 + 1], z = vb[j * 3 + 2];
        pts[j] = make_float4(x, y, z, x * x + y * y + z * z);
    }
    __syncthreads();
    int lane = threadIdx.x & 63;
    int w = threadIdx.x >> 6;
    int i = blockIdx.x * 4 + w; // 4 waves/block, grid sized exactly
    if (i >= V_out) return;
    float4 pi = pts[i];
    unsigned ud[NS];
    unsigned lmin = 0xFFFFFFFFu;
#pragma unroll
    for (int s = 0; s < NS; ++s) {
        int j = s * 64 + lane;
        float4 pj = pts[j];
        float dist = pi.w + pj.w - 2.f * (pi.x * pj.x + pi.y * pj.y + pi.z * pj.z);
        dist = fmaxf(dist, 0.f); // keep bit-monotone (fp rounding can go < 0)
        unsigned v = (j == i) ? 0xFFFFFFFFu : __float_as_uint(dist);
        ud[s] = v;
        lmin = v < lmin ? v : lmin;
    }
    // pair-min upper bound: 32 disjoint lane-pair mins are all real candidates,
    // so their wave-max M has >=32 candidates <= M (valid hi for K<=32).
    unsigned pmin = lmin;
    {
        unsigned o = (unsigned)__shfl_xor((int)pmin, 1, 64);
        pmin = o < pmin ? o : pmin;
    }
    unsigned gmin = lmin, M = pmin;
#pragma unroll
    for (int off = 32; off > 1; off >>= 1) {
        unsigned on = (unsigned)__shfl_xor((int)gmin, off, 64);
        gmin = on < gmin ? on : gmin;
        unsigned om = (unsigned)__shfl_xor((int)M, off, 64);
        M = om > M ? om : M;
    }
    {
        unsigned on = (unsigned)__shfl_xor((int)gmin, 1, 64);
        gmin = on < gmin ? on : gmin;
    }
    // invariant: count(lo) < K <= count(hi); count(m) = #{ud < m}
    unsigned lo = gmin, hi = M + 1u;
    while (hi - lo > 1u) {
        unsigned mid = lo + ((hi - lo) >> 1);
        int cnt = 0;
#pragma unroll
        for (int s = 0; s < NS; ++s)
            cnt += __popcll(__ballot(ud[s] < mid));
        if (cnt >= K) hi = mid; else lo = mid;
    }
    unsigned T = lo;
    int* orow = knn + ((size_t)(b * V_out + i)) * K;
    unsigned long long lmask = (1ull << lane) - 1ull;
    int base = 0;
#pragma unroll
    for (int s = 0; s < NS; ++s) {
        unsigned long long m = __ballot(ud[s] < T);
        if (ud[s] < T) {
            int p = base + __popcll(m & lmask);
            sidx[w][p] = s * 64 + lane;
            orow[p] = s * 64 + lane;
        }
        base += __popcll(m);
    }
    int need = K - base; // >= 1 ties at T fill the rest, lowest index first
    int run = 0;
#pragma unroll
    for (int s = 0; s < NS; ++s) {
        unsigned long long m = __ballot(ud[s] == T);
        int r = run + __popcll(m & lmask);
        if (ud[s] == T && r < need) {
            sidx[w][base + r] = s * 64 + lane;
            orow[base + r] = s * 64 + lane;
        }
        run += __popcll(m);
    }
    // --- epilogues: wave-synchronous LDS reads (same wave wrote sidx[w]) ---
    if (WDIR) {
        if (lane < K) {
            int j = sidx[w][lane];
            float4 pj = pts[j];
            float dx = pj.x - pi.x, dy = pj.y - pi.y, dz = pj.z - pi.z;
            float inv = 1.f / fmaxf(sqrtf(dx * dx + dy * dy + dz * dz), 1e-12f);
            float* o = ndir + ((size_t)(b * V_out + i) * K + lane) * 3;
            float nx = dx * inv, ny = dy * inv, nz = dz * inv;
            o[0] = nx; o[1] = ny; o[2] = nz;
            if (CSURF) { sdir[w][lane][0] = nx; sdir[w][lane][1] = ny; sdir[w][lane][2] = nz; }
        }
        if (CSURF && lane < 32) {
            int c = lane;
            float d0 = c0dir[c], d1 = c0dir[32 + c], d2 = c0dir[64 + c];
            float inv = 1.f / fmaxf(sqrtf(d0 * d0 + d1 * d1 + d2 * d2), 1e-12f);
            d0 *= inv; d1 *= inv; d2 *= inv;
            float m = 0.f;
            for (int n = 0; n < K; ++n) {
                float th = sdir[w][n][0] * d0 + sdir[w][n][1] * d1 + sdir[w][n][2] * d2;
                m = fmaxf(m, th);
            }
            fm0[(size_t)(b * V_out + i) * 32 + c] = m; // relu(max) == max of relus
        }
    }
    if (K2 > 0 && i < V2) {
        // 4-NN subset of the 20-NN: exact rank among the K selected candidates
        // via shfl loop, (dist, vertex-index) lexicographic (jax tie-break).
        float dsel = FINF;
        int jsel = 0x7FFFFFFF;
        if (lane < K) {
            jsel = sidx[w][lane];
            float4 pj = pts[jsel];
            dsel = fmaxf(pi.w + pj.w - 2.f * (pi.x * pj.x + pi.y * pj.y + pi.z * pj.z), 0.f);
        }
        int rank = 0;
        for (int m = 0; m < K; ++m) {
            float dm = __shfl(dsel, m, 64);
            int jm = __shfl(jsel, m, 64);
            rank += (dm < dsel || (dm == dsel && jm < jsel)) ? 1 : 0;
        }
        if (lane < K && rank < K2) knn4[((size_t)(b * V2 + i)) * K2 + rank] = jsel;
    }
}

// ---------------- LDS-tiled GEMM 64x64, BK=32 ----------------
// MODE 0: out = A@W + bias.  MODE 1: out = bnrelu(conv) + A@W, with BN stats
// finalized in-kernel from the partial buffer (mean/rsqrt per column slice).
template <int MODE>
__global__ __launch_bounds__(TPB) void gemm64_kernel(const float* __restrict__ A, const float* __restrict__ W,
                                                     const float* __restrict__ bias,
                                                     const float* __restrict__ conv, const float* __restrict__ partial,
                                                     float* __restrict__ out, int M, int N, int K, int nsplit) {
    __shared__ float As[64][36]; // padded rows (144 B, 16B-aligned)
    __shared__ float Bs[32][68]; // padded rows (272 B, 16B-aligned)
    __shared__ float smean[64], sinv[64];
    int t = threadIdx.x;
    int tx = t & 15, ty = t >> 4;
    int colbase = blockIdx.x * 64, rowbase = blockIdx.y * 64;
    int r0 = ty * 4, c0 = tx * 4;
    if (MODE == 1 && t < 64) {
        int c = colbase + t;
        double s = 0.0, ss = 0.0;
        for (int sp = 0; sp < nsplit; ++sp) {
            s += partial[(size_t)sp * 2 * N + c];
            ss += partial[(size_t)sp * 2 * N + N + c];
        }
        double mean = s / M;
        double var = ss / M - mean * mean;
        if (var < 0) var = 0;
        smean[t] = (float)mean;
        sinv[t] = rsqrtf((float)var + 1e-5f);
    }
    float4 acc0, acc1, acc2, acc3;
    if (MODE == 0) {
        float4 bv = *(const float4*)(bias + colbase + c0);
        acc0 = bv; acc1 = bv; acc2 = bv; acc3 = bv;
    } else {
        acc0 = make_float4(0.f, 0.f, 0.f, 0.f); acc1 = acc0; acc2 = acc0; acc3 = acc0;
    }
    for (int kt = 0; kt < K; kt += 32) {
#pragma unroll
        for (int l = 0; l < 2; ++l) {
            int lin = t + l * 256;
            int ar = lin >> 3, ak = (lin & 7) << 2;
            *(float4*)&As[ar][ak] = *(const float4*)(A + (size_t)(rowbase + ar) * K + kt + ak);
            int br = lin >> 4, bn = (lin & 15) << 2;
            *(float4*)&Bs[br][bn] = *(const float4*)(W + (size_t)(kt + br) * N + colbase + bn);
        }
        __syncthreads();
#pragma unroll 4
        for (int k = 0; k < 32; ++k) {
            float4 bv = *(const float4*)&Bs[k][c0];
            float a0 = As[r0][k], a1 = As[r0 + 1][k], a2 = As[r0 + 2][k], a3 = As[r0 + 3][k];
            acc0.x += a0 * bv.x; acc0.y += a0 * bv.y; acc0.z += a0 * bv.z; acc0.w += a0 * bv.w;
            acc1.x += a1 * bv.x; acc1.y += a1 * bv.y; acc1.z += a1 * bv.z; acc1.w += a1 * bv.w;
            acc2.x += a2 * bv.x; acc2.y += a2 * bv.y; acc2.z += a2 * bv.z; acc2.w += a2 * bv.w;
            acc3.x += a3 * bv.x; acc3.y += a3 * bv.y; acc3.z += a3 * bv.z; acc3.w += a3 * bv.w;
        }
        __syncthreads();
    }
    float4 accs[4] = {acc0, acc1, acc2, acc3};
    if (MODE == 1) {
        float4 mean = *(const float4*)&smean[c0];
        float4 inv = *(const float4*)&sinv[c0];
#pragma unroll
        for (int rr = 0; rr < 4; ++rr) {
            float4 cv = *(const float4*)(conv + (size_t)(rowbase + r0 + rr) * N + colbase + c0);
            accs[rr].x += fmaxf((cv.x - mean.x) * inv.x, 0.f);
            accs[rr].y += fmaxf((cv.y - mean.y) * inv.y, 0.f);
            accs[rr].z += fmaxf((cv.z - mean.z) * inv.z, 0.f);
            accs[rr].w += fmaxf((cv.w - mean.w) * inv.w, 0.f);
        }
    }
#pragma unroll
    for (int rr = 0; rr < 4; ++rr)
        *(float4*)(out + (size_t)(rowbase + r0 + rr) * N + colbase + c0) = accs[rr];
}

// ---------------- conv_layer: center + max_n(theta * support) ----------------
__global__ __launch_bounds__(TPB) void conv_act_kernel(const float* __restrict__ ndir, const int* __restrict__ knn,
                                const float* __restrict__ fout, const float* __restrict__ dir,
                                float* __restrict__ out, int B, int Vst, int K, int Cout) {
    int t = blockIdx.x * blockDim.x + threadIdx.x;
    if (t >= B * Vst * Cout) return;
    int row = t / Cout, c = t % Cout;
    int b = row / Vst;
    float d0 = dir[c], d1 = dir[Cout + c], d2 = dir[2 * Cout + c];
    float inv = 1.f / fmaxf(sqrtf(d0 * d0 + d1 * d1 + d2 * d2), 1e-12f);
    d0 *= inv; d1 *= inv; d2 *= inv;
    int Cw = 2 * Cout;
    float m = -FINF;
    const float* nd = ndir + (size_t)row * K * 3;
    const int* kr = knn + (size_t)row * K;
    for (int n = 0; n < K; ++n) {
        int j = kr[n];
        float th = fmaxf(nd[n * 3] * d0 + nd[n * 3 + 1] * d1 + nd[n * 3 + 2] * d2, 0.f);
        float s = fout[((size_t)(b * Vst + j)) * Cw + Cout + c];
        m = fmaxf(m, th * s);
    }
    out[t] = fout[(size_t)row * Cw + c] + m;
}

// ---------------- BN stats pass 1: coalesced float partials ----------------
__global__ __launch_bounds__(TPB) void bn_partial_kernel(const float* __restrict__ x, float* __restrict__ partial,
                                                         int rows, int C, int nsplit) {
    int t = blockIdx.x * blockDim.x + threadIdx.x;
    if (t >= C * nsplit) return;
    int c = t % C, sp = t / C;
    int chunk = rows / nsplit;
    int r0 = sp * chunk;
    float s = 0.f, ss = 0.f;
    for (int r = r0; r < r0 + chunk; ++r) {
        float v = x[(size_t)r * C + c];
        s += v; ss += v * v;
    }
    partial[(size_t)sp * 2 * C + c] = s;
    partial[(size_t)sp * 2 * C + C + c] = ss;
}

// ---------------- pool: max over 4 NN features ----------------
__global__ __launch_bounds__(TPB) void pool_max_kernel(const float* __restrict__ fm, const int* __restrict__ knn4,
                                float* __restrict__ out, int B, int Vin, int pn, int C) {
    int t = blockIdx.x * blockDim.x + threadIdx.x;
    if (t >= B * pn * C) return;
    int row = t / C, c = t % C;
    int b = row / pn;
    const int* kr = knn4 + (size_t)row * 4;
    float m = fmaxf(fmaxf(fm[((size_t)(b * Vin + kr[0])) * C + c], fm[((size_t)(b * Vin + kr[1])) * C + c]),
                    fmaxf(fm[((size_t)(b * Vin + kr[2])) * C + c], fm[((size_t)(b * Vin + kr[3])) * C + c]));
    out[t] = m;
}

// ---------------- g = max over vertices ----------------
__global__ __launch_bounds__(TPB) void rowmax_kernel(const float* __restrict__ fm, float* __restrict__ g,
                              int B, int V, int C) {
    int t = blockIdx.x * blockDim.x + threadIdx.x;
    if (t >= B * C) return;
    int b = t / C, c = t % C;
    float m = -FINF;
    for (int i = 0; i < V; ++i) m = fmaxf(m, fm[((size_t)(b * V + i)) * C + c]);
    g[t] = m;
}

// ---------------- wave-per-output: out[r,c] = in[r,:]@w[c,:] + bias[c] ----------------
__global__ __launch_bounds__(TPB, 1) void gemm_t_wave_kernel(const float* __restrict__ in, const float* __restrict__ w,
                                   const float* __restrict__ bias, float* __restrict__ out,
                                   int rows, int Cin, int Cout) {
    int wid = (blockIdx.x * blockDim.x + threadIdx.x) >> 6;
    int lane = threadIdx.x & 63;
    if (wid >= rows * Cout) return;
    int r = wid / Cout, c = wid % Cout;
    const float4* a = (const float4*)(in + (size_t)r * Cin);
    const float4* wr = (const float4*)(w + (size_t)c * Cin);
    int n4 = Cin >> 2;
    float acc = 0.f;
    for (int k = lane; k < n4; k += 64) {
        float4 av = a[k], wv = wr[k];
        acc += av.x * wv.x + av.y * wv.y + av.z * wv.z + av.w * wv.w;
    }
#pragma unroll
    for (int off = 32; off > 0; off >>= 1) acc += __shfl_xor(acc, off, 64);
    if (lane == 0) out[wid] = acc + bias[c];
}

// ---------------- classifier BN stats over batch (32) ----------------
__global__ __launch_bounds__(TPB) void cls_bn_stats_kernel(const float* __restrict__ h, float* __restrict__ stats) {
    int c = blockIdx.x * blockDim.x + threadIdx.x;
    if (c >= 256) return;
    float s = 0.f, ss = 0.f;
    for (int b = 0; b < 32; ++b) {
        float v = h[(size_t)b * 256 + c];
        s += v; ss += v * v;
    }
    float m = s / 32.f;
    float var = ss / 32.f - m * m;
    if (var < 0.f) var = 0.f;
    stats[c] = m;
    stats[256 + c] = rsqrtf(var + 1e-5f);
}

// ---------------- final: wave-per-output relu(bn(h)*g+beta) @ w2^T + b2 ----------------
__global__ __launch_bounds__(TPB, 1) void cls_final_wave_kernel(const float* __restrict__ h, const float* __restrict__ stats,
                                 const float* __restrict__ gam, const float* __restrict__ beta,
                                 const float* __restrict__ w2, const float* __restrict__ b2,
                                 float* __restrict__ out) {
    int wid = (blockIdx.x * blockDim.x + threadIdx.x) >> 6;
    int lane = threadIdx.x & 63;
    if (wid >= 32 * 40) return;
    int b = wid / 40, o = wid % 40;
    float acc = 0.f;
#pragma unroll
    for (int kk = 0; kk < 4; ++kk) {
        int c = lane + kk * 64;
        float v = fmaxf((h[b * 256 + c] - stats[c]) * stats[256 + c] * gam[c] + beta[c], 0.f);
        acc += v * w2[o * 256 + c];
    }
#pragma unroll
    for (int off = 32; off > 0; off >>= 1) acc += __shfl_xor(acc, off, 64);
    if (lane == 0) out[wid] = acc + b2[o];
}

extern "C" void kernel_launch(void* const* d_in, const int* in_sizes, int n_in,
                              void* d_out, int out_size, void* d_ws, size_t ws_size,
                              hipStream_t stream) {
    const float* vertices = (const float*)d_in[0];
    const float* c0_dir = (const float*)d_in[1];
    const float* c1_w  = (const float*)d_in[2];
    const float* c1_b  = (const float*)d_in[3];
    const float* c1_dir = (const float*)d_in[4];
    const float* d1_w  = (const float*)d_in[5];
    const float* c2_w  = (const float*)d_in[6];
    const float* c2_b  = (const float*)d_in[7];
    const float* c2_dir = (const float*)d_in[8];
    const float* d2_w  = (const float*)d_in[9];
    const float* c3_w  = (const float*)d_in[10];
    const float* c3_b  = (const float*)d_in[11];
    const float* c3_dir = (const float*)d_in[12];
    const float* d3_w  = (const float*)d_in[13];
    const float* c4_w  = (const float*)d_in[14];
    const float* c4_b  = (const float*)d_in[15];
    const float* c4_dir = (const float*)d_in[16];
    const float* d4_w  = (const float*)d_in[17];
    const float* cls_w1 = (const float*)d_in[18];
    const float* cls_b1 = (const float*)d_in[19];
    const float* cls_g  = (const float*)d_in[20];
    const float* cls_beta = (const float*)d_in[21];
    const float* cls_w2 = (const float*)d_in[22];
    const float* cls_b2 = (const float*)d_in[23];

    const int B = 32;
    float* ws = (float*)d_ws;
    size_t off = 0;
    auto alloc = [&](size_t n) { float* p = ws + off; off += n; return p; };
    float* verts = alloc(98304);            // B*1024*3
    int*   knn   = (int*)alloc(655360);     // max B*1024*20
    int*   knn4  = (int*)alloc(32768);      // max B*256*4
    float* ndir  = alloc(1966080);          // max B*1024*20*3
    float* fm0   = alloc(1048576);          // B*1024*32
    float* fm1   = alloc(2097152);          // B*1024*64
    float* fm1p  = alloc(524288);           // B*256*64
    float* fm2   = alloc(1048576);          // B*256*128
    float* fm3   = alloc(2097152);          // B*256*256
    float* fm3p  = alloc(524288);           // B*64*256
    float* fm4   = alloc(2097152);          // B*64*1024
    float* fout  = alloc(4194304);          // max fout sizes
    float* convp = alloc(2097152);          // pre-BN conv out
    float* gbuf  = alloc(32768);            // B*1024
    float* hbuf  = alloc(8192);             // B*256
    float* hstats = alloc(512);
    float* d1t   = alloc(2048);             // 32 x 64
    float* d2t   = alloc(8192);             // 64 x 128
    float* d3t   = alloc(32768);            // 128 x 256
    float* d4t   = alloc(262144);           // 256 x 1024
    float* partial = alloc(65536);          // bn partials, max 2*C*nsplit

    // ---- fused input transposes ----
    transpose_all_kernel<<<nblk(32768 + 2048 + 8192 + 32768 + 262144), TPB, 0, stream>>>(
        vertices, verts, d1_w, d2_w, d3_w, d4_w, d1t, d2t, d3t, d4t);

    // ---- stage 1 (V=1024) ----
    knn_radix_kernel<20, 16, true, true, 4><<<dim3(256, B), TPB, 0, stream>>>(
        verts, knn, ndir, 1024, c0_dir, fm0, 256, knn4);
    gemm64_kernel<0><<<dim3(2, 512), TPB, 0, stream>>>(fm0, c1_w, c1_b, nullptr, nullptr, fout, B * 1024, 128, 32, 0);
    conv_act_kernel<<<nblk((long)B * 1024 * 64), TPB, 0, stream>>>(ndir, knn, fout, c1_dir, convp, B, 1024, 20, 64);
    bn_partial_kernel<<<nblk(64 * 256), TPB, 0, stream>>>(convp, partial, B * 1024, 64, 256);
    gemm64_kernel<1><<<dim3(1, 512), TPB, 0, stream>>>(fm0, d1t, nullptr, convp, partial, fm1, B * 1024, 64, 32, 256);
    // pool 1024 -> 256 (indices precomputed in stage-1 knn)
    pool_max_kernel<<<nblk((long)B * 256 * 64), TPB, 0, stream>>>(fm1, knn4, fm1p, B, 1024, 256, 64);

    // ---- stage 2 (V=256) ----
    knn_radix_kernel<20, 4, true, false, 4><<<dim3(64, B), TPB, 0, stream>>>(
        verts, knn, ndir, 256, nullptr, nullptr, 64, knn4);
    gemm64_kernel<0><<<dim3(4, 128), TPB, 0, stream>>>(fm1p, c2_w, c2_b, nullptr, nullptr, fout, B * 256, 256, 64, 0);
    conv_act_kernel<<<nblk((long)B * 256 * 128), TPB, 0, stream>>>(ndir, knn, fout, c2_dir, convp, B, 256, 20, 128);
    bn_partial_kernel<<<nblk(128 * 128), TPB, 0, stream>>>(convp, partial, B * 256, 128, 128);
    gemm64_kernel<1><<<dim3(2, 128), TPB, 0, stream>>>(fm1p, d2t, nullptr, convp, partial, fm2, B * 256, 128, 64, 128);
    gemm64_kernel<0><<<dim3(8, 128), TPB, 0, stream>>>(fm2, c3_w, c3_b, nullptr, nullptr, fout, B * 256, 512, 128, 0);
    conv_act_kernel<<<nblk((long)B * 256 * 256), TPB, 0, stream>>>(ndir, knn, fout, c3_dir, convp, B, 256, 20, 256);
    bn_partial_kernel<<<nblk(256 * 128), TPB, 0, stream>>>(convp, partial, B * 256, 256, 128);
    gemm64_kernel<1><<<dim3(4, 128), TPB, 0, stream>>>(fm2, d3t, nullptr, convp, partial, fm3, B * 256, 256, 128, 128);
    // pool 256 -> 64 (indices precomputed in stage-2 knn)
    pool_max_kernel<<<nblk((long)B * 64 * 256), TPB, 0, stream>>>(fm3, knn4, fm3p, B, 256, 64, 256);

    // ---- stage 3 (V=64) ----
    knn_radix_kernel<20, 1, true, false, 0><<<dim3(16, B), TPB, 0, stream>>>(
        verts, knn, ndir, 64, nullptr, nullptr, 0, nullptr);
    gemm64_kernel<0><<<dim3(32, 32), TPB, 0, stream>>>(fm3p, c4_w, c4_b, nullptr, nullptr, fout, B * 64, 2048, 256, 0);
    conv_act_kernel<<<nblk((long)B * 64 * 1024), TPB, 0, stream>>>(ndir, knn, fout, c4_dir, convp, B, 64, 20, 1024);
    bn_partial_kernel<<<nblk(1024 * 32), TPB, 0, stream>>>(convp, partial, B * 64, 1024, 32);
    gemm64_kernel<1><<<dim3(16, 32), TPB, 0, stream>>>(fm3p, d4t, nullptr, convp, partial, fm4, B * 64, 1024, 256, 32);

    // ---- classifier ----
    rowmax_kernel<<<nblk((long)B * 1024), TPB, 0, stream>>>(fm4, gbuf, B, 64, 1024);
    gemm_t_wave_kernel<<<nblk((long)32 * 256 * 64), TPB, 0, stream>>>(gbuf, cls_w1, cls_b1, hbuf, 32, 1024, 256);
    cls_bn_stats_kernel<<<1, TPB, 0, stream>>>(hbuf, hstats);
    cls_final_wave_kernel<<<nblk((long)32 * 40 * 64), TPB, 0, stream>>>(hbuf, hstats, cls_g, cls_beta, cls_w2, cls_b2, (float*)d_out);
}

// Round 11
// 516.154 us; speedup vs baseline: 1.5714x; 1.2831x over previous
//
#include <hip/hip_runtime.h>

#define TPB 256
static inline int nblk(long n) { return (int)((n + TPB - 1) / TPB); }

#define FINF 3.402823466e38f

// ---------------- fused input transposes: verts (B,3,V)->(B,V,3) + d1..d4 w^T ----------------
__global__ __launch_bounds__(TPB) void transpose_all_kernel(const float* __restrict__ vin, float* __restrict__ verts,
                                                            const float* __restrict__ d1, const float* __restrict__ d2,
                                                            const float* __restrict__ d3, const float* __restrict__ d4,
                                                            float* __restrict__ o1, float* __restrict__ o2,
                                                            float* __restrict__ o3, float* __restrict__ o4) {
    int t = blockIdx.x * blockDim.x + threadIdx.x;
    if (t < 32768) { // verts: B=32, V=1024
        int b = t >> 10, i = t & 1023;
        const float* p = vin + (size_t)b * 3072;
        float* o = verts + (size_t)t * 3;
        o[0] = p[i]; o[1] = p[1024 + i]; o[2] = p[2048 + i];
        return;
    }
    int t1 = t - 32768;
    if (t1 < 2048) { int r = t1 / 32, c = t1 % 32; o1[c * 64 + r] = d1[t1]; return; }
    int t2 = t1 - 2048;
    if (t2 < 8192) { int r = t2 / 64, c = t2 % 64; o2[c * 128 + r] = d2[t2]; return; }
    int t3 = t2 - 8192;
    if (t3 < 32768) { int r = t3 / 128, c = t3 % 128; o3[c * 256 + r] = d3[t3]; return; }
    int t4 = t3 - 32768;
    if (t4 < 262144) { int r = t4 / 256, c = t4 % 256; o4[c * 1024 + r] = d4[t4]; }
}

// ---------------- KNN radix-select, fused epilogues ----------------
// Wave-per-vertex. Exact K-th smallest via bisection on float bit patterns.
// NS>=8: candidates <= M (group-min bound, ~11% of set) are first ballot-
// compacted into a 256-slot LDS array, so bisection runs over 4 slots not NS
// (4x fewer ballots/iter). Order-preserving => jax lowest-index tie-break kept.
// Overflow (cnt>256, ~0.3%) falls back to the full-width path.
// WDIR: write normalized neighbor dirs. CSURF: also compute conv_surface fm0.
// K2>0: vertices i<V2 also emit K2-NN indices for pooling via shfl rank.
template <int K, int NS, bool WDIR, bool CSURF, int K2>
__global__ __launch_bounds__(TPB, 1) void knn_radix_kernel(const float* __restrict__ verts,
                                                           int* __restrict__ knn, float* __restrict__ ndir,
                                                           int V_out, const float* __restrict__ c0dir,
                                                           float* __restrict__ fm0,
                                                           int V2, int* __restrict__ knn4) {
    constexpr int VF = NS * 64;
    __shared__ float4 pts[VF]; // (x, y, z, |p|^2)
    __shared__ int sidx[4][K];
    __shared__ float sdir[4][K][3];
    int b = blockIdx.y;
    const float* vb = verts + (size_t)b * 1024 * 3;
    for (int j = threadIdx.x; j < VF; j += blockDim.x) {
        float x = vb[j * 3], y = vb[j * 3 + 1], z = vb[j * 3 + 2];
        pts[j] = make_float4(x, y, z, x * x + y * y + z * z);
    }
    __syncthreads();
    int lane = threadIdx.x & 63;
    int w = threadIdx.x >> 6;
    int i = blockIdx.x * 4 + w; // 4 waves/block, grid sized exactly
    if (i >= V_out) return;
    float4 pi = pts[i];
    unsigned ud[NS];
    unsigned lmin = 0xFFFFFFFFu;
#pragma unroll
    for (int s = 0; s < NS; ++s) {
        int j = s * 64 + lane;
        float4 pj = pts[j];
        float dist = pi.w + pj.w - 2.f * (pi.x * pj.x + pi.y * pj.y + pi.z * pj.z);
        dist = fmaxf(dist, 0.f); // keep bit-monotone (fp rounding can go < 0)
        unsigned v = (j == i) ? 0xFFFFFFFFu : __float_as_uint(dist);
        ud[s] = v;
        lmin = v < lmin ? v : lmin;
    }
    // group-min upper bound: 32 disjoint lane-pair groups (2*NS values each);
    // each group-min is a candidate <= M, so count(<=M) >= 32 >= K.
    unsigned pmin = lmin;
    {
        unsigned o = (unsigned)__shfl_xor((int)pmin, 1, 64);
        pmin = o < pmin ? o : pmin;
    }
    unsigned gmin = lmin, M = pmin;
#pragma unroll
    for (int off = 32; off > 1; off >>= 1) {
        unsigned on = (unsigned)__shfl_xor((int)gmin, off, 64);
        gmin = on < gmin ? on : gmin;
        unsigned om = (unsigned)__shfl_xor((int)M, off, 64);
        M = om > M ? om : M;
    }
    {
        unsigned on = (unsigned)__shfl_xor((int)gmin, 1, 64);
        gmin = on < gmin ? on : gmin;
    }
    int* orow = knn + ((size_t)(b * V_out + i)) * K;
    unsigned long long lmask = (1ull << lane) - 1ull;
    bool done = false;
    if constexpr (NS >= 8) {
        __shared__ unsigned cdist[4][256];
        __shared__ unsigned short cidx[4][256];
        int cnt = 0;
#pragma unroll
        for (int s = 0; s < NS; ++s) {
            unsigned long long mm = __ballot(ud[s] <= M);
            if (ud[s] <= M) {
                int p = cnt + __popcll(mm & lmask);
                if (p < 256) { cdist[w][p] = ud[s]; cidx[w][p] = (unsigned short)(s * 64 + lane); }
            }
            cnt += __popcll(mm);
        }
        if (cnt <= 256) { // wave-uniform (cnt from ballots)
            unsigned cd[4];
#pragma unroll
            for (int r = 0; r < 4; ++r) {
                int p = lane + r * 64;
                cd[r] = p < cnt ? cdist[w][p] : 0xFFFFFFFFu;
            }
            unsigned lo = gmin, hi = M + 1u;
            while (hi - lo > 1u) {
                unsigned mid = lo + ((hi - lo) >> 1);
                int c = 0;
#pragma unroll
                for (int r = 0; r < 4; ++r)
                    c += __popcll(__ballot(cd[r] < mid));
                if (c >= K) hi = mid; else lo = mid;
            }
            unsigned T = lo;
            int base = 0;
#pragma unroll
            for (int r = 0; r < 4; ++r) {
                unsigned long long mm = __ballot(cd[r] < T);
                if (cd[r] < T) {
                    int p = base + __popcll(mm & lmask);
                    int j = cidx[w][lane + r * 64];
                    sidx[w][p] = j; orow[p] = j;
                }
                base += __popcll(mm);
            }
            int need = K - base, run = 0;
#pragma unroll
            for (int r = 0; r < 4; ++r) {
                unsigned long long mm = __ballot(cd[r] == T);
                int rr = run + __popcll(mm & lmask);
                if (cd[r] == T && rr < need) {
                    int j = cidx[w][lane + r * 64];
                    sidx[w][base + rr] = j; orow[base + rr] = j;
                }
                run += __popcll(mm);
            }
            done = true;
        }
    }
    if (!done) { // full-width path (NS<8 instances, or rare compaction overflow)
        unsigned lo = gmin, hi = M + 1u;
        while (hi - lo > 1u) {
            unsigned mid = lo + ((hi - lo) >> 1);
            int cnt = 0;
#pragma unroll
            for (int s = 0; s < NS; ++s)
                cnt += __popcll(__ballot(ud[s] < mid));
            if (cnt >= K) hi = mid; else lo = mid;
        }
        unsigned T = lo;
        int base = 0;
#pragma unroll
        for (int s = 0; s < NS; ++s) {
            unsigned long long m = __ballot(ud[s] < T);
            if (ud[s] < T) {
                int p = base + __popcll(m & lmask);
                sidx[w][p] = s * 64 + lane;
                orow[p] = s * 64 + lane;
            }
            base += __popcll(m);
        }
        int need = K - base, run = 0;
#pragma unroll
        for (int s = 0; s < NS; ++s) {
            unsigned long long m = __ballot(ud[s] == T);
            int r = run + __popcll(m & lmask);
            if (ud[s] == T && r < need) {
                sidx[w][base + r] = s * 64 + lane;
                orow[base + r] = s * 64 + lane;
            }
            run += __popcll(m);
        }
    }
    // --- epilogues: wave-synchronous LDS reads (same wave wrote sidx[w]) ---
    if (WDIR) {
        if (lane < K) {
            int j = sidx[w][lane];
            float4 pj = pts[j];
            float dx = pj.x - pi.x, dy = pj.y - pi.y, dz = pj.z - pi.z;
            float inv = 1.f / fmaxf(sqrtf(dx * dx + dy * dy + dz * dz), 1e-12f);
            float* o = ndir + ((size_t)(b * V_out + i) * K + lane) * 3;
            float nx = dx * inv, ny = dy * inv, nz = dz * inv;
            o[0] = nx; o[1] = ny; o[2] = nz;
            if (CSURF) { sdir[w][lane][0] = nx; sdir[w][lane][1] = ny; sdir[w][lane][2] = nz; }
        }
        if (CSURF && lane < 32) {
            int c = lane;
            float d0 = c0dir[c], d1 = c0dir[32 + c], d2 = c0dir[64 + c];
            float inv = 1.f / fmaxf(sqrtf(d0 * d0 + d1 * d1 + d2 * d2), 1e-12f);
            d0 *= inv; d1 *= inv; d2 *= inv;
            float m = 0.f;
            for (int n = 0; n < K; ++n) {
                float th = sdir[w][n][0] * d0 + sdir[w][n][1] * d1 + sdir[w][n][2] * d2;
                m = fmaxf(m, th);
            }
            fm0[(size_t)(b * V_out + i) * 32 + c] = m; // relu(max) == max of relus
        }
    }
    if (K2 > 0 && i < V2) {
        // 4-NN subset of the 20-NN: exact rank among the K selected candidates
        // via shfl loop, (dist, vertex-index) lexicographic (jax tie-break).
        float dsel = FINF;
        int jsel = 0x7FFFFFFF;
        if (lane < K) {
            jsel = sidx[w][lane];
            float4 pj = pts[jsel];
            dsel = fmaxf(pi.w + pj.w - 2.f * (pi.x * pj.x + pi.y * pj.y + pi.z * pj.z), 0.f);
        }
        int rank = 0;
        for (int m = 0; m < K; ++m) {
            float dm = __shfl(dsel, m, 64);
            int jm = __shfl(jsel, m, 64);
            rank += (dm < dsel || (dm == dsel && jm < jsel)) ? 1 : 0;
        }
        if (lane < K && rank < K2) knn4[((size_t)(b * V2 + i)) * K2 + rank] = jsel;
    }
}

// ---------------- LDS-tiled GEMM 64x64, BK=32 ----------------
// MODE 0: out = A@W + bias.  MODE 1: out = bnrelu(conv) + A@W, with BN stats
// finalized in-kernel from the partial buffer (mean/rsqrt per column slice).
template <int MODE>
__global__ __launch_bounds__(TPB) void gemm64_kernel(const float* __restrict__ A, const float* __restrict__ W,
                                                     const float* __restrict__ bias,
                                                     const float* __restrict__ conv, const float* __restrict__ partial,
                                                     float* __restrict__ out, int M, int N, int K, int nsplit) {
    __shared__ float As[64][36]; // padded rows (144 B, 16B-aligned)
    __shared__ float Bs[32][68]; // padded rows (272 B, 16B-aligned)
    __shared__ float smean[64], sinv[64];
    int t = threadIdx.x;
    int tx = t & 15, ty = t >> 4;
    int colbase = blockIdx.x * 64, rowbase = blockIdx.y * 64;
    int r0 = ty * 4, c0 = tx * 4;
    if (MODE == 1 && t < 64) {
        int c = colbase + t;
        double s = 0.0, ss = 0.0;
        for (int sp = 0; sp < nsplit; ++sp) {
            s += partial[(size_t)sp * 2 * N + c];
            ss += partial[(size_t)sp * 2 * N + N + c];
        }
        double mean = s / M;
        double var = ss / M - mean * mean;
        if (var < 0) var = 0;
        smean[t] = (float)mean;
        sinv[t] = rsqrtf((float)var + 1e-5f);
    }
    float4 acc0, acc1, acc2, acc3;
    if (MODE == 0) {
        float4 bv = *(const float4*)(bias + colbase + c0);
        acc0 = bv; acc1 = bv; acc2 = bv; acc3 = bv;
    } else {
        acc0 = make_float4(0.f, 0.f, 0.f, 0.f); acc1 = acc0; acc2 = acc0; acc3 = acc0;
    }
    for (int kt = 0; kt < K; kt += 32) {
#pragma unroll
        for (int l = 0; l < 2; ++l) {
            int lin = t + l * 256;
            int ar = lin >> 3, ak = (lin & 7) << 2;
            *(float4*)&As[ar][ak] = *(const float4*)(A + (size_t)(rowbase + ar) * K + kt + ak);
            int br = lin >> 4, bn = (lin & 15) << 2;
            *(float4*)&Bs[br][bn] = *(const float4*)(W + (size_t)(kt + br) * N + colbase + bn);
        }
        __syncthreads();
#pragma unroll 4
        for (int k = 0; k < 32; ++k) {
            float4 bv = *(const float4*)&Bs[k][c0];
            float a0 = As[r0][k], a1 = As[r0 + 1][k], a2 = As[r0 + 2][k], a3 = As[r0 + 3][k];
            acc0.x += a0 * bv.x; acc0.y += a0 * bv.y; acc0.z += a0 * bv.z; acc0.w += a0 * bv.w;
            acc1.x += a1 * bv.x; acc1.y += a1 * bv.y; acc1.z += a1 * bv.z; acc1.w += a1 * bv.w;
            acc2.x += a2 * bv.x; acc2.y += a2 * bv.y; acc2.z += a2 * bv.z; acc2.w += a2 * bv.w;
            acc3.x += a3 * bv.x; acc3.y += a3 * bv.y; acc3.z += a3 * bv.z; acc3.w += a3 * bv.w;
        }
        __syncthreads();
    }
    float4 accs[4] = {acc0, acc1, acc2, acc3};
    if (MODE == 1) {
        float4 mean = *(const float4*)&smean[c0];
        float4 inv = *(const float4*)&sinv[c0];
#pragma unroll
        for (int rr = 0; rr < 4; ++rr) {
            float4 cv = *(const float4*)(conv + (size_t)(rowbase + r0 + rr) * N + colbase + c0);
            accs[rr].x += fmaxf((cv.x - mean.x) * inv.x, 0.f);
            accs[rr].y += fmaxf((cv.y - mean.y) * inv.y, 0.f);
            accs[rr].z += fmaxf((cv.z - mean.z) * inv.z, 0.f);
            accs[rr].w += fmaxf((cv.w - mean.w) * inv.w, 0.f);
        }
    }
#pragma unroll
    for (int rr = 0; rr < 4; ++rr)
        *(float4*)(out + (size_t)(rowbase + r0 + rr) * N + colbase + c0) = accs[rr];
}

// ---------------- conv_layer: center + max_n(theta * support), 4 ch/thread ----------------
__global__ __launch_bounds__(TPB) void conv_act_kernel(const float* __restrict__ ndir, const int* __restrict__ knn,
                                const float* __restrict__ fout, const float* __restrict__ dir,
                                float* __restrict__ out, int B, int Vst, int K, int Cout) {
    int t = blockIdx.x * blockDim.x + threadIdx.x;
    int nc4 = Cout >> 2;
    if (t >= B * Vst * nc4) return;
    int row = t / nc4, c4 = (t % nc4) * 4;
    int b = row / Vst;
    float4 D0 = *(const float4*)(dir + c4);
    float4 D1 = *(const float4*)(dir + Cout + c4);
    float4 D2 = *(const float4*)(dir + 2 * Cout + c4);
    float4 e0, e1, e2;
    {
        float i0 = 1.f / fmaxf(sqrtf(D0.x * D0.x + D1.x * D1.x + D2.x * D2.x), 1e-12f);
        float i1 = 1.f / fmaxf(sqrtf(D0.y * D0.y + D1.y * D1.y + D2.y * D2.y), 1e-12f);
        float i2 = 1.f / fmaxf(sqrtf(D0.z * D0.z + D1.z * D1.z + D2.z * D2.z), 1e-12f);
        float i3 = 1.f / fmaxf(sqrtf(D0.w * D0.w + D1.w * D1.w + D2.w * D2.w), 1e-12f);
        e0 = make_float4(D0.x * i0, D0.y * i1, D0.z * i2, D0.w * i3);
        e1 = make_float4(D1.x * i0, D1.y * i1, D1.z * i2, D1.w * i3);
        e2 = make_float4(D2.x * i0, D2.y * i1, D2.z * i2, D2.w * i3);
    }
    int Cw = 2 * Cout;
    float4 m = make_float4(-FINF, -FINF, -FINF, -FINF);
    const float* nd = ndir + (size_t)row * K * 3;
    const int* kr = knn + (size_t)row * K;
    for (int n = 0; n < K; ++n) {
        int j = kr[n];
        float n0 = nd[n * 3], n1 = nd[n * 3 + 1], n2 = nd[n * 3 + 2];
        float4 s = *(const float4*)(fout + ((size_t)(b * Vst + j)) * Cw + Cout + c4);
        float t0 = fmaxf(n0 * e0.x + n1 * e1.x + n2 * e2.x, 0.f);
        float t1 = fmaxf(n0 * e0.y + n1 * e1.y + n2 * e2.y, 0.f);
        float t2 = fmaxf(n0 * e0.z + n1 * e1.z + n2 * e2.z, 0.f);
        float t3 = fmaxf(n0 * e0.w + n1 * e1.w + n2 * e2.w, 0.f);
        m.x = fmaxf(m.x, t0 * s.x);
        m.y = fmaxf(m.y, t1 * s.y);
        m.z = fmaxf(m.z, t2 * s.z);
        m.w = fmaxf(m.w, t3 * s.w);
    }
    float4 ctr = *(const float4*)(fout + (size_t)row * Cw + c4);
    *(float4*)(out + (size_t)row * Cout + c4) = make_float4(ctr.x + m.x, ctr.y + m.y, ctr.z + m.z, ctr.w + m.w);
}

// ---------------- BN stats pass 1: coalesced float partials ----------------
__global__ __launch_bounds__(TPB) void bn_partial_kernel(const float* __restrict__ x, float* __restrict__ partial,
                                                         int rows, int C, int nsplit) {
    int t = blockIdx.x * blockDim.x + threadIdx.x;
    if (t >= C * nsplit) return;
    int c = t % C, sp = t / C;
    int chunk = rows / nsplit;
    int r0 = sp * chunk;
    float s = 0.f, ss = 0.f;
    for (int r = r0; r < r0 + chunk; ++r) {
        float v = x[(size_t)r * C + c];
        s += v; ss += v * v;
    }
    partial[(size_t)sp * 2 * C + c] = s;
    partial[(size_t)sp * 2 * C + C + c] = ss;
}

// ---------------- pool: max over 4 NN features ----------------
__global__ __launch_bounds__(TPB) void pool_max_kernel(const float* __restrict__ fm, const int* __restrict__ knn4,
                                float* __restrict__ out, int B, int Vin, int pn, int C) {
    int t = blockIdx.x * blockDim.x + threadIdx.x;
    if (t >= B * pn * C) return;
    int row = t / C, c = t % C;
    int b = row / pn;
    const int* kr = knn4 + (size_t)row * 4;
    float m = fmaxf(fmaxf(fm[((size_t)(b * Vin + kr[0])) * C + c], fm[((size_t)(b * Vin + kr[1])) * C + c]),
                    fmaxf(fm[((size_t)(b * Vin + kr[2])) * C + c], fm[((size_t)(b * Vin + kr[3])) * C + c]));
    out[t] = m;
}

// ---------------- g = max over vertices ----------------
__global__ __launch_bounds__(TPB) void rowmax_kernel(const float* __restrict__ fm, float* __restrict__ g,
                              int B, int V, int C) {
    int t = blockIdx.x * blockDim.x + threadIdx.x;
    if (t >= B * C) return;
    int b = t / C, c = t % C;
    float m = -FINF;
    for (int i = 0; i < V; ++i) m = fmaxf(m, fm[((size_t)(b * V + i)) * C + c]);
    g[t] = m;
}

// ---------------- wave-per-output: out[r,c] = in[r,:]@w[c,:] + bias[c] ----------------
__global__ __launch_bounds__(TPB, 1) void gemm_t_wave_kernel(const float* __restrict__ in, const float* __restrict__ w,
                                   const float* __restrict__ bias, float* __restrict__ out,
                                   int rows, int Cin, int Cout) {
    int wid = (blockIdx.x * blockDim.x + threadIdx.x) >> 6;
    int lane = threadIdx.x & 63;
    if (wid >= rows * Cout) return;
    int r = wid / Cout, c = wid % Cout;
    const float4* a = (const float4*)(in + (size_t)r * Cin);
    const float4* wr = (const float4*)(w + (size_t)c * Cin);
    int n4 = Cin >> 2;
    float acc = 0.f;
    for (int k = lane; k < n4; k += 64) {
        float4 av = a[k], wv = wr[k];
        acc += av.x * wv.x + av.y * wv.y + av.z * wv.z + av.w * wv.w;
    }
#pragma unroll
    for (int off = 32; off > 0; off >>= 1) acc += __shfl_xor(acc, off, 64);
    if (lane == 0) out[wid] = acc + bias[c];
}

// ---------------- fused classifier tail: BN stats (per-block) + relu(bn(h))@w2^T + b2 ----------------
__global__ __launch_bounds__(TPB, 1) void cls_fused_kernel(const float* __restrict__ h,
                                 const float* __restrict__ gam, const float* __restrict__ beta,
                                 const float* __restrict__ w2, const float* __restrict__ b2,
                                 float* __restrict__ out) {
    __shared__ float smean[256], sa[256];
    int t = threadIdx.x;
    {
        float s = 0.f, ss = 0.f;
        for (int b = 0; b < 32; ++b) {
            float v = h[(size_t)b * 256 + t];
            s += v; ss += v * v;
        }
        float mn = s / 32.f;
        float var = ss / 32.f - mn * mn;
        if (var < 0.f) var = 0.f;
        smean[t] = mn;
        sa[t] = rsqrtf(var + 1e-5f) * gam[t]; // fold gamma
    }
    __syncthreads();
    int wid = blockIdx.x * 4 + (t >> 6);
    int lane = t & 63;
    if (wid >= 32 * 40) return;
    int b = wid / 40, o = wid % 40;
    float acc = 0.f;
#pragma unroll
    for (int kk = 0; kk < 4; ++kk) {
        int c = lane + kk * 64;
        float v = fmaxf((h[b * 256 + c] - smean[c]) * sa[c] + beta[c], 0.f);
        acc += v * w2[o * 256 + c];
    }
#pragma unroll
    for (int off = 32; off > 0; off >>= 1) acc += __shfl_xor(acc, off, 64);
    if (lane == 0) out[wid] = acc + b2[o];
}

extern "C" void kernel_launch(void* const* d_in, const int* in_sizes, int n_in,
                              void* d_out, int out_size, void* d_ws, size_t ws_size,
                              hipStream_t stream) {
    const float* vertices = (const float*)d_in[0];
    const float* c0_dir = (const float*)d_in[1];
    const float* c1_w  = (const float*)d_in[2];
    const float* c1_b  = (const float*)d_in[3];
    const float* c1_dir = (const float*)d_in[4];
    const float* d1_w  = (const float*)d_in[5];
    const float* c2_w  = (const float*)d_in[6];
    const float* c2_b  = (const float*)d_in[7];
    const float* c2_dir = (const float*)d_in[8];
    const float* d2_w  = (const float*)d_in[9];
    const float* c3_w  = (const float*)d_in[10];
    const float* c3_b  = (const float*)d_in[11];
    const float* c3_dir = (const float*)d_in[12];
    const float* d3_w  = (const float*)d_in[13];
    const float* c4_w  = (const float*)d_in[14];
    const float* c4_b  = (const float*)d_in[15];
    const float* c4_dir = (const float*)d_in[16];
    const float* d4_w  = (const float*)d_in[17];
    const float* cls_w1 = (const float*)d_in[18];
    const float* cls_b1 = (const float*)d_in[19];
    const float* cls_g  = (const float*)d_in[20];
    const float* cls_beta = (const float*)d_in[21];
    const float* cls_w2 = (const float*)d_in[22];
    const float* cls_b2 = (const float*)d_in[23];

    const int B = 32;
    float* ws = (float*)d_ws;
    size_t off = 0;
    auto alloc = [&](size_t n) { float* p = ws + off; off += n; return p; };
    float* verts = alloc(98304);            // B*1024*3
    int*   knn   = (int*)alloc(655360);     // max B*1024*20
    int*   knn4  = (int*)alloc(32768);      // max B*256*4
    float* ndir  = alloc(1966080);          // max B*1024*20*3
    float* fm0   = alloc(1048576);          // B*1024*32
    float* fm1   = alloc(2097152);          // B*1024*64
    float* fm1p  = alloc(524288);           // B*256*64
    float* fm2   = alloc(1048576);          // B*256*128
    float* fm3   = alloc(2097152);          // B*256*256
    float* fm3p  = alloc(524288);           // B*64*256
    float* fm4   = alloc(2097152);          // B*64*1024
    float* fout  = alloc(4194304);          // max fout sizes
    float* convp = alloc(2097152);          // pre-BN conv out
    float* gbuf  = alloc(32768);            // B*1024
    float* hbuf  = alloc(8192);             // B*256
    float* d1t   = alloc(2048);             // 32 x 64
    float* d2t   = alloc(8192);             // 64 x 128
    float* d3t   = alloc(32768);            // 128 x 256
    float* d4t   = alloc(262144);           // 256 x 1024
    float* partial = alloc(65536);          // bn partials, max 2*C*nsplit

    // ---- fused input transposes ----
    transpose_all_kernel<<<nblk(32768 + 2048 + 8192 + 32768 + 262144), TPB, 0, stream>>>(
        vertices, verts, d1_w, d2_w, d3_w, d4_w, d1t, d2t, d3t, d4t);

    // ---- stage 1 (V=1024) ----
    knn_radix_kernel<20, 16, true, true, 4><<<dim3(256, B), TPB, 0, stream>>>(
        verts, knn, ndir, 1024, c0_dir, fm0, 256, knn4);
    gemm64_kernel<0><<<dim3(2, 512), TPB, 0, stream>>>(fm0, c1_w, c1_b, nullptr, nullptr, fout, B * 1024, 128, 32, 0);
    conv_act_kernel<<<nblk((long)B * 1024 * 16), TPB, 0, stream>>>(ndir, knn, fout, c1_dir, convp, B, 1024, 20, 64);
    bn_partial_kernel<<<nblk(64 * 256), TPB, 0, stream>>>(convp, partial, B * 1024, 64, 256);
    gemm64_kernel<1><<<dim3(1, 512), TPB, 0, stream>>>(fm0, d1t, nullptr, convp, partial, fm1, B * 1024, 64, 32, 256);
    // pool 1024 -> 256 (indices precomputed in stage-1 knn)
    pool_max_kernel<<<nblk((long)B * 256 * 64), TPB, 0, stream>>>(fm1, knn4, fm1p, B, 1024, 256, 64);

    // ---- stage 2 (V=256) ----
    knn_radix_kernel<20, 4, true, false, 4><<<dim3(64, B), TPB, 0, stream>>>(
        verts, knn, ndir, 256, nullptr, nullptr, 64, knn4);
    gemm64_kernel<0><<<dim3(4, 128), TPB, 0, stream>>>(fm1p, c2_w, c2_b, nullptr, nullptr, fout, B * 256, 256, 64, 0);
    conv_act_kernel<<<nblk((long)B * 256 * 32), TPB, 0, stream>>>(ndir, knn, fout, c2_dir, convp, B, 256, 20, 128);
    bn_partial_kernel<<<nblk(128 * 128), TPB, 0, stream>>>(convp, partial, B * 256, 128, 128);
    gemm64_kernel<1><<<dim3(2, 128), TPB, 0, stream>>>(fm1p, d2t, nullptr, convp, partial, fm2, B * 256, 128, 64, 128);
    gemm64_kernel<0><<<dim3(8, 128), TPB, 0, stream>>>(fm2, c3_w, c3_b, nullptr, nullptr, fout, B * 256, 512, 128, 0);
    conv_act_kernel<<<nblk((long)B * 256 * 64), TPB, 0, stream>>>(ndir, knn, fout, c3_dir, convp, B, 256, 20, 256);
    bn_partial_kernel<<<nblk(256 * 128), TPB, 0, stream>>>(convp, partial, B * 256, 256, 128);
    gemm64_kernel<1><<<dim3(4, 128), TPB, 0, stream>>>(fm2, d3t, nullptr, convp, partial, fm3, B * 256, 256, 128, 128);
    // pool 256 -> 64 (indices precomputed in stage-2 knn)
    pool_max_kernel<<<nblk((long)B * 64 * 256), TPB, 0, stream>>>(fm3, knn4, fm3p, B, 256, 64, 256);

    // ---- stage 3 (V=64) ----
    knn_radix_kernel<20, 1, true, false, 0><<<dim3(16, B), TPB, 0, stream>>>(
        verts, knn, ndir, 64, nullptr, nullptr, 0, nullptr);
    gemm64_kernel<0><<<dim3(32, 32), TPB, 0, stream>>>(fm3p, c4_w, c4_b, nullptr, nullptr, fout, B * 64, 2048, 256, 0);
    conv_act_kernel<<<nblk((long)B * 64 * 256), TPB, 0, stream>>>(ndir, knn, fout, c4_dir, convp, B, 64, 20, 1024);
    bn_partial_kernel<<<nblk(1024 * 32), TPB, 0, stream>>>(convp, partial, B * 64, 1024, 32);
    gemm64_kernel<1><<<dim3(16, 32), TPB, 0, stream>>>(fm3p, d4t, nullptr, convp, partial, fm4, B * 64, 1024, 256, 32);

    // ---- classifier ----
    rowmax_kernel<<<nblk((long)B * 1024), TPB, 0, stream>>>(fm4, gbuf, B, 64, 1024);
    gemm_t_wave_kernel<<<nblk((long)32 * 256 * 64), TPB, 0, stream>>>(gbuf, cls_w1, cls_b1, hbuf, 32, 1024, 256);
    cls_fused_kernel<<<320, TPB, 0, stream>>>(hbuf, cls_g, cls_beta, cls_w2, cls_b2, (float*)d_out);
}

// Round 12
// 413.628 us; speedup vs baseline: 1.9609x; 1.2479x over previous
//
#include <hip/hip_runtime.h>

#define TPB 256
static inline int nblk(long n) { return (int)((n + TPB - 1) / TPB); }

#define FINF 3.402823466e38f

// ---------------- fused input transposes: verts (B,3,V)->(B,V,3) + d1..d4 w^T ----------------
__global__ __launch_bounds__(TPB) void transpose_all_kernel(const float* __restrict__ vin, float* __restrict__ verts,
                                                            const float* __restrict__ d1, const float* __restrict__ d2,
                                                            const float* __restrict__ d3, const float* __restrict__ d4,
                                                            float* __restrict__ o1, float* __restrict__ o2,
                                                            float* __restrict__ o3, float* __restrict__ o4) {
    int t = blockIdx.x * blockDim.x + threadIdx.x;
    if (t < 32768) { // verts: B=32, V=1024
        int b = t >> 10, i = t & 1023;
        const float* p = vin + (size_t)b * 3072;
        float* o = verts + (size_t)t * 3;
        o[0] = p[i]; o[1] = p[1024 + i]; o[2] = p[2048 + i];
        return;
    }
    int t1 = t - 32768;
    if (t1 < 2048) { int r = t1 / 32, c = t1 % 32; o1[c * 64 + r] = d1[t1]; return; }
    int t2 = t1 - 2048;
    if (t2 < 8192) { int r = t2 / 64, c = t2 % 64; o2[c * 128 + r] = d2[t2]; return; }
    int t3 = t2 - 8192;
    if (t3 < 32768) { int r = t3 / 128, c = t3 % 128; o3[c * 256 + r] = d3[t3]; return; }
    int t4 = t3 - 32768;
    if (t4 < 262144) { int r = t4 / 256, c = t4 % 256; o4[c * 1024 + r] = d4[t4]; }
}

// ---------------- KNN radix-select, fused epilogues ----------------
// Wave-per-vertex. Exact K-th smallest via bisection on float bit patterns.
// NS>=8: candidates <= M (group-min bound, ~11% of set) are first ballot-
// compacted into a 256-slot LDS array, so bisection runs over 4 slots not NS
// (4x fewer ballots/iter). Order-preserving => jax lowest-index tie-break kept.
// Overflow (cnt>256, ~0.3%) falls back to the full-width path.
// WDIR: write normalized neighbor dirs. CSURF: also compute conv_surface fm0.
// K2>0: vertices i<V2 also emit K2-NN indices for pooling via shfl rank.
template <int K, int NS, bool WDIR, bool CSURF, int K2>
__global__ __launch_bounds__(TPB, 1) void knn_radix_kernel(const float* __restrict__ verts,
                                                           int* __restrict__ knn, float* __restrict__ ndir,
                                                           int V_out, const float* __restrict__ c0dir,
                                                           float* __restrict__ fm0,
                                                           int V2, int* __restrict__ knn4) {
    constexpr int VF = NS * 64;
    __shared__ float4 pts[VF]; // (x, y, z, |p|^2)
    __shared__ int sidx[4][K];
    __shared__ float sdir[4][K][3];
    int b = blockIdx.y;
    const float* vb = verts + (size_t)b * 1024 * 3;
    for (int j = threadIdx.x; j < VF; j += blockDim.x) {
        float x = vb[j * 3], y = vb[j * 3 + 1], z = vb[j * 3 + 2];
        pts[j] = make_float4(x, y, z, x * x + y * y + z * z);
    }
    __syncthreads();
    int lane = threadIdx.x & 63;
    int w = threadIdx.x >> 6;
    int i = blockIdx.x * 4 + w; // 4 waves/block, grid sized exactly
    if (i >= V_out) return;
    float4 pi = pts[i];
    unsigned ud[NS];
    unsigned lmin = 0xFFFFFFFFu;
#pragma unroll
    for (int s = 0; s < NS; ++s) {
        int j = s * 64 + lane;
        float4 pj = pts[j];
        float dist = pi.w + pj.w - 2.f * (pi.x * pj.x + pi.y * pj.y + pi.z * pj.z);
        dist = fmaxf(dist, 0.f); // keep bit-monotone (fp rounding can go < 0)
        unsigned v = (j == i) ? 0xFFFFFFFFu : __float_as_uint(dist);
        ud[s] = v;
        lmin = v < lmin ? v : lmin;
    }
    // group-min upper bound: 32 disjoint lane-pair groups (2*NS values each);
    // each group-min is a candidate <= M, so count(<=M) >= 32 >= K.
    unsigned pmin = lmin;
    {
        unsigned o = (unsigned)__shfl_xor((int)pmin, 1, 64);
        pmin = o < pmin ? o : pmin;
    }
    unsigned gmin = lmin, M = pmin;
#pragma unroll
    for (int off = 32; off > 1; off >>= 1) {
        unsigned on = (unsigned)__shfl_xor((int)gmin, off, 64);
        gmin = on < gmin ? on : gmin;
        unsigned om = (unsigned)__shfl_xor((int)M, off, 64);
        M = om > M ? om : M;
    }
    {
        unsigned on = (unsigned)__shfl_xor((int)gmin, 1, 64);
        gmin = on < gmin ? on : gmin;
    }
    int* orow = knn + ((size_t)(b * V_out + i)) * K;
    unsigned long long lmask = (1ull << lane) - 1ull;
    bool done = false;
    if constexpr (NS >= 8) {
        __shared__ unsigned cdist[4][256];
        __shared__ unsigned short cidx[4][256];
        int cnt = 0;
#pragma unroll
        for (int s = 0; s < NS; ++s) {
            unsigned long long mm = __ballot(ud[s] <= M);
            if (ud[s] <= M) {
                int p = cnt + __popcll(mm & lmask);
                if (p < 256) { cdist[w][p] = ud[s]; cidx[w][p] = (unsigned short)(s * 64 + lane); }
            }
            cnt += __popcll(mm);
        }
        if (cnt <= 256) { // wave-uniform (cnt from ballots)
            unsigned cd[4];
#pragma unroll
            for (int r = 0; r < 4; ++r) {
                int p = lane + r * 64;
                cd[r] = p < cnt ? cdist[w][p] : 0xFFFFFFFFu;
            }
            unsigned lo = gmin, hi = M + 1u;
            while (hi - lo > 1u) {
                unsigned mid = lo + ((hi - lo) >> 1);
                int c = 0;
#pragma unroll
                for (int r = 0; r < 4; ++r)
                    c += __popcll(__ballot(cd[r] < mid));
                if (c >= K) hi = mid; else lo = mid;
            }
            unsigned T = lo;
            int base = 0;
#pragma unroll
            for (int r = 0; r < 4; ++r) {
                unsigned long long mm = __ballot(cd[r] < T);
                if (cd[r] < T) {
                    int p = base + __popcll(mm & lmask);
                    int j = cidx[w][lane + r * 64];
                    sidx[w][p] = j; orow[p] = j;
                }
                base += __popcll(mm);
            }
            int need = K - base, run = 0;
#pragma unroll
            for (int r = 0; r < 4; ++r) {
                unsigned long long mm = __ballot(cd[r] == T);
                int rr = run + __popcll(mm & lmask);
                if (cd[r] == T && rr < need) {
                    int j = cidx[w][lane + r * 64];
                    sidx[w][base + rr] = j; orow[base + rr] = j;
                }
                run += __popcll(mm);
            }
            done = true;
        }
    }
    if (!done) { // full-width path (NS<8 instances, or rare compaction overflow)
        unsigned lo = gmin, hi = M + 1u;
        while (hi - lo > 1u) {
            unsigned mid = lo + ((hi - lo) >> 1);
            int cnt = 0;
#pragma unroll
            for (int s = 0; s < NS; ++s)
                cnt += __popcll(__ballot(ud[s] < mid));
            if (cnt >= K) hi = mid; else lo = mid;
        }
        unsigned T = lo;
        int base = 0;
#pragma unroll
        for (int s = 0; s < NS; ++s) {
            unsigned long long m = __ballot(ud[s] < T);
            if (ud[s] < T) {
                int p = base + __popcll(m & lmask);
                sidx[w][p] = s * 64 + lane;
                orow[p] = s * 64 + lane;
            }
            base += __popcll(m);
        }
        int need = K - base, run = 0;
#pragma unroll
        for (int s = 0; s < NS; ++s) {
            unsigned long long m = __ballot(ud[s] == T);
            int r = run + __popcll(m & lmask);
            if (ud[s] == T && r < need) {
                sidx[w][base + r] = s * 64 + lane;
                orow[base + r] = s * 64 + lane;
            }
            run += __popcll(m);
        }
    }
    // --- epilogues: wave-synchronous LDS reads (same wave wrote sidx[w]) ---
    if (WDIR) {
        if (lane < K) {
            int j = sidx[w][lane];
            float4 pj = pts[j];
            float dx = pj.x - pi.x, dy = pj.y - pi.y, dz = pj.z - pi.z;
            float inv = 1.f / fmaxf(sqrtf(dx * dx + dy * dy + dz * dz), 1e-12f);
            float* o = ndir + ((size_t)(b * V_out + i) * K + lane) * 3;
            float nx = dx * inv, ny = dy * inv, nz = dz * inv;
            o[0] = nx; o[1] = ny; o[2] = nz;
            if (CSURF) { sdir[w][lane][0] = nx; sdir[w][lane][1] = ny; sdir[w][lane][2] = nz; }
        }
        if (CSURF && lane < 32) {
            int c = lane;
            float d0 = c0dir[c], d1 = c0dir[32 + c], d2 = c0dir[64 + c];
            float inv = 1.f / fmaxf(sqrtf(d0 * d0 + d1 * d1 + d2 * d2), 1e-12f);
            d0 *= inv; d1 *= inv; d2 *= inv;
            float m = 0.f;
            for (int n = 0; n < K; ++n) {
                float th = sdir[w][n][0] * d0 + sdir[w][n][1] * d1 + sdir[w][n][2] * d2;
                m = fmaxf(m, th);
            }
            fm0[(size_t)(b * V_out + i) * 32 + c] = m; // relu(max) == max of relus
        }
    }
    if (K2 > 0 && i < V2) {
        // 4-NN subset of the 20-NN: exact rank among the K selected candidates
        // via shfl loop, (dist, vertex-index) lexicographic (jax tie-break).
        float dsel = FINF;
        int jsel = 0x7FFFFFFF;
        if (lane < K) {
            jsel = sidx[w][lane];
            float4 pj = pts[jsel];
            dsel = fmaxf(pi.w + pj.w - 2.f * (pi.x * pj.x + pi.y * pj.y + pi.z * pj.z), 0.f);
        }
        int rank = 0;
        for (int m = 0; m < K; ++m) {
            float dm = __shfl(dsel, m, 64);
            int jm = __shfl(jsel, m, 64);
            rank += (dm < dsel || (dm == dsel && jm < jsel)) ? 1 : 0;
        }
        if (lane < K && rank < K2) knn4[((size_t)(b * V2 + i)) * K2 + rank] = jsel;
    }
}

// ---------------- LDS-tiled GEMM 64x64, BK=32 ----------------
// MODE 0: out = A@W + bias.  MODE 1: out = bnrelu(conv) + A@W, with BN stats
// finalized in-kernel from the partial buffer. Finalize is parallelized over
// all 256 threads (4 split-groups x 64 cols) - the old 64-thread serial loop
// over nsplit was a ~20us latency stall per block (r11 profile: VALUBusy 3.7%).
template <int MODE>
__global__ __launch_bounds__(TPB) void gemm64_kernel(const float* __restrict__ A, const float* __restrict__ W,
                                                     const float* __restrict__ bias,
                                                     const float* __restrict__ conv, const float* __restrict__ partial,
                                                     float* __restrict__ out, int M, int N, int K, int nsplit) {
    __shared__ float As[64][36]; // padded rows (144 B, 16B-aligned)
    __shared__ float Bs[32][68]; // padded rows (272 B, 16B-aligned)
    __shared__ float smean[64], sinv[64];
    int t = threadIdx.x;
    int tx = t & 15, ty = t >> 4;
    int colbase = blockIdx.x * 64, rowbase = blockIdx.y * 64;
    int r0 = ty * 4, c0 = tx * 4;
    if constexpr (MODE == 1) {
        __shared__ double sred[2][4][64];
        int cc = t & 63, g = t >> 6;
        double s = 0.0, ss = 0.0;
        for (int sp = g; sp < nsplit; sp += 4) {
            s += partial[(size_t)sp * 2 * N + colbase + cc];
            ss += partial[(size_t)sp * 2 * N + N + colbase + cc];
        }
        sred[0][g][cc] = s; sred[1][g][cc] = ss;
        __syncthreads();
        if (t < 64) {
            double S = sred[0][0][t] + sred[0][1][t] + sred[0][2][t] + sred[0][3][t];
            double SS = sred[1][0][t] + sred[1][1][t] + sred[1][2][t] + sred[1][3][t];
            double mean = S / M;
            double var = SS / M - mean * mean;
            if (var < 0) var = 0;
            smean[t] = (float)mean;
            sinv[t] = rsqrtf((float)var + 1e-5f);
        }
        __syncthreads();
    }
    float4 acc0, acc1, acc2, acc3;
    if (MODE == 0) {
        float4 bv = *(const float4*)(bias + colbase + c0);
        acc0 = bv; acc1 = bv; acc2 = bv; acc3 = bv;
    } else {
        acc0 = make_float4(0.f, 0.f, 0.f, 0.f); acc1 = acc0; acc2 = acc0; acc3 = acc0;
    }
    for (int kt = 0; kt < K; kt += 32) {
#pragma unroll
        for (int l = 0; l < 2; ++l) {
            int lin = t + l * 256;
            int ar = lin >> 3, ak = (lin & 7) << 2;
            *(float4*)&As[ar][ak] = *(const float4*)(A + (size_t)(rowbase + ar) * K + kt + ak);
            int br = lin >> 4, bn = (lin & 15) << 2;
            *(float4*)&Bs[br][bn] = *(const float4*)(W + (size_t)(kt + br) * N + colbase + bn);
        }
        __syncthreads();
#pragma unroll 4
        for (int k = 0; k < 32; ++k) {
            float4 bv = *(const float4*)&Bs[k][c0];
            float a0 = As[r0][k], a1 = As[r0 + 1][k], a2 = As[r0 + 2][k], a3 = As[r0 + 3][k];
            acc0.x += a0 * bv.x; acc0.y += a0 * bv.y; acc0.z += a0 * bv.z; acc0.w += a0 * bv.w;
            acc1.x += a1 * bv.x; acc1.y += a1 * bv.y; acc1.z += a1 * bv.z; acc1.w += a1 * bv.w;
            acc2.x += a2 * bv.x; acc2.y += a2 * bv.y; acc2.z += a2 * bv.z; acc2.w += a2 * bv.w;
            acc3.x += a3 * bv.x; acc3.y += a3 * bv.y; acc3.z += a3 * bv.z; acc3.w += a3 * bv.w;
        }
        __syncthreads();
    }
    float4 accs[4] = {acc0, acc1, acc2, acc3};
    if (MODE == 1) {
        float4 mean = *(const float4*)&smean[c0];
        float4 inv = *(const float4*)&sinv[c0];
#pragma unroll
        for (int rr = 0; rr < 4; ++rr) {
            float4 cv = *(const float4*)(conv + (size_t)(rowbase + r0 + rr) * N + colbase + c0);
            accs[rr].x += fmaxf((cv.x - mean.x) * inv.x, 0.f);
            accs[rr].y += fmaxf((cv.y - mean.y) * inv.y, 0.f);
            accs[rr].z += fmaxf((cv.z - mean.z) * inv.z, 0.f);
            accs[rr].w += fmaxf((cv.w - mean.w) * inv.w, 0.f);
        }
    }
#pragma unroll
    for (int rr = 0; rr < 4; ++rr)
        *(float4*)(out + (size_t)(rowbase + r0 + rr) * N + colbase + c0) = accs[rr];
}

// ---------------- conv_layer: center + max_n(theta * support), 4 ch/thread ----------------
__global__ __launch_bounds__(TPB) void conv_act_kernel(const float* __restrict__ ndir, const int* __restrict__ knn,
                                const float* __restrict__ fout, const float* __restrict__ dir,
                                float* __restrict__ out, int B, int Vst, int K, int Cout) {
    int t = blockIdx.x * blockDim.x + threadIdx.x;
    int nc4 = Cout >> 2;
    if (t >= B * Vst * nc4) return;
    int row = t / nc4, c4 = (t % nc4) * 4;
    int b = row / Vst;
    float4 D0 = *(const float4*)(dir + c4);
    float4 D1 = *(const float4*)(dir + Cout + c4);
    float4 D2 = *(const float4*)(dir + 2 * Cout + c4);
    float4 e0, e1, e2;
    {
        float i0 = 1.f / fmaxf(sqrtf(D0.x * D0.x + D1.x * D1.x + D2.x * D2.x), 1e-12f);
        float i1 = 1.f / fmaxf(sqrtf(D0.y * D0.y + D1.y * D1.y + D2.y * D2.y), 1e-12f);
        float i2 = 1.f / fmaxf(sqrtf(D0.z * D0.z + D1.z * D1.z + D2.z * D2.z), 1e-12f);
        float i3 = 1.f / fmaxf(sqrtf(D0.w * D0.w + D1.w * D1.w + D2.w * D2.w), 1e-12f);
        e0 = make_float4(D0.x * i0, D0.y * i1, D0.z * i2, D0.w * i3);
        e1 = make_float4(D1.x * i0, D1.y * i1, D1.z * i2, D1.w * i3);
        e2 = make_float4(D2.x * i0, D2.y * i1, D2.z * i2, D2.w * i3);
    }
    int Cw = 2 * Cout;
    float4 m = make_float4(-FINF, -FINF, -FINF, -FINF);
    const float* nd = ndir + (size_t)row * K * 3;
    const int* kr = knn + (size_t)row * K;
    for (int n = 0; n < K; ++n) {
        int j = kr[n];
        float n0 = nd[n * 3], n1 = nd[n * 3 + 1], n2 = nd[n * 3 + 2];
        float4 s = *(const float4*)(fout + ((size_t)(b * Vst + j)) * Cw + Cout + c4);
        float t0 = fmaxf(n0 * e0.x + n1 * e1.x + n2 * e2.x, 0.f);
        float t1 = fmaxf(n0 * e0.y + n1 * e1.y + n2 * e2.y, 0.f);
        float t2 = fmaxf(n0 * e0.z + n1 * e1.z + n2 * e2.z, 0.f);
        float t3 = fmaxf(n0 * e0.w + n1 * e1.w + n2 * e2.w, 0.f);
        m.x = fmaxf(m.x, t0 * s.x);
        m.y = fmaxf(m.y, t1 * s.y);
        m.z = fmaxf(m.z, t2 * s.z);
        m.w = fmaxf(m.w, t3 * s.w);
    }
    float4 ctr = *(const float4*)(fout + (size_t)row * Cw + c4);
    *(float4*)(out + (size_t)row * Cout + c4) = make_float4(ctr.x + m.x, ctr.y + m.y, ctr.z + m.z, ctr.w + m.w);
}

// ---------------- BN stats pass 1: coalesced float partials ----------------
__global__ __launch_bounds__(TPB) void bn_partial_kernel(const float* __restrict__ x, float* __restrict__ partial,
                                                         int rows, int C, int nsplit) {
    int t = blockIdx.x * blockDim.x + threadIdx.x;
    if (t >= C * nsplit) return;
    int c = t % C, sp = t / C;
    int chunk = rows / nsplit;
    int r0 = sp * chunk;
    float s = 0.f, ss = 0.f;
    for (int r = r0; r < r0 + chunk; ++r) {
        float v = x[(size_t)r * C + c];
        s += v; ss += v * v;
    }
    partial[(size_t)sp * 2 * C + c] = s;
    partial[(size_t)sp * 2 * C + C + c] = ss;
}

// ---------------- pool: max over 4 NN features ----------------
__global__ __launch_bounds__(TPB) void pool_max_kernel(const float* __restrict__ fm, const int* __restrict__ knn4,
                                float* __restrict__ out, int B, int Vin, int pn, int C) {
    int t = blockIdx.x * blockDim.x + threadIdx.x;
    if (t >= B * pn * C) return;
    int row = t / C, c = t % C;
    int b = row / pn;
    const int* kr = knn4 + (size_t)row * 4;
    float m = fmaxf(fmaxf(fm[((size_t)(b * Vin + kr[0])) * C + c], fm[((size_t)(b * Vin + kr[1])) * C + c]),
                    fmaxf(fm[((size_t)(b * Vin + kr[2])) * C + c], fm[((size_t)(b * Vin + kr[3])) * C + c]));
    out[t] = m;
}

// ---------------- g = max over vertices ----------------
__global__ __launch_bounds__(TPB) void rowmax_kernel(const float* __restrict__ fm, float* __restrict__ g,
                              int B, int V, int C) {
    int t = blockIdx.x * blockDim.x + threadIdx.x;
    if (t >= B * C) return;
    int b = t / C, c = t % C;
    float m = -FINF;
    for (int i = 0; i < V; ++i) m = fmaxf(m, fm[((size_t)(b * V + i)) * C + c]);
    g[t] = m;
}

// ---------------- wave-per-output: out[r,c] = in[r,:]@w[c,:] + bias[c] ----------------
__global__ __launch_bounds__(TPB, 1) void gemm_t_wave_kernel(const float* __restrict__ in, const float* __restrict__ w,
                                   const float* __restrict__ bias, float* __restrict__ out,
                                   int rows, int Cin, int Cout) {
    int wid = (blockIdx.x * blockDim.x + threadIdx.x) >> 6;
    int lane = threadIdx.x & 63;
    if (wid >= rows * Cout) return;
    int r = wid / Cout, c = wid % Cout;
    const float4* a = (const float4*)(in + (size_t)r * Cin);
    const float4* wr = (const float4*)(w + (size_t)c * Cin);
    int n4 = Cin >> 2;
    float acc = 0.f;
    for (int k = lane; k < n4; k += 64) {
        float4 av = a[k], wv = wr[k];
        acc += av.x * wv.x + av.y * wv.y + av.z * wv.z + av.w * wv.w;
    }
#pragma unroll
    for (int off = 32; off > 0; off >>= 1) acc += __shfl_xor(acc, off, 64);
    if (lane == 0) out[wid] = acc + bias[c];
}

// ---------------- fused classifier tail: BN stats (per-block) + relu(bn(h))@w2^T + b2 ----------------
__global__ __launch_bounds__(TPB, 1) void cls_fused_kernel(const float* __restrict__ h,
                                 const float* __restrict__ gam, const float* __restrict__ beta,
                                 const float* __restrict__ w2, const float* __restrict__ b2,
                                 float* __restrict__ out) {
    __shared__ float smean[256], sa[256];
    int t = threadIdx.x;
    {
        float s = 0.f, ss = 0.f;
        for (int b = 0; b < 32; ++b) {
            float v = h[(size_t)b * 256 + t];
            s += v; ss += v * v;
        }
        float mn = s / 32.f;
        float var = ss / 32.f - mn * mn;
        if (var < 0.f) var = 0.f;
        smean[t] = mn;
        sa[t] = rsqrtf(var + 1e-5f) * gam[t]; // fold gamma
    }
    __syncthreads();
    int wid = blockIdx.x * 4 + (t >> 6);
    int lane = t & 63;
    if (wid >= 32 * 40) return;
    int b = wid / 40, o = wid % 40;
    float acc = 0.f;
#pragma unroll
    for (int kk = 0; kk < 4; ++kk) {
        int c = lane + kk * 64;
        float v = fmaxf((h[b * 256 + c] - smean[c]) * sa[c] + beta[c], 0.f);
        acc += v * w2[o * 256 + c];
    }
#pragma unroll
    for (int off = 32; off > 0; off >>= 1) acc += __shfl_xor(acc, off, 64);
    if (lane == 0) out[wid] = acc + b2[o];
}

extern "C" void kernel_launch(void* const* d_in, const int* in_sizes, int n_in,
                              void* d_out, int out_size, void* d_ws, size_t ws_size,
                              hipStream_t stream) {
    const float* vertices = (const float*)d_in[0];
    const float* c0_dir = (const float*)d_in[1];
    const float* c1_w  = (const float*)d_in[2];
    const float* c1_b  = (const float*)d_in[3];
    const float* c1_dir = (const float*)d_in[4];
    const float* d1_w  = (const float*)d_in[5];
    const float* c2_w  = (const float*)d_in[6];
    const float* c2_b  = (const float*)d_in[7];
    const float* c2_dir = (const float*)d_in[8];
    const float* d2_w  = (const float*)d_in[9];
    const float* c3_w  = (const float*)d_in[10];
    const float* c3_b  = (const float*)d_in[11];
    const float* c3_dir = (const float*)d_in[12];
    const float* d3_w  = (const float*)d_in[13];
    const float* c4_w  = (const float*)d_in[14];
    const float* c4_b  = (const float*)d_in[15];
    const float* c4_dir = (const float*)d_in[16];
    const float* d4_w  = (const float*)d_in[17];
    const float* cls_w1 = (const float*)d_in[18];
    const float* cls_b1 = (const float*)d_in[19];
    const float* cls_g  = (const float*)d_in[20];
    const float* cls_beta = (const float*)d_in[21];
    const float* cls_w2 = (const float*)d_in[22];
    const float* cls_b2 = (const float*)d_in[23];

    const int B = 32;
    float* ws = (float*)d_ws;
    size_t off = 0;
    auto alloc = [&](size_t n) { float* p = ws + off; off += n; return p; };
    float* verts = alloc(98304);            // B*1024*3
    int*   knn   = (int*)alloc(655360);     // max B*1024*20
    int*   knn4  = (int*)alloc(32768);      // max B*256*4
    float* ndir  = alloc(1966080);          // max B*1024*20*3
    float* fm0   = alloc(1048576);          // B*1024*32
    float* fm1   = alloc(2097152);          // B*1024*64
    float* fm1p  = alloc(524288);           // B*256*64
    float* fm2   = alloc(1048576);          // B*256*128
    float* fm3   = alloc(2097152);          // B*256*256
    float* fm3p  = alloc(524288);           // B*64*256
    float* fm4   = alloc(2097152);          // B*64*1024
    float* fout  = alloc(4194304);          // max fout sizes
    float* convp = alloc(2097152);          // pre-BN conv out
    float* gbuf  = alloc(32768);            // B*1024
    float* hbuf  = alloc(8192);             // B*256
    float* d1t   = alloc(2048);             // 32 x 64
    float* d2t   = alloc(8192);             // 64 x 128
    float* d3t   = alloc(32768);            // 128 x 256
    float* d4t   = alloc(262144);           // 256 x 1024
    float* partial = alloc(65536);          // bn partials, max 2*C*nsplit

    // ---- fused input transposes ----
    transpose_all_kernel<<<nblk(32768 + 2048 + 8192 + 32768 + 262144), TPB, 0, stream>>>(
        vertices, verts, d1_w, d2_w, d3_w, d4_w, d1t, d2t, d3t, d4t);

    // ---- stage 1 (V=1024) ----
    knn_radix_kernel<20, 16, true, true, 4><<<dim3(256, B), TPB, 0, stream>>>(
        verts, knn, ndir, 1024, c0_dir, fm0, 256, knn4);
    gemm64_kernel<0><<<dim3(2, 512), TPB, 0, stream>>>(fm0, c1_w, c1_b, nullptr, nullptr, fout, B * 1024, 128, 32, 0);
    conv_act_kernel<<<nblk((long)B * 1024 * 16), TPB, 0, stream>>>(ndir, knn, fout, c1_dir, convp, B, 1024, 20, 64);
    bn_partial_kernel<<<nblk(64 * 256), TPB, 0, stream>>>(convp, partial, B * 1024, 64, 256);
    gemm64_kernel<1><<<dim3(1, 512), TPB, 0, stream>>>(fm0, d1t, nullptr, convp, partial, fm1, B * 1024, 64, 32, 256);
    // pool 1024 -> 256 (indices precomputed in stage-1 knn)
    pool_max_kernel<<<nblk((long)B * 256 * 64), TPB, 0, stream>>>(fm1, knn4, fm1p, B, 1024, 256, 64);

    // ---- stage 2 (V=256) ----
    knn_radix_kernel<20, 4, true, false, 4><<<dim3(64, B), TPB, 0, stream>>>(
        verts, knn, ndir, 256, nullptr, nullptr, 64, knn4);
    gemm64_kernel<0><<<dim3(4, 128), TPB, 0, stream>>>(fm1p, c2_w, c2_b, nullptr, nullptr, fout, B * 256, 256, 64, 0);
    conv_act_kernel<<<nblk((long)B * 256 * 32), TPB, 0, stream>>>(ndir, knn, fout, c2_dir, convp, B, 256, 20, 128);
    bn_partial_kernel<<<nblk(128 * 128), TPB, 0, stream>>>(convp, partial, B * 256, 128, 128);
    gemm64_kernel<1><<<dim3(2, 128), TPB, 0, stream>>>(fm1p, d2t, nullptr, convp, partial, fm2, B * 256, 128, 64, 128);
    gemm64_kernel<0><<<dim3(8, 128), TPB, 0, stream>>>(fm2, c3_w, c3_b, nullptr, nullptr, fout, B * 256, 512, 128, 0);
    conv_act_kernel<<<nblk((long)B * 256 * 64), TPB, 0, stream>>>(ndir, knn, fout, c3_dir, convp, B, 256, 20, 256);
    bn_partial_kernel<<<nblk(256 * 128), TPB, 0, stream>>>(convp, partial, B * 256, 256, 128);
    gemm64_kernel<1><<<dim3(4, 128), TPB, 0, stream>>>(fm2, d3t, nullptr, convp, partial, fm3, B * 256, 256, 128, 128);
    // pool 256 -> 64 (indices precomputed in stage-2 knn)
    pool_max_kernel<<<nblk((long)B * 64 * 256), TPB, 0, stream>>>(fm3, knn4, fm3p, B, 256, 64, 256);

    // ---- stage 3 (V=64) ----
    knn_radix_kernel<20, 1, true, false, 0><<<dim3(16, B), TPB, 0, stream>>>(
        verts, knn, ndir, 64, nullptr, nullptr, 0, nullptr);
    gemm64_kernel<0><<<dim3(32, 32), TPB, 0, stream>>>(fm3p, c4_w, c4_b, nullptr, nullptr, fout, B * 64, 2048, 256, 0);
    conv_act_kernel<<<nblk((long)B * 64 * 256), TPB, 0, stream>>>(ndir, knn, fout, c4_dir, convp, B, 64, 20, 1024);
    bn_partial_kernel<<<nblk(1024 * 32), TPB, 0, stream>>>(convp, partial, B * 64, 1024, 32);
    gemm64_kernel<1><<<dim3(16, 32), TPB, 0, stream>>>(fm3p, d4t, nullptr, convp, partial, fm4, B * 64, 1024, 256, 32);

    // ---- classifier ----
    rowmax_kernel<<<nblk((long)B * 1024), TPB, 0, stream>>>(fm4, gbuf, B, 64, 1024);
    gemm_t_wave_kernel<<<nblk((long)32 * 256 * 64), TPB, 0, stream>>>(gbuf, cls_w1, cls_b1, hbuf, 32, 1024, 256);
    cls_fused_kernel<<<320, TPB, 0, stream>>>(hbuf, cls_g, cls_beta, cls_w2, cls_b2, (float*)d_out);
}

// Round 13
// 393.165 us; speedup vs baseline: 2.0630x; 1.0520x over previous
//
#include <hip/hip_runtime.h>

#define TPB 256
#define KNN_TPB 512
static inline int nblk(long n) { return (int)((n + TPB - 1) / TPB); }

#define FINF 3.402823466e38f

// ---------------- fused weight transposes: d1..d4 (Cout x Cin) -> (Cin x Cout) ----------------
__global__ __launch_bounds__(TPB) void transpose_all_kernel(const float* __restrict__ d1, const float* __restrict__ d2,
                                                            const float* __restrict__ d3, const float* __restrict__ d4,
                                                            float* __restrict__ o1, float* __restrict__ o2,
                                                            float* __restrict__ o3, float* __restrict__ o4) {
    int t = blockIdx.x * blockDim.x + threadIdx.x;
    if (t < 2048) { int r = t / 32, c = t % 32; o1[c * 64 + r] = d1[t]; return; }
    int t2 = t - 2048;
    if (t2 < 8192) { int r = t2 / 64, c = t2 % 64; o2[c * 128 + r] = d2[t2]; return; }
    int t3 = t2 - 8192;
    if (t3 < 32768) { int r = t3 / 128, c = t3 % 128; o3[c * 256 + r] = d3[t3]; return; }
    int t4 = t3 - 32768;
    if (t4 < 262144) { int r = t4 / 256, c = t4 % 256; o4[c * 1024 + r] = d4[t4]; }
}

// ---------------- KNN radix-select, fused epilogues ----------------
// 8 waves/block share one LDS point cache (amortizes staging, lifts occupancy
// to ~100%; r12 profile showed 50% at 4 waves/24KB). Reads vertices in the
// ORIGINAL (B,3,V) layout - coalesced per component, no transpose needed.
// Exact K-th smallest via bisection on float bit patterns; NS>=8 first ballot-
// compacts candidates <= M (group-min bound) into 256 LDS slots so bisection
// ballots 4 regs not NS. Overflow (cnt>256, rare) falls back to full width.
// WDIR: write normalized neighbor dirs. CSURF: conv_surface fm0 fused.
// K2>0: vertices i<V2 emit K2-NN indices for pooling via shfl rank.
template <int K, int NS, bool WDIR, bool CSURF, int K2>
__global__ __launch_bounds__(KNN_TPB, 1) void knn_radix_kernel(const float* __restrict__ vin,
                                                           int* __restrict__ knn, float* __restrict__ ndir,
                                                           int V_out, const float* __restrict__ c0dir,
                                                           float* __restrict__ fm0,
                                                           int V2, int* __restrict__ knn4) {
    constexpr int VF = NS * 64;
    __shared__ float4 pts[VF]; // (x, y, z, |p|^2)
    __shared__ int sidx[8][K];
    __shared__ float sdir[8][K][3];
    int b = blockIdx.y;
    const float* vb = vin + (size_t)b * 3072; // (3, 1024) layout
    for (int j = threadIdx.x; j < VF; j += blockDim.x) {
        float x = vb[j], y = vb[1024 + j], z = vb[2048 + j];
        pts[j] = make_float4(x, y, z, x * x + y * y + z * z);
    }
    __syncthreads();
    int lane = threadIdx.x & 63;
    int w = threadIdx.x >> 6;
    int i = blockIdx.x * 8 + w; // 8 waves/block, grid sized exactly
    if (i >= V_out) return;
    float4 pi = pts[i];
    unsigned ud[NS];
    unsigned lmin = 0xFFFFFFFFu;
#pragma unroll
    for (int s = 0; s < NS; ++s) {
        int j = s * 64 + lane;
        float4 pj = pts[j];
        float dist = pi.w + pj.w - 2.f * (pi.x * pj.x + pi.y * pj.y + pi.z * pj.z);
        dist = fmaxf(dist, 0.f); // keep bit-monotone (fp rounding can go < 0)
        unsigned v = (j == i) ? 0xFFFFFFFFu : __float_as_uint(dist);
        ud[s] = v;
        lmin = v < lmin ? v : lmin;
    }
    // group-min upper bound: 32 disjoint lane-pair groups (2*NS values each);
    // each group-min is a candidate <= M, so count(<=M) >= 32 >= K.
    unsigned pmin = lmin;
    {
        unsigned o = (unsigned)__shfl_xor((int)pmin, 1, 64);
        pmin = o < pmin ? o : pmin;
    }
    unsigned gmin = lmin, M = pmin;
#pragma unroll
    for (int off = 32; off > 1; off >>= 1) {
        unsigned on = (unsigned)__shfl_xor((int)gmin, off, 64);
        gmin = on < gmin ? on : gmin;
        unsigned om = (unsigned)__shfl_xor((int)M, off, 64);
        M = om > M ? om : M;
    }
    {
        unsigned on = (unsigned)__shfl_xor((int)gmin, 1, 64);
        gmin = on < gmin ? on : gmin;
    }
    int* orow = knn + ((size_t)(b * V_out + i)) * K;
    unsigned long long lmask = (1ull << lane) - 1ull;
    bool done = false;
    if constexpr (NS >= 8) {
        __shared__ unsigned cdist[8][256];
        __shared__ unsigned short cidx[8][256];
        int cnt = 0;
#pragma unroll
        for (int s = 0; s < NS; ++s) {
            unsigned long long mm = __ballot(ud[s] <= M);
            if (ud[s] <= M) {
                int p = cnt + __popcll(mm & lmask);
                if (p < 256) { cdist[w][p] = ud[s]; cidx[w][p] = (unsigned short)(s * 64 + lane); }
            }
            cnt += __popcll(mm);
        }
        if (cnt <= 256) { // wave-uniform (cnt from ballots)
            unsigned cd[4];
#pragma unroll
            for (int r = 0; r < 4; ++r) {
                int p = lane + r * 64;
                cd[r] = p < cnt ? cdist[w][p] : 0xFFFFFFFFu;
            }
            unsigned lo = gmin, hi = M + 1u;
            while (hi - lo > 1u) {
                unsigned mid = lo + ((hi - lo) >> 1);
                int c = 0;
#pragma unroll
                for (int r = 0; r < 4; ++r)
                    c += __popcll(__ballot(cd[r] < mid));
                if (c >= K) hi = mid; else lo = mid;
            }
            unsigned T = lo;
            int base = 0;
#pragma unroll
            for (int r = 0; r < 4; ++r) {
                unsigned long long mm = __ballot(cd[r] < T);
                if (cd[r] < T) {
                    int p = base + __popcll(mm & lmask);
                    int j = cidx[w][lane + r * 64];
                    sidx[w][p] = j; orow[p] = j;
                }
                base += __popcll(mm);
            }
            int need = K - base, run = 0;
#pragma unroll
            for (int r = 0; r < 4; ++r) {
                unsigned long long mm = __ballot(cd[r] == T);
                int rr = run + __popcll(mm & lmask);
                if (cd[r] == T && rr < need) {
                    int j = cidx[w][lane + r * 64];
                    sidx[w][base + rr] = j; orow[base + rr] = j;
                }
                run += __popcll(mm);
            }
            done = true;
        }
    }
    if (!done) { // full-width path (NS<8 instances, or rare compaction overflow)
        unsigned lo = gmin, hi = M + 1u;
        while (hi - lo > 1u) {
            unsigned mid = lo + ((hi - lo) >> 1);
            int cnt = 0;
#pragma unroll
            for (int s = 0; s < NS; ++s)
                cnt += __popcll(__ballot(ud[s] < mid));
            if (cnt >= K) hi = mid; else lo = mid;
        }
        unsigned T = lo;
        int base = 0;
#pragma unroll
        for (int s = 0; s < NS; ++s) {
            unsigned long long m = __ballot(ud[s] < T);
            if (ud[s] < T) {
                int p = base + __popcll(m & lmask);
                sidx[w][p] = s * 64 + lane;
                orow[p] = s * 64 + lane;
            }
            base += __popcll(m);
        }
        int need = K - base, run = 0;
#pragma unroll
        for (int s = 0; s < NS; ++s) {
            unsigned long long m = __ballot(ud[s] == T);
            int r = run + __popcll(m & lmask);
            if (ud[s] == T && r < need) {
                sidx[w][base + r] = s * 64 + lane;
                orow[base + r] = s * 64 + lane;
            }
            run += __popcll(m);
        }
    }
    // --- epilogues: wave-synchronous LDS reads (same wave wrote sidx[w]) ---
    if (WDIR) {
        if (lane < K) {
            int j = sidx[w][lane];
            float4 pj = pts[j];
            float dx = pj.x - pi.x, dy = pj.y - pi.y, dz = pj.z - pi.z;
            float inv = 1.f / fmaxf(sqrtf(dx * dx + dy * dy + dz * dz), 1e-12f);
            float* o = ndir + ((size_t)(b * V_out + i) * K + lane) * 3;
            float nx = dx * inv, ny = dy * inv, nz = dz * inv;
            o[0] = nx; o[1] = ny; o[2] = nz;
            if (CSURF) { sdir[w][lane][0] = nx; sdir[w][lane][1] = ny; sdir[w][lane][2] = nz; }
        }
        if (CSURF && lane < 32) {
            int c = lane;
            float d0 = c0dir[c], d1 = c0dir[32 + c], d2 = c0dir[64 + c];
            float inv = 1.f / fmaxf(sqrtf(d0 * d0 + d1 * d1 + d2 * d2), 1e-12f);
            d0 *= inv; d1 *= inv; d2 *= inv;
            float m = 0.f;
            for (int n = 0; n < K; ++n) {
                float th = sdir[w][n][0] * d0 + sdir[w][n][1] * d1 + sdir[w][n][2] * d2;
                m = fmaxf(m, th);
            }
            fm0[(size_t)(b * V_out + i) * 32 + c] = m; // relu(max) == max of relus
        }
    }
    if (K2 > 0 && i < V2) {
        // 4-NN subset of the 20-NN: exact rank among the K selected candidates
        // via shfl loop, (dist, vertex-index) lexicographic (jax tie-break).
        float dsel = FINF;
        int jsel = 0x7FFFFFFF;
        if (lane < K) {
            jsel = sidx[w][lane];
            float4 pj = pts[jsel];
            dsel = fmaxf(pi.w + pj.w - 2.f * (pi.x * pj.x + pi.y * pj.y + pi.z * pj.z), 0.f);
        }
        int rank = 0;
        for (int m = 0; m < K; ++m) {
            float dm = __shfl(dsel, m, 64);
            int jm = __shfl(jsel, m, 64);
            rank += (dm < dsel || (dm == dsel && jm < jsel)) ? 1 : 0;
        }
        if (lane < K && rank < K2) knn4[((size_t)(b * V2 + i)) * K2 + rank] = jsel;
    }
}

// ---------------- LDS-tiled GEMM 64x64, BK=32 ----------------
// MODE 0: out = A@W + bias.  MODE 1: out = bnrelu(conv) + A@W (BN finalized
// in-kernel, parallel over 256 threads).  MODE 2: MODE 1 but instead of
// storing the M x N result, reduce column-max over the block's 64 rows
// (= one batch, V=64) and write gbuf[batch*N + col] - fuses rowmax and
// skips the fm4 round-trip entirely.
template <int MODE>
__global__ __launch_bounds__(TPB) void gemm64_kernel(const float* __restrict__ A, const float* __restrict__ W,
                                                     const float* __restrict__ bias,
                                                     const float* __restrict__ conv, const float* __restrict__ partial,
                                                     float* __restrict__ out, int M, int N, int K, int nsplit) {
    __shared__ float As[64][36]; // padded rows (144 B, 16B-aligned)
    __shared__ float Bs[32][68]; // padded rows (272 B, 16B-aligned)
    __shared__ float smean[64], sinv[64];
    int t = threadIdx.x;
    int tx = t & 15, ty = t >> 4;
    int colbase = blockIdx.x * 64, rowbase = blockIdx.y * 64;
    int r0 = ty * 4, c0 = tx * 4;
    if constexpr (MODE >= 1) {
        __shared__ double sred[2][4][64];
        int cc = t & 63, g = t >> 6;
        double s = 0.0, ss = 0.0;
        for (int sp = g; sp < nsplit; sp += 4) {
            s += partial[(size_t)sp * 2 * N + colbase + cc];
            ss += partial[(size_t)sp * 2 * N + N + colbase + cc];
        }
        sred[0][g][cc] = s; sred[1][g][cc] = ss;
        __syncthreads();
        if (t < 64) {
            double S = sred[0][0][t] + sred[0][1][t] + sred[0][2][t] + sred[0][3][t];
            double SS = sred[1][0][t] + sred[1][1][t] + sred[1][2][t] + sred[1][3][t];
            double mean = S / M;
            double var = SS / M - mean * mean;
            if (var < 0) var = 0;
            smean[t] = (float)mean;
            sinv[t] = rsqrtf((float)var + 1e-5f);
        }
        __syncthreads();
    }
    float4 acc0, acc1, acc2, acc3;
    if (MODE == 0) {
        float4 bv = *(const float4*)(bias + colbase + c0);
        acc0 = bv; acc1 = bv; acc2 = bv; acc3 = bv;
    } else {
        acc0 = make_float4(0.f, 0.f, 0.f, 0.f); acc1 = acc0; acc2 = acc0; acc3 = acc0;
    }
    for (int kt = 0; kt < K; kt += 32) {
#pragma unroll
        for (int l = 0; l < 2; ++l) {
            int lin = t + l * 256;
            int ar = lin >> 3, ak = (lin & 7) << 2;
            *(float4*)&As[ar][ak] = *(const float4*)(A + (size_t)(rowbase + ar) * K + kt + ak);
            int br = lin >> 4, bn = (lin & 15) << 2;
            *(float4*)&Bs[br][bn] = *(const float4*)(W + (size_t)(kt + br) * N + colbase + bn);
        }
        __syncthreads();
#pragma unroll 4
        for (int k = 0; k < 32; ++k) {
            float4 bv = *(const float4*)&Bs[k][c0];
            float a0 = As[r0][k], a1 = As[r0 + 1][k], a2 = As[r0 + 2][k], a3 = As[r0 + 3][k];
            acc0.x += a0 * bv.x; acc0.y += a0 * bv.y; acc0.z += a0 * bv.z; acc0.w += a0 * bv.w;
            acc1.x += a1 * bv.x; acc1.y += a1 * bv.y; acc1.z += a1 * bv.z; acc1.w += a1 * bv.w;
            acc2.x += a2 * bv.x; acc2.y += a2 * bv.y; acc2.z += a2 * bv.z; acc2.w += a2 * bv.w;
            acc3.x += a3 * bv.x; acc3.y += a3 * bv.y; acc3.z += a3 * bv.z; acc3.w += a3 * bv.w;
        }
        __syncthreads();
    }
    float4 accs[4] = {acc0, acc1, acc2, acc3};
    if constexpr (MODE >= 1) {
        float4 mean = *(const float4*)&smean[c0];
        float4 inv = *(const float4*)&sinv[c0];
#pragma unroll
        for (int rr = 0; rr < 4; ++rr) {
            float4 cv = *(const float4*)(conv + (size_t)(rowbase + r0 + rr) * N + colbase + c0);
            accs[rr].x += fmaxf((cv.x - mean.x) * inv.x, 0.f);
            accs[rr].y += fmaxf((cv.y - mean.y) * inv.y, 0.f);
            accs[rr].z += fmaxf((cv.z - mean.z) * inv.z, 0.f);
            accs[rr].w += fmaxf((cv.w - mean.w) * inv.w, 0.f);
        }
    }
    if constexpr (MODE == 2) {
        // column-max over the block's 64 rows (one batch) -> gbuf
        __shared__ float redmax[16][68];
        float4 tm = accs[0];
        tm.x = fmaxf(fmaxf(accs[0].x, accs[1].x), fmaxf(accs[2].x, accs[3].x));
        tm.y = fmaxf(fmaxf(accs[0].y, accs[1].y), fmaxf(accs[2].y, accs[3].y));
        tm.z = fmaxf(fmaxf(accs[0].z, accs[1].z), fmaxf(accs[2].z, accs[3].z));
        tm.w = fmaxf(fmaxf(accs[0].w, accs[1].w), fmaxf(accs[2].w, accs[3].w));
        *(float4*)&redmax[ty][c0] = tm;
        __syncthreads();
        if (t < 64) {
            float m = redmax[0][t];
#pragma unroll
            for (int g = 1; g < 16; ++g) m = fmaxf(m, redmax[g][t]);
            out[(size_t)blockIdx.y * N + colbase + t] = m; // out = gbuf (B x N)
        }
    } else {
#pragma unroll
        for (int rr = 0; rr < 4; ++rr)
            *(float4*)(out + (size_t)(rowbase + r0 + rr) * N + colbase + c0) = accs[rr];
    }
}

// ---------------- conv_layer: center + max_n(theta * support), 4 ch/thread ----------------
__global__ __launch_bounds__(TPB) void conv_act_kernel(const float* __restrict__ ndir, const int* __restrict__ knn,
                                const float* __restrict__ fout, const float* __restrict__ dir,
                                float* __restrict__ out, int B, int Vst, int K, int Cout) {
    int t = blockIdx.x * blockDim.x + threadIdx.x;
    int nc4 = Cout >> 2;
    if (t >= B * Vst * nc4) return;
    int row = t / nc4, c4 = (t % nc4) * 4;
    int b = row / Vst;
    float4 D0 = *(const float4*)(dir + c4);
    float4 D1 = *(const float4*)(dir + Cout + c4);
    float4 D2 = *(const float4*)(dir + 2 * Cout + c4);
    float4 e0, e1, e2;
    {
        float i0 = 1.f / fmaxf(sqrtf(D0.x * D0.x + D1.x * D1.x + D2.x * D2.x), 1e-12f);
        float i1 = 1.f / fmaxf(sqrtf(D0.y * D0.y + D1.y * D1.y + D2.y * D2.y), 1e-12f);
        float i2 = 1.f / fmaxf(sqrtf(D0.z * D0.z + D1.z * D1.z + D2.z * D2.z), 1e-12f);
        float i3 = 1.f / fmaxf(sqrtf(D0.w * D0.w + D1.w * D1.w + D2.w * D2.w), 1e-12f);
        e0 = make_float4(D0.x * i0, D0.y * i1, D0.z * i2, D0.w * i3);
        e1 = make_float4(D1.x * i0, D1.y * i1, D1.z * i2, D1.w * i3);
        e2 = make_float4(D2.x * i0, D2.y * i1, D2.z * i2, D2.w * i3);
    }
    int Cw = 2 * Cout;
    float4 m = make_float4(-FINF, -FINF, -FINF, -FINF);
    const float* nd = ndir + (size_t)row * K * 3;
    const int* kr = knn + (size_t)row * K;
    for (int n = 0; n < K; ++n) {
        int j = kr[n];
        float n0 = nd[n * 3], n1 = nd[n * 3 + 1], n2 = nd[n * 3 + 2];
        float4 s = *(const float4*)(fout + ((size_t)(b * Vst + j)) * Cw + Cout + c4);
        float t0 = fmaxf(n0 * e0.x + n1 * e1.x + n2 * e2.x, 0.f);
        float t1 = fmaxf(n0 * e0.y + n1 * e1.y + n2 * e2.y, 0.f);
        float t2 = fmaxf(n0 * e0.z + n1 * e1.z + n2 * e2.z, 0.f);
        float t3 = fmaxf(n0 * e0.w + n1 * e1.w + n2 * e2.w, 0.f);
        m.x = fmaxf(m.x, t0 * s.x);
        m.y = fmaxf(m.y, t1 * s.y);
        m.z = fmaxf(m.z, t2 * s.z);
        m.w = fmaxf(m.w, t3 * s.w);
    }
    float4 ctr = *(const float4*)(fout + (size_t)row * Cw + c4);
    *(float4*)(out + (size_t)row * Cout + c4) = make_float4(ctr.x + m.x, ctr.y + m.y, ctr.z + m.z, ctr.w + m.w);
}

// ---------------- BN stats pass 1: coalesced float partials ----------------
__global__ __launch_bounds__(TPB) void bn_partial_kernel(const float* __restrict__ x, float* __restrict__ partial,
                                                         int rows, int C, int nsplit) {
    int t = blockIdx.x * blockDim.x + threadIdx.x;
    if (t >= C * nsplit) return;
    int c = t % C, sp = t / C;
    int chunk = rows / nsplit;
    int r0 = sp * chunk;
    float s = 0.f, ss = 0.f;
    for (int r = r0; r < r0 + chunk; ++r) {
        float v = x[(size_t)r * C + c];
        s += v; ss += v * v;
    }
    partial[(size_t)sp * 2 * C + c] = s;
    partial[(size_t)sp * 2 * C + C + c] = ss;
}

// ---------------- pool: max over 4 NN features ----------------
__global__ __launch_bounds__(TPB) void pool_max_kernel(const float* __restrict__ fm, const int* __restrict__ knn4,
                                float* __restrict__ out, int B, int Vin, int pn, int C) {
    int t = blockIdx.x * blockDim.x + threadIdx.x;
    if (t >= B * pn * C) return;
    int row = t / C, c = t % C;
    int b = row / pn;
    const int* kr = knn4 + (size_t)row * 4;
    float m = fmaxf(fmaxf(fm[((size_t)(b * Vin + kr[0])) * C + c], fm[((size_t)(b * Vin + kr[1])) * C + c]),
                    fmaxf(fm[((size_t)(b * Vin + kr[2])) * C + c], fm[((size_t)(b * Vin + kr[3])) * C + c]));
    out[t] = m;
}

// ---------------- wave-per-output: out[r,c] = in[r,:]@w[c,:] + bias[c] ----------------
__global__ __launch_bounds__(TPB, 1) void gemm_t_wave_kernel(const float* __restrict__ in, const float* __restrict__ w,
                                   const float* __restrict__ bias, float* __restrict__ out,
                                   int rows, int Cin, int Cout) {
    int wid = (blockIdx.x * blockDim.x + threadIdx.x) >> 6;
    int lane = threadIdx.x & 63;
    if (wid >= rows * Cout) return;
    int r = wid / Cout, c = wid % Cout;
    const float4* a = (const float4*)(in + (size_t)r * Cin);
    const float4* wr = (const float4*)(w + (size_t)c * Cin);
    int n4 = Cin >> 2;
    float acc = 0.f;
    for (int k = lane; k < n4; k += 64) {
        float4 av = a[k], wv = wr[k];
        acc += av.x * wv.x + av.y * wv.y + av.z * wv.z + av.w * wv.w;
    }
#pragma unroll
    for (int off = 32; off > 0; off >>= 1) acc += __shfl_xor(acc, off, 64);
    if (lane == 0) out[wid] = acc + bias[c];
}

// ---------------- fused classifier tail: BN stats (per-block) + relu(bn(h))@w2^T + b2 ----------------
__global__ __launch_bounds__(TPB, 1) void cls_fused_kernel(const float* __restrict__ h,
                                 const float* __restrict__ gam, const float* __restrict__ beta,
                                 const float* __restrict__ w2, const float* __restrict__ b2,
                                 float* __restrict__ out) {
    __shared__ float smean[256], sa[256];
    int t = threadIdx.x;
    {
        float s = 0.f, ss = 0.f;
        for (int b = 0; b < 32; ++b) {
            float v = h[(size_t)b * 256 + t];
            s += v; ss += v * v;
        }
        float mn = s / 32.f;
        float var = ss / 32.f - mn * mn;
        if (var < 0.f) var = 0.f;
        smean[t] = mn;
        sa[t] = rsqrtf(var + 1e-5f) * gam[t]; // fold gamma
    }
    __syncthreads();
    int wid = blockIdx.x * 4 + (t >> 6);
    int lane = t & 63;
    if (wid >= 32 * 40) return;
    int b = wid / 40, o = wid % 40;
    float acc = 0.f;
#pragma unroll
    for (int kk = 0; kk < 4; ++kk) {
        int c = lane + kk * 64;
        float v = fmaxf((h[b * 256 + c] - smean[c]) * sa[c] + beta[c], 0.f);
        acc += v * w2[o * 256 + c];
    }
#pragma unroll
    for (int off = 32; off > 0; off >>= 1) acc += __shfl_xor(acc, off, 64);
    if (lane == 0) out[wid] = acc + b2[o];
}

extern "C" void kernel_launch(void* const* d_in, const int* in_sizes, int n_in,
                              void* d_out, int out_size, void* d_ws, size_t ws_size,
                              hipStream_t stream) {
    const float* vertices = (const float*)d_in[0];
    const float* c0_dir = (const float*)d_in[1];
    const float* c1_w  = (const float*)d_in[2];
    const float* c1_b  = (const float*)d_in[3];
    const float* c1_dir = (const float*)d_in[4];
    const float* d1_w  = (const float*)d_in[5];
    const float* c2_w  = (const float*)d_in[6];
    const float* c2_b  = (const float*)d_in[7];
    const float* c2_dir = (const float*)d_in[8];
    const float* d2_w  = (const float*)d_in[9];
    const float* c3_w  = (const float*)d_in[10];
    const float* c3_b  = (const float*)d_in[11];
    const float* c3_dir = (const float*)d_in[12];
    const float* d3_w  = (const float*)d_in[13];
    const float* c4_w  = (const float*)d_in[14];
    const float* c4_b  = (const float*)d_in[15];
    const float* c4_dir = (const float*)d_in[16];
    const float* d4_w  = (const float*)d_in[17];
    const float* cls_w1 = (const float*)d_in[18];
    const float* cls_b1 = (const float*)d_in[19];
    const float* cls_g  = (const float*)d_in[20];
    const float* cls_beta = (const float*)d_in[21];
    const float* cls_w2 = (const float*)d_in[22];
    const float* cls_b2 = (const float*)d_in[23];

    const int B = 32;
    float* ws = (float*)d_ws;
    size_t off = 0;
    auto alloc = [&](size_t n) { float* p = ws + off; off += n; return p; };
    int*   knn   = (int*)alloc(655360);     // max B*1024*20
    int*   knn4  = (int*)alloc(32768);      // max B*256*4
    float* ndir  = alloc(1966080);          // max B*1024*20*3
    float* fm0   = alloc(1048576);          // B*1024*32
    float* fm1   = alloc(2097152);          // B*1024*64
    float* fm1p  = alloc(524288);           // B*256*64
    float* fm2   = alloc(1048576);          // B*256*128
    float* fm3   = alloc(2097152);          // B*256*256
    float* fm3p  = alloc(524288);           // B*64*256
    float* fout  = alloc(4194304);          // max fout sizes
    float* convp = alloc(2097152);          // pre-BN conv out
    float* gbuf  = alloc(32768);            // B*1024
    float* hbuf  = alloc(8192);             // B*256
    float* d1t   = alloc(2048);             // 32 x 64
    float* d2t   = alloc(8192);             // 64 x 128
    float* d3t   = alloc(32768);            // 128 x 256
    float* d4t   = alloc(262144);           // 256 x 1024
    float* partial = alloc(65536);          // bn partials, max 2*C*nsplit

    // ---- fused weight transposes ----
    transpose_all_kernel<<<nblk(2048 + 8192 + 32768 + 262144), TPB, 0, stream>>>(
        d1_w, d2_w, d3_w, d4_w, d1t, d2t, d3t, d4t);

    // ---- stage 1 (V=1024) ----
    knn_radix_kernel<20, 16, true, true, 4><<<dim3(128, B), KNN_TPB, 0, stream>>>(
        vertices, knn, ndir, 1024, c0_dir, fm0, 256, knn4);
    gemm64_kernel<0><<<dim3(2, 512), TPB, 0, stream>>>(fm0, c1_w, c1_b, nullptr, nullptr, fout, B * 1024, 128, 32, 0);
    conv_act_kernel<<<nblk((long)B * 1024 * 16), TPB, 0, stream>>>(ndir, knn, fout, c1_dir, convp, B, 1024, 20, 64);
    bn_partial_kernel<<<nblk(64 * 256), TPB, 0, stream>>>(convp, partial, B * 1024, 64, 256);
    gemm64_kernel<1><<<dim3(1, 512), TPB, 0, stream>>>(fm0, d1t, nullptr, convp, partial, fm1, B * 1024, 64, 32, 256);
    // pool 1024 -> 256 (indices precomputed in stage-1 knn)
    pool_max_kernel<<<nblk((long)B * 256 * 64), TPB, 0, stream>>>(fm1, knn4, fm1p, B, 1024, 256, 64);

    // ---- stage 2 (V=256) ----
    knn_radix_kernel<20, 4, true, false, 4><<<dim3(32, B), KNN_TPB, 0, stream>>>(
        vertices, knn, ndir, 256, nullptr, nullptr, 64, knn4);
    gemm64_kernel<0><<<dim3(4, 128), TPB, 0, stream>>>(fm1p, c2_w, c2_b, nullptr, nullptr, fout, B * 256, 256, 64, 0);
    conv_act_kernel<<<nblk((long)B * 256 * 32), TPB, 0, stream>>>(ndir, knn, fout, c2_dir, convp, B, 256, 20, 128);
    bn_partial_kernel<<<nblk(128 * 128), TPB, 0, stream>>>(convp, partial, B * 256, 128, 128);
    gemm64_kernel<1><<<dim3(2, 128), TPB, 0, stream>>>(fm1p, d2t, nullptr, convp, partial, fm2, B * 256, 128, 64, 128);
    gemm64_kernel<0><<<dim3(8, 128), TPB, 0, stream>>>(fm2, c3_w, c3_b, nullptr, nullptr, fout, B * 256, 512, 128, 0);
    conv_act_kernel<<<nblk((long)B * 256 * 64), TPB, 0, stream>>>(ndir, knn, fout, c3_dir, convp, B, 256, 20, 256);
    bn_partial_kernel<<<nblk(256 * 128), TPB, 0, stream>>>(convp, partial, B * 256, 256, 128);
    gemm64_kernel<1><<<dim3(4, 128), TPB, 0, stream>>>(fm2, d3t, nullptr, convp, partial, fm3, B * 256, 256, 128, 128);
    // pool 256 -> 64 (indices precomputed in stage-2 knn)
    pool_max_kernel<<<nblk((long)B * 64 * 256), TPB, 0, stream>>>(fm3, knn4, fm3p, B, 256, 64, 256);

    // ---- stage 3 (V=64) ----
    knn_radix_kernel<20, 1, true, false, 0><<<dim3(8, B), KNN_TPB, 0, stream>>>(
        vertices, knn, ndir, 64, nullptr, nullptr, 0, nullptr);
    gemm64_kernel<0><<<dim3(32, 32), TPB, 0, stream>>>(fm3p, c4_w, c4_b, nullptr, nullptr, fout, B * 64, 2048, 256, 0);
    conv_act_kernel<<<nblk((long)B * 64 * 256), TPB, 0, stream>>>(ndir, knn, fout, c4_dir, convp, B, 64, 20, 1024);
    bn_partial_kernel<<<nblk(1024 * 32), TPB, 0, stream>>>(convp, partial, B * 64, 1024, 32);
    // MODE 2: BN+residual GEMM fused with per-batch column max -> gbuf (no fm4)
    gemm64_kernel<2><<<dim3(16, 32), TPB, 0, stream>>>(fm3p, d4t, nullptr, convp, partial, gbuf, B * 64, 1024, 256, 32);

    // ---- classifier ----
    gemm_t_wave_kernel<<<nblk((long)32 * 256 * 64), TPB, 0, stream>>>(gbuf, cls_w1, cls_b1, hbuf, 32, 1024, 256);
    cls_fused_kernel<<<320, TPB, 0, stream>>>(hbuf, cls_g, cls_beta, cls_w2, cls_b2, (float*)d_out);
}

// Round 14
// 387.587 us; speedup vs baseline: 2.0927x; 1.0144x over previous
//
#include <hip/hip_runtime.h>

#define TPB 256
#define KNN_TPB 512
static inline int nblk(long n) { return (int)((n + TPB - 1) / TPB); }

#define FINF 3.402823466e38f

// ---------------- KNN body: radix-select + fused epilogues (K=20 fixed) ----------------
// Exact 20 smallest (excluding self) via bisection on float bit patterns.
// NS>=8: ballot-compact candidates <= M (group-min bound) into 256 LDS slots
// so bisection ballots 4 regs, not NS. Overflow falls back to full width.
// WDIR: write normalized neighbor dirs. CSURF: conv_surface fm0 fused.
// K2>0: vertices i<V2 emit K2-NN indices for pooling via shfl rank.
template <int NS, bool WDIR, bool CSURF, int K2>
__device__ __forceinline__ void knn_body(int bx, int b, const float* __restrict__ vin,
                                         int* __restrict__ knn, float* __restrict__ ndir,
                                         int V_out, const float* __restrict__ c0dir,
                                         float* __restrict__ fm0, int V2, int* __restrict__ knn4,
                                         float4* pts, int (*sidx)[20], float (*sdir)[20][3],
                                         unsigned (*cdist)[256], unsigned short (*cidx)[256]) {
    constexpr int K = 20;
    constexpr int VF = NS * 64;
    const float* vb = vin + (size_t)b * 3072; // (3, 1024) layout
    for (int j = threadIdx.x; j < VF; j += blockDim.x) {
        float x = vb[j], y = vb[1024 + j], z = vb[2048 + j];
        pts[j] = make_float4(x, y, z, x * x + y * y + z * z);
    }
    __syncthreads();
    int lane = threadIdx.x & 63;
    int w = threadIdx.x >> 6;
    int i = bx * 8 + w;
    if (i >= V_out) return;
    float4 pi = pts[i];
    unsigned ud[NS];
    unsigned lmin = 0xFFFFFFFFu;
#pragma unroll
    for (int s = 0; s < NS; ++s) {
        int j = s * 64 + lane;
        float4 pj = pts[j];
        float dist = pi.w + pj.w - 2.f * (pi.x * pj.x + pi.y * pj.y + pi.z * pj.z);
        dist = fmaxf(dist, 0.f); // keep bit-monotone
        unsigned v = (j == i) ? 0xFFFFFFFFu : __float_as_uint(dist);
        ud[s] = v;
        lmin = v < lmin ? v : lmin;
    }
    // pair-min upper bound: 32 disjoint lane-pair mins are real candidates => count(<=M) >= 32 >= K
    unsigned pmin = lmin;
    {
        unsigned o = (unsigned)__shfl_xor((int)pmin, 1, 64);
        pmin = o < pmin ? o : pmin;
    }
    unsigned gmin = lmin, M = pmin;
#pragma unroll
    for (int off = 32; off > 1; off >>= 1) {
        unsigned on = (unsigned)__shfl_xor((int)gmin, off, 64);
        gmin = on < gmin ? on : gmin;
        unsigned om = (unsigned)__shfl_xor((int)M, off, 64);
        M = om > M ? om : M;
    }
    {
        unsigned on = (unsigned)__shfl_xor((int)gmin, 1, 64);
        gmin = on < gmin ? on : gmin;
    }
    int* orow = knn + ((size_t)(b * V_out + i)) * K;
    unsigned long long lmask = (1ull << lane) - 1ull;
    bool done = false;
    if constexpr (NS >= 8) {
        int cnt = 0;
#pragma unroll
        for (int s = 0; s < NS; ++s) {
            unsigned long long mm = __ballot(ud[s] <= M);
            if (ud[s] <= M) {
                int p = cnt + __popcll(mm & lmask);
                if (p < 256) { cdist[w][p] = ud[s]; cidx[w][p] = (unsigned short)(s * 64 + lane); }
            }
            cnt += __popcll(mm);
        }
        if (cnt <= 256) {
            unsigned cd[4];
#pragma unroll
            for (int r = 0; r < 4; ++r) {
                int p = lane + r * 64;
                cd[r] = p < cnt ? cdist[w][p] : 0xFFFFFFFFu;
            }
            unsigned lo = gmin, hi = M + 1u;
            while (hi - lo > 1u) {
                unsigned mid = lo + ((hi - lo) >> 1);
                int c = 0;
#pragma unroll
                for (int r = 0; r < 4; ++r)
                    c += __popcll(__ballot(cd[r] < mid));
                if (c >= K) hi = mid; else lo = mid;
            }
            unsigned T = lo;
            int base = 0;
#pragma unroll
            for (int r = 0; r < 4; ++r) {
                unsigned long long mm = __ballot(cd[r] < T);
                if (cd[r] < T) {
                    int p = base + __popcll(mm & lmask);
                    int j = cidx[w][lane + r * 64];
                    sidx[w][p] = j; orow[p] = j;
                }
                base += __popcll(mm);
            }
            int need = K - base, run = 0;
#pragma unroll
            for (int r = 0; r < 4; ++r) {
                unsigned long long mm = __ballot(cd[r] == T);
                int rr = run + __popcll(mm & lmask);
                if (cd[r] == T && rr < need) {
                    int j = cidx[w][lane + r * 64];
                    sidx[w][base + rr] = j; orow[base + rr] = j;
                }
                run += __popcll(mm);
            }
            done = true;
        }
    }
    if (!done) { // full-width (NS<8 or rare overflow)
        unsigned lo = gmin, hi = M + 1u;
        while (hi - lo > 1u) {
            unsigned mid = lo + ((hi - lo) >> 1);
            int cnt = 0;
#pragma unroll
            for (int s = 0; s < NS; ++s)
                cnt += __popcll(__ballot(ud[s] < mid));
            if (cnt >= K) hi = mid; else lo = mid;
        }
        unsigned T = lo;
        int base = 0;
#pragma unroll
        for (int s = 0; s < NS; ++s) {
            unsigned long long m = __ballot(ud[s] < T);
            if (ud[s] < T) {
                int p = base + __popcll(m & lmask);
                sidx[w][p] = s * 64 + lane;
                orow[p] = s * 64 + lane;
            }
            base += __popcll(m);
        }
        int need = K - base, run = 0;
#pragma unroll
        for (int s = 0; s < NS; ++s) {
            unsigned long long m = __ballot(ud[s] == T);
            int r = run + __popcll(m & lmask);
            if (ud[s] == T && r < need) {
                sidx[w][base + r] = s * 64 + lane;
                orow[base + r] = s * 64 + lane;
            }
            run += __popcll(m);
        }
    }
    // --- epilogues (wave-synchronous LDS reads) ---
    if (WDIR) {
        if (lane < K) {
            int j = sidx[w][lane];
            float4 pj = pts[j];
            float dx = pj.x - pi.x, dy = pj.y - pi.y, dz = pj.z - pi.z;
            float inv = 1.f / fmaxf(sqrtf(dx * dx + dy * dy + dz * dz), 1e-12f);
            float* o = ndir + ((size_t)(b * V_out + i) * K + lane) * 3;
            float nx = dx * inv, ny = dy * inv, nz = dz * inv;
            o[0] = nx; o[1] = ny; o[2] = nz;
            if (CSURF) { sdir[w][lane][0] = nx; sdir[w][lane][1] = ny; sdir[w][lane][2] = nz; }
        }
        if (CSURF && lane < 32) {
            int c = lane;
            float d0 = c0dir[c], d1 = c0dir[32 + c], d2 = c0dir[64 + c];
            float inv = 1.f / fmaxf(sqrtf(d0 * d0 + d1 * d1 + d2 * d2), 1e-12f);
            d0 *= inv; d1 *= inv; d2 *= inv;
            float m = 0.f;
            for (int n = 0; n < K; ++n) {
                float th = sdir[w][n][0] * d0 + sdir[w][n][1] * d1 + sdir[w][n][2] * d2;
                m = fmaxf(m, th);
            }
            fm0[(size_t)(b * V_out + i) * 32 + c] = m;
        }
    }
    if (K2 > 0 && i < V2) {
        float dsel = FINF;
        int jsel = 0x7FFFFFFF;
        if (lane < K) {
            jsel = sidx[w][lane];
            float4 pj = pts[jsel];
            dsel = fmaxf(pi.w + pj.w - 2.f * (pi.x * pj.x + pi.y * pj.y + pi.z * pj.z), 0.f);
        }
        int rank = 0;
        for (int m = 0; m < K; ++m) {
            float dm = __shfl(dsel, m, 64);
            int jm = __shfl(jsel, m, 64);
            rank += (dm < dsel || (dm == dsel && jm < jsel)) ? 1 : 0;
        }
        if (lane < K && rank < K2) knn4[((size_t)(b * V2 + i)) * K2 + rank] = jsel;
    }
}

// ---------------- prep: ALL knn stages + all weight transposes in one launch ----------------
// All depend only on kernel inputs -> run concurrently (fills the machine during
// knn1; removes 3 launch gaps). Block ranges: [0,128) knn1, [128,160) knn2,
// [160,168) knn3, [168,764) transposes (y==0 only).
__global__ __launch_bounds__(KNN_TPB, 1) void prep_kernel(const float* __restrict__ vin, const float* __restrict__ c0dir,
                                                          int* __restrict__ knn1, float* __restrict__ ndir1,
                                                          float* __restrict__ fm0, int* __restrict__ knn4_1,
                                                          int* __restrict__ knn2, float* __restrict__ ndir2,
                                                          int* __restrict__ knn4_2,
                                                          int* __restrict__ knn3, float* __restrict__ ndir3,
                                                          const float* __restrict__ d1, const float* __restrict__ d2,
                                                          const float* __restrict__ d3, const float* __restrict__ d4,
                                                          float* __restrict__ o1, float* __restrict__ o2,
                                                          float* __restrict__ o3, float* __restrict__ o4) {
    __shared__ float4 pts[1024];
    __shared__ int sidx[8][20];
    __shared__ float sdir[8][20][3];
    __shared__ unsigned cdist[8][256];
    __shared__ unsigned short cidx[8][256];
    int bx = blockIdx.x, b = blockIdx.y;
    if (bx < 128) {
        knn_body<16, true, true, 4>(bx, b, vin, knn1, ndir1, 1024, c0dir, fm0, 256, knn4_1,
                                    pts, sidx, sdir, cdist, cidx);
        return;
    }
    if (bx < 160) {
        knn_body<4, true, false, 4>(bx - 128, b, vin, knn2, ndir2, 256, nullptr, nullptr, 64, knn4_2,
                                    pts, sidx, sdir, cdist, cidx);
        return;
    }
    if (bx < 168) {
        knn_body<1, true, false, 0>(bx - 160, b, vin, knn3, ndir3, 64, nullptr, nullptr, 0, nullptr,
                                    pts, sidx, sdir, cdist, cidx);
        return;
    }
    if (b != 0) return;
    int t = (bx - 168) * KNN_TPB + threadIdx.x;
    if (t < 2048) { int r = t / 32, c = t % 32; o1[c * 64 + r] = d1[t]; return; }
    int t2 = t - 2048;
    if (t2 < 8192) { int r = t2 / 64, c = t2 % 64; o2[c * 128 + r] = d2[t2]; return; }
    int t3 = t2 - 8192;
    if (t3 < 32768) { int r = t3 / 128, c = t3 % 128; o3[c * 256 + r] = d3[t3]; return; }
    int t4 = t3 - 32768;
    if (t4 < 262144) { int r = t4 / 256, c = t4 % 256; o4[c * 1024 + r] = d4[t4]; }
}

// ---------------- LDS-tiled GEMM 64x64, BK=32 ----------------
// MODE 0: out = A@W + bias.  MODE 1: bnrelu(conv) + A@W (BN finalized in-kernel,
// parallel over all 256 threads).  MODE 2: MODE 1 + per-batch column-max -> gbuf.
template <int MODE>
__global__ __launch_bounds__(TPB) void gemm64_kernel(const float* __restrict__ A, const float* __restrict__ W,
                                                     const float* __restrict__ bias,
                                                     const float* __restrict__ conv, const float* __restrict__ partial,
                                                     float* __restrict__ out, int M, int N, int K, int nsplit) {
    __shared__ float As[64][36];
    __shared__ float Bs[32][68];
    __shared__ float smean[64], sinv[64];
    int t = threadIdx.x;
    int tx = t & 15, ty = t >> 4;
    int colbase = blockIdx.x * 64, rowbase = blockIdx.y * 64;
    int r0 = ty * 4, c0 = tx * 4;
    if constexpr (MODE >= 1) {
        __shared__ double sred[2][4][64];
        int cc = t & 63, g = t >> 6;
        double s = 0.0, ss = 0.0;
        for (int sp = g; sp < nsplit; sp += 4) {
            s += partial[(size_t)sp * 2 * N + colbase + cc];
            ss += partial[(size_t)sp * 2 * N + N + colbase + cc];
        }
        sred[0][g][cc] = s; sred[1][g][cc] = ss;
        __syncthreads();
        if (t < 64) {
            double S = sred[0][0][t] + sred[0][1][t] + sred[0][2][t] + sred[0][3][t];
            double SS = sred[1][0][t] + sred[1][1][t] + sred[1][2][t] + sred[1][3][t];
            double mean = S / M;
            double var = SS / M - mean * mean;
            if (var < 0) var = 0;
            smean[t] = (float)mean;
            sinv[t] = rsqrtf((float)var + 1e-5f);
        }
        __syncthreads();
    }
    float4 acc0, acc1, acc2, acc3;
    if (MODE == 0) {
        float4 bv = *(const float4*)(bias + colbase + c0);
        acc0 = bv; acc1 = bv; acc2 = bv; acc3 = bv;
    } else {
        acc0 = make_float4(0.f, 0.f, 0.f, 0.f); acc1 = acc0; acc2 = acc0; acc3 = acc0;
    }
    for (int kt = 0; kt < K; kt += 32) {
#pragma unroll
        for (int l = 0; l < 2; ++l) {
            int lin = t + l * 256;
            int ar = lin >> 3, ak = (lin & 7) << 2;
            *(float4*)&As[ar][ak] = *(const float4*)(A + (size_t)(rowbase + ar) * K + kt + ak);
            int br = lin >> 4, bn = (lin & 15) << 2;
            *(float4*)&Bs[br][bn] = *(const float4*)(W + (size_t)(kt + br) * N + colbase + bn);
        }
        __syncthreads();
#pragma unroll 4
        for (int k = 0; k < 32; ++k) {
            float4 bv = *(const float4*)&Bs[k][c0];
            float a0 = As[r0][k], a1 = As[r0 + 1][k], a2 = As[r0 + 2][k], a3 = As[r0 + 3][k];
            acc0.x += a0 * bv.x; acc0.y += a0 * bv.y; acc0.z += a0 * bv.z; acc0.w += a0 * bv.w;
            acc1.x += a1 * bv.x; acc1.y += a1 * bv.y; acc1.z += a1 * bv.z; acc1.w += a1 * bv.w;
            acc2.x += a2 * bv.x; acc2.y += a2 * bv.y; acc2.z += a2 * bv.z; acc2.w += a2 * bv.w;
            acc3.x += a3 * bv.x; acc3.y += a3 * bv.y; acc3.z += a3 * bv.z; acc3.w += a3 * bv.w;
        }
        __syncthreads();
    }
    float4 accs[4] = {acc0, acc1, acc2, acc3};
    if constexpr (MODE >= 1) {
        float4 mean = *(const float4*)&smean[c0];
        float4 inv = *(const float4*)&sinv[c0];
#pragma unroll
        for (int rr = 0; rr < 4; ++rr) {
            float4 cv = *(const float4*)(conv + (size_t)(rowbase + r0 + rr) * N + colbase + c0);
            accs[rr].x += fmaxf((cv.x - mean.x) * inv.x, 0.f);
            accs[rr].y += fmaxf((cv.y - mean.y) * inv.y, 0.f);
            accs[rr].z += fmaxf((cv.z - mean.z) * inv.z, 0.f);
            accs[rr].w += fmaxf((cv.w - mean.w) * inv.w, 0.f);
        }
    }
    if constexpr (MODE == 2) {
        __shared__ float redmax[16][68];
        float4 tm;
        tm.x = fmaxf(fmaxf(accs[0].x, accs[1].x), fmaxf(accs[2].x, accs[3].x));
        tm.y = fmaxf(fmaxf(accs[0].y, accs[1].y), fmaxf(accs[2].y, accs[3].y));
        tm.z = fmaxf(fmaxf(accs[0].z, accs[1].z), fmaxf(accs[2].z, accs[3].z));
        tm.w = fmaxf(fmaxf(accs[0].w, accs[1].w), fmaxf(accs[2].w, accs[3].w));
        *(float4*)&redmax[ty][c0] = tm;
        __syncthreads();
        if (t < 64) {
            float m = redmax[0][t];
#pragma unroll
            for (int g = 1; g < 16; ++g) m = fmaxf(m, redmax[g][t]);
            out[(size_t)blockIdx.y * N + colbase + t] = m;
        }
    } else {
#pragma unroll
        for (int rr = 0; rr < 4; ++rr)
            *(float4*)(out + (size_t)(rowbase + r0 + rr) * N + colbase + c0) = accs[rr];
    }
}

// ---------------- conv_layer: center + max_n(theta * support), 4 ch/thread ----------------
__global__ __launch_bounds__(TPB) void conv_act_kernel(const float* __restrict__ ndir, const int* __restrict__ knn,
                                const float* __restrict__ fout, const float* __restrict__ dir,
                                float* __restrict__ out, int B, int Vst, int K, int Cout) {
    int t = blockIdx.x * blockDim.x + threadIdx.x;
    int nc4 = Cout >> 2;
    if (t >= B * Vst * nc4) return;
    int row = t / nc4, c4 = (t % nc4) * 4;
    int b = row / Vst;
    float4 D0 = *(const float4*)(dir + c4);
    float4 D1 = *(const float4*)(dir + Cout + c4);
    float4 D2 = *(const float4*)(dir + 2 * Cout + c4);
    float4 e0, e1, e2;
    {
        float i0 = 1.f / fmaxf(sqrtf(D0.x * D0.x + D1.x * D1.x + D2.x * D2.x), 1e-12f);
        float i1 = 1.f / fmaxf(sqrtf(D0.y * D0.y + D1.y * D1.y + D2.y * D2.y), 1e-12f);
        float i2 = 1.f / fmaxf(sqrtf(D0.z * D0.z + D1.z * D1.z + D2.z * D2.z), 1e-12f);
        float i3 = 1.f / fmaxf(sqrtf(D0.w * D0.w + D1.w * D1.w + D2.w * D2.w), 1e-12f);
        e0 = make_float4(D0.x * i0, D0.y * i1, D0.z * i2, D0.w * i3);
        e1 = make_float4(D1.x * i0, D1.y * i1, D1.z * i2, D1.w * i3);
        e2 = make_float4(D2.x * i0, D2.y * i1, D2.z * i2, D2.w * i3);
    }
    int Cw = 2 * Cout;
    float4 m = make_float4(-FINF, -FINF, -FINF, -FINF);
    const float* nd = ndir + (size_t)row * K * 3;
    const int* kr = knn + (size_t)row * K;
    for (int n = 0; n < K; ++n) {
        int j = kr[n];
        float n0 = nd[n * 3], n1 = nd[n * 3 + 1], n2 = nd[n * 3 + 2];
        float4 s = *(const float4*)(fout + ((size_t)(b * Vst + j)) * Cw + Cout + c4);
        float t0 = fmaxf(n0 * e0.x + n1 * e1.x + n2 * e2.x, 0.f);
        float t1 = fmaxf(n0 * e0.y + n1 * e1.y + n2 * e2.y, 0.f);
        float t2 = fmaxf(n0 * e0.z + n1 * e1.z + n2 * e2.z, 0.f);
        float t3 = fmaxf(n0 * e0.w + n1 * e1.w + n2 * e2.w, 0.f);
        m.x = fmaxf(m.x, t0 * s.x);
        m.y = fmaxf(m.y, t1 * s.y);
        m.z = fmaxf(m.z, t2 * s.z);
        m.w = fmaxf(m.w, t3 * s.w);
    }
    float4 ctr = *(const float4*)(fout + (size_t)row * Cw + c4);
    *(float4*)(out + (size_t)row * Cout + c4) = make_float4(ctr.x + m.x, ctr.y + m.y, ctr.z + m.z, ctr.w + m.w);
}

// ---------------- BN stats pass 1: coalesced float partials ----------------
__global__ __launch_bounds__(TPB) void bn_partial_kernel(const float* __restrict__ x, float* __restrict__ partial,
                                                         int rows, int C, int nsplit) {
    int t = blockIdx.x * blockDim.x + threadIdx.x;
    if (t >= C * nsplit) return;
    int c = t % C, sp = t / C;
    int chunk = rows / nsplit;
    int r0 = sp * chunk;
    float s = 0.f, ss = 0.f;
    for (int r = r0; r < r0 + chunk; ++r) {
        float v = x[(size_t)r * C + c];
        s += v; ss += v * v;
    }
    partial[(size_t)sp * 2 * C + c] = s;
    partial[(size_t)sp * 2 * C + C + c] = ss;
}

// ---------------- pool: max over 4 NN features ----------------
__global__ __launch_bounds__(TPB) void pool_max_kernel(const float* __restrict__ fm, const int* __restrict__ knn4,
                                float* __restrict__ out, int B, int Vin, int pn, int C) {
    int t = blockIdx.x * blockDim.x + threadIdx.x;
    if (t >= B * pn * C) return;
    int row = t / C, c = t % C;
    int b = row / pn;
    const int* kr = knn4 + (size_t)row * 4;
    float m = fmaxf(fmaxf(fm[((size_t)(b * Vin + kr[0])) * C + c], fm[((size_t)(b * Vin + kr[1])) * C + c]),
                    fmaxf(fm[((size_t)(b * Vin + kr[2])) * C + c], fm[((size_t)(b * Vin + kr[3])) * C + c]));
    out[t] = m;
}

// ---------------- wave-per-output: out[r,c] = in[r,:]@w[c,:] + bias[c] ----------------
__global__ __launch_bounds__(TPB, 1) void gemm_t_wave_kernel(const float* __restrict__ in, const float* __restrict__ w,
                                   const float* __restrict__ bias, float* __restrict__ out,
                                   int rows, int Cin, int Cout) {
    int wid = (blockIdx.x * blockDim.x + threadIdx.x) >> 6;
    int lane = threadIdx.x & 63;
    if (wid >= rows * Cout) return;
    int r = wid / Cout, c = wid % Cout;
    const float4* a = (const float4*)(in + (size_t)r * Cin);
    const float4* wr = (const float4*)(w + (size_t)c * Cin);
    int n4 = Cin >> 2;
    float acc = 0.f;
    for (int k = lane; k < n4; k += 64) {
        float4 av = a[k], wv = wr[k];
        acc += av.x * wv.x + av.y * wv.y + av.z * wv.z + av.w * wv.w;
    }
#pragma unroll
    for (int off = 32; off > 0; off >>= 1) acc += __shfl_xor(acc, off, 64);
    if (lane == 0) out[wid] = acc + bias[c];
}

// ---------------- fused classifier tail ----------------
__global__ __launch_bounds__(TPB, 1) void cls_fused_kernel(const float* __restrict__ h,
                                 const float* __restrict__ gam, const float* __restrict__ beta,
                                 const float* __restrict__ w2, const float* __restrict__ b2,
                                 float* __restrict__ out) {
    __shared__ float smean[256], sa[256];
    int t = threadIdx.x;
    {
        float s = 0.f, ss = 0.f;
        for (int b = 0; b < 32; ++b) {
            float v = h[(size_t)b * 256 + t];
            s += v; ss += v * v;
        }
        float mn = s / 32.f;
        float var = ss / 32.f - mn * mn;
        if (var < 0.f) var = 0.f;
        smean[t] = mn;
        sa[t] = rsqrtf(var + 1e-5f) * gam[t];
    }
    __syncthreads();
    int wid = blockIdx.x * 4 + (t >> 6);
    int lane = t & 63;
    if (wid >= 32 * 40) return;
    int b = wid / 40, o = wid % 40;
    float acc = 0.f;
#pragma unroll
    for (int kk = 0; kk < 4; ++kk) {
        int c = lane + kk * 64;
        float v = fmaxf((h[b * 256 + c] - smean[c]) * sa[c] + beta[c], 0.f);
        acc += v * w2[o * 256 + c];
    }
#pragma unroll
    for (int off = 32; off > 0; off >>= 1) acc += __shfl_xor(acc, off, 64);
    if (lane == 0) out[wid] = acc + b2[o];
}

extern "C" void kernel_launch(void* const* d_in, const int* in_sizes, int n_in,
                              void* d_out, int out_size, void* d_ws, size_t ws_size,
                              hipStream_t stream) {
    const float* vertices = (const float*)d_in[0];
    const float* c0_dir = (const float*)d_in[1];
    const float* c1_w  = (const float*)d_in[2];
    const float* c1_b  = (const float*)d_in[3];
    const float* c1_dir = (const float*)d_in[4];
    const float* d1_w  = (const float*)d_in[5];
    const float* c2_w  = (const float*)d_in[6];
    const float* c2_b  = (const float*)d_in[7];
    const float* c2_dir = (const float*)d_in[8];
    const float* d2_w  = (const float*)d_in[9];
    const float* c3_w  = (const float*)d_in[10];
    const float* c3_b  = (const float*)d_in[11];
    const float* c3_dir = (const float*)d_in[12];
    const float* d3_w  = (const float*)d_in[13];
    const float* c4_w  = (const float*)d_in[14];
    const float* c4_b  = (const float*)d_in[15];
    const float* c4_dir = (const float*)d_in[16];
    const float* d4_w  = (const float*)d_in[17];
    const float* cls_w1 = (const float*)d_in[18];
    const float* cls_b1 = (const float*)d_in[19];
    const float* cls_g  = (const float*)d_in[20];
    const float* cls_beta = (const float*)d_in[21];
    const float* cls_w2 = (const float*)d_in[22];
    const float* cls_b2 = (const float*)d_in[23];

    const int B = 32;
    float* ws = (float*)d_ws;
    size_t off = 0;
    auto alloc = [&](size_t n) { float* p = ws + off; off += n; return p; };
    int*   knn1  = (int*)alloc(655360);     // B*1024*20
    int*   knn2  = (int*)alloc(163840);     // B*256*20
    int*   knn3  = (int*)alloc(40960);      // B*64*20
    int*   knn4_1 = (int*)alloc(32768);     // B*256*4
    int*   knn4_2 = (int*)alloc(8192);      // B*64*4
    float* ndir1 = alloc(1966080);          // B*1024*20*3
    float* ndir2 = alloc(491520);           // B*256*20*3
    float* ndir3 = alloc(122880);           // B*64*20*3
    float* fm0   = alloc(1048576);          // B*1024*32
    float* fm1   = alloc(2097152);          // B*1024*64
    float* fm1p  = alloc(524288);           // B*256*64
    float* fm2   = alloc(1048576);          // B*256*128
    float* fm3   = alloc(2097152);          // B*256*256
    float* fm3p  = alloc(524288);           // B*64*256
    float* fout  = alloc(4194304);          // max fout sizes
    float* convp = alloc(2097152);          // pre-BN conv out
    float* gbuf  = alloc(32768);            // B*1024
    float* hbuf  = alloc(8192);             // B*256
    float* d1t   = alloc(2048);             // 32 x 64
    float* d2t   = alloc(8192);             // 64 x 128
    float* d3t   = alloc(32768);            // 128 x 256
    float* d4t   = alloc(262144);           // 256 x 1024
    float* partial = alloc(131072);         // bn partials, max 2*C*nsplit

    // ---- prep: all knn stages + all transposes, one launch ----
    prep_kernel<<<dim3(764, B), KNN_TPB, 0, stream>>>(
        vertices, c0_dir, knn1, ndir1, fm0, knn4_1, knn2, ndir2, knn4_2, knn3, ndir3,
        d1_w, d2_w, d3_w, d4_w, d1t, d2t, d3t, d4t);

    // ---- stage 1 (V=1024) ----
    gemm64_kernel<0><<<dim3(2, 512), TPB, 0, stream>>>(fm0, c1_w, c1_b, nullptr, nullptr, fout, B * 1024, 128, 32, 0);
    conv_act_kernel<<<nblk((long)B * 1024 * 16), TPB, 0, stream>>>(ndir1, knn1, fout, c1_dir, convp, B, 1024, 20, 64);
    bn_partial_kernel<<<nblk(64 * 512), TPB, 0, stream>>>(convp, partial, B * 1024, 64, 512);
    gemm64_kernel<1><<<dim3(1, 512), TPB, 0, stream>>>(fm0, d1t, nullptr, convp, partial, fm1, B * 1024, 64, 32, 512);
    pool_max_kernel<<<nblk((long)B * 256 * 64), TPB, 0, stream>>>(fm1, knn4_1, fm1p, B, 1024, 256, 64);

    // ---- stage 2 (V=256) ----
    gemm64_kernel<0><<<dim3(4, 128), TPB, 0, stream>>>(fm1p, c2_w, c2_b, nullptr, nullptr, fout, B * 256, 256, 64, 0);
    conv_act_kernel<<<nblk((long)B * 256 * 32), TPB, 0, stream>>>(ndir2, knn2, fout, c2_dir, convp, B, 256, 20, 128);
    bn_partial_kernel<<<nblk(128 * 256), TPB, 0, stream>>>(convp, partial, B * 256, 128, 256);
    gemm64_kernel<1><<<dim3(2, 128), TPB, 0, stream>>>(fm1p, d2t, nullptr, convp, partial, fm2, B * 256, 128, 64, 256);
    gemm64_kernel<0><<<dim3(8, 128), TPB, 0, stream>>>(fm2, c3_w, c3_b, nullptr, nullptr, fout, B * 256, 512, 128, 0);
    conv_act_kernel<<<nblk((long)B * 256 * 64), TPB, 0, stream>>>(ndir2, knn2, fout, c3_dir, convp, B, 256, 20, 256);
    bn_partial_kernel<<<nblk(256 * 128), TPB, 0, stream>>>(convp, partial, B * 256, 256, 128);
    gemm64_kernel<1><<<dim3(4, 128), TPB, 0, stream>>>(fm2, d3t, nullptr, convp, partial, fm3, B * 256, 256, 128, 128);
    pool_max_kernel<<<nblk((long)B * 64 * 256), TPB, 0, stream>>>(fm3, knn4_2, fm3p, B, 256, 64, 256);

    // ---- stage 3 (V=64) ----
    gemm64_kernel<0><<<dim3(32, 32), TPB, 0, stream>>>(fm3p, c4_w, c4_b, nullptr, nullptr, fout, B * 64, 2048, 256, 0);
    conv_act_kernel<<<nblk((long)B * 64 * 256), TPB, 0, stream>>>(ndir3, knn3, fout, c4_dir, convp, B, 64, 20, 1024);
    bn_partial_kernel<<<nblk(1024 * 64), TPB, 0, stream>>>(convp, partial, B * 64, 1024, 64);
    gemm64_kernel<2><<<dim3(16, 32), TPB, 0, stream>>>(fm3p, d4t, nullptr, convp, partial, gbuf, B * 64, 1024, 256, 64);

    // ---- classifier ----
    gemm_t_wave_kernel<<<nblk((long)32 * 256 * 64), TPB, 0, stream>>>(gbuf, cls_w1, cls_b1, hbuf, 32, 1024, 256);
    cls_fused_kernel<<<320, TPB, 0, stream>>>(hbuf, cls_g, cls_beta, cls_w2, cls_b2, (float*)d_out);
}

// Round 15
// 344.334 us; speedup vs baseline: 2.3556x; 1.1256x over previous
//
#include <hip/hip_runtime.h>

#define TPB 256
#define KNN_TPB 512
static inline int nblk(long n) { return (int)((n + TPB - 1) / TPB); }

#define FINF 3.402823466e38f

// ---------------- KNN body: radix-select + fused epilogues (K=20 fixed) ----------------
template <int NS, bool WDIR, bool CSURF, int K2>
__device__ __forceinline__ void knn_body(int bx, int b, const float* __restrict__ vin,
                                         int* __restrict__ knn, float* __restrict__ ndir,
                                         int V_out, const float* __restrict__ c0dir,
                                         float* __restrict__ fm0, int V2, int* __restrict__ knn4,
                                         float4* pts, int (*sidx)[20], float (*sdir)[20][3],
                                         unsigned (*cdist)[256], unsigned short (*cidx)[256]) {
    constexpr int K = 20;
    constexpr int VF = NS * 64;
    const float* vb = vin + (size_t)b * 3072; // (3, 1024) layout
    for (int j = threadIdx.x; j < VF; j += blockDim.x) {
        float x = vb[j], y = vb[1024 + j], z = vb[2048 + j];
        pts[j] = make_float4(x, y, z, x * x + y * y + z * z);
    }
    __syncthreads();
    int lane = threadIdx.x & 63;
    int w = threadIdx.x >> 6;
    int i = bx * 8 + w;
    if (i >= V_out) return;
    float4 pi = pts[i];
    unsigned ud[NS];
    unsigned lmin = 0xFFFFFFFFu;
#pragma unroll
    for (int s = 0; s < NS; ++s) {
        int j = s * 64 + lane;
        float4 pj = pts[j];
        float dist = pi.w + pj.w - 2.f * (pi.x * pj.x + pi.y * pj.y + pi.z * pj.z);
        dist = fmaxf(dist, 0.f); // keep bit-monotone
        unsigned v = (j == i) ? 0xFFFFFFFFu : __float_as_uint(dist);
        ud[s] = v;
        lmin = v < lmin ? v : lmin;
    }
    // pair-min upper bound: 32 disjoint lane-pair mins are real candidates => count(<=M) >= 32 >= K
    unsigned pmin = lmin;
    {
        unsigned o = (unsigned)__shfl_xor((int)pmin, 1, 64);
        pmin = o < pmin ? o : pmin;
    }
    unsigned gmin = lmin, M = pmin;
#pragma unroll
    for (int off = 32; off > 1; off >>= 1) {
        unsigned on = (unsigned)__shfl_xor((int)gmin, off, 64);
        gmin = on < gmin ? on : gmin;
        unsigned om = (unsigned)__shfl_xor((int)M, off, 64);
        M = om > M ? om : M;
    }
    {
        unsigned on = (unsigned)__shfl_xor((int)gmin, 1, 64);
        gmin = on < gmin ? on : gmin;
    }
    int* orow = knn + ((size_t)(b * V_out + i)) * K;
    unsigned long long lmask = (1ull << lane) - 1ull;
    bool done = false;
    if constexpr (NS >= 8) {
        int cnt = 0;
#pragma unroll
        for (int s = 0; s < NS; ++s) {
            unsigned long long mm = __ballot(ud[s] <= M);
            if (ud[s] <= M) {
                int p = cnt + __popcll(mm & lmask);
                if (p < 256) { cdist[w][p] = ud[s]; cidx[w][p] = (unsigned short)(s * 64 + lane); }
            }
            cnt += __popcll(mm);
        }
        if (cnt <= 256) {
            unsigned cd[4];
#pragma unroll
            for (int r = 0; r < 4; ++r) {
                int p = lane + r * 64;
                cd[r] = p < cnt ? cdist[w][p] : 0xFFFFFFFFu;
            }
            unsigned lo = gmin, hi = M + 1u;
            while (hi - lo > 1u) {
                unsigned mid = lo + ((hi - lo) >> 1);
                int c = 0;
#pragma unroll
                for (int r = 0; r < 4; ++r)
                    c += __popcll(__ballot(cd[r] < mid));
                if (c >= K) hi = mid; else lo = mid;
            }
            unsigned T = lo;
            int base = 0;
#pragma unroll
            for (int r = 0; r < 4; ++r) {
                unsigned long long mm = __ballot(cd[r] < T);
                if (cd[r] < T) {
                    int p = base + __popcll(mm & lmask);
                    int j = cidx[w][lane + r * 64];
                    sidx[w][p] = j; orow[p] = j;
                }
                base += __popcll(mm);
            }
            int need = K - base, run = 0;
#pragma unroll
            for (int r = 0; r < 4; ++r) {
                unsigned long long mm = __ballot(cd[r] == T);
                int rr = run + __popcll(mm & lmask);
                if (cd[r] == T && rr < need) {
                    int j = cidx[w][lane + r * 64];
                    sidx[w][base + rr] = j; orow[base + rr] = j;
                }
                run += __popcll(mm);
            }
            done = true;
        }
    }
    if (!done) { // full-width (NS<8 or rare overflow)
        unsigned lo = gmin, hi = M + 1u;
        while (hi - lo > 1u) {
            unsigned mid = lo + ((hi - lo) >> 1);
            int cnt = 0;
#pragma unroll
            for (int s = 0; s < NS; ++s)
                cnt += __popcll(__ballot(ud[s] < mid));
            if (cnt >= K) hi = mid; else lo = mid;
        }
        unsigned T = lo;
        int base = 0;
#pragma unroll
        for (int s = 0; s < NS; ++s) {
            unsigned long long m = __ballot(ud[s] < T);
            if (ud[s] < T) {
                int p = base + __popcll(m & lmask);
                sidx[w][p] = s * 64 + lane;
                orow[p] = s * 64 + lane;
            }
            base += __popcll(m);
        }
        int need = K - base, run = 0;
#pragma unroll
        for (int s = 0; s < NS; ++s) {
            unsigned long long m = __ballot(ud[s] == T);
            int r = run + __popcll(m & lmask);
            if (ud[s] == T && r < need) {
                sidx[w][base + r] = s * 64 + lane;
                orow[base + r] = s * 64 + lane;
            }
            run += __popcll(m);
        }
    }
    // --- epilogues (wave-synchronous LDS reads) ---
    if (WDIR) {
        if (lane < K) {
            int j = sidx[w][lane];
            float4 pj = pts[j];
            float dx = pj.x - pi.x, dy = pj.y - pi.y, dz = pj.z - pi.z;
            float inv = 1.f / fmaxf(sqrtf(dx * dx + dy * dy + dz * dz), 1e-12f);
            float* o = ndir + ((size_t)(b * V_out + i) * K + lane) * 3;
            float nx = dx * inv, ny = dy * inv, nz = dz * inv;
            o[0] = nx; o[1] = ny; o[2] = nz;
            if (CSURF) { sdir[w][lane][0] = nx; sdir[w][lane][1] = ny; sdir[w][lane][2] = nz; }
        }
        if (CSURF && lane < 32) {
            int c = lane;
            float d0 = c0dir[c], d1 = c0dir[32 + c], d2 = c0dir[64 + c];
            float inv = 1.f / fmaxf(sqrtf(d0 * d0 + d1 * d1 + d2 * d2), 1e-12f);
            d0 *= inv; d1 *= inv; d2 *= inv;
            float m = 0.f;
            for (int n = 0; n < K; ++n) {
                float th = sdir[w][n][0] * d0 + sdir[w][n][1] * d1 + sdir[w][n][2] * d2;
                m = fmaxf(m, th);
            }
            fm0[(size_t)(b * V_out + i) * 32 + c] = m;
        }
    }
    if (K2 > 0 && i < V2) {
        float dsel = FINF;
        int jsel = 0x7FFFFFFF;
        if (lane < K) {
            jsel = sidx[w][lane];
            float4 pj = pts[jsel];
            dsel = fmaxf(pi.w + pj.w - 2.f * (pi.x * pj.x + pi.y * pj.y + pi.z * pj.z), 0.f);
        }
        int rank = 0;
        for (int m = 0; m < K; ++m) {
            float dm = __shfl(dsel, m, 64);
            int jm = __shfl(jsel, m, 64);
            rank += (dm < dsel || (dm == dsel && jm < jsel)) ? 1 : 0;
        }
        if (lane < K && rank < K2) knn4[((size_t)(b * V2 + i)) * K2 + rank] = jsel;
    }
}

// ---------------- prep: knn stages + weight transposes + BN-bin zeroing, one launch ----------------
// Block ranges: [0,128) knn1, [128,160) knn2, [160,168) knn3,
// [168,764) transposes (y==0), [764,876) zero BN partial bins (y==0).
__global__ __launch_bounds__(KNN_TPB, 1) void prep_kernel(const float* __restrict__ vin, const float* __restrict__ c0dir,
                                                          int* __restrict__ knn1, float* __restrict__ ndir1,
                                                          float* __restrict__ fm0, int* __restrict__ knn4_1,
                                                          int* __restrict__ knn2, float* __restrict__ ndir2,
                                                          int* __restrict__ knn4_2,
                                                          int* __restrict__ knn3, float* __restrict__ ndir3,
                                                          const float* __restrict__ d1, const float* __restrict__ d2,
                                                          const float* __restrict__ d3, const float* __restrict__ d4,
                                                          float* __restrict__ o1, float* __restrict__ o2,
                                                          float* __restrict__ o3, float* __restrict__ o4,
                                                          float* __restrict__ pz) {
    __shared__ float4 pts[1024];
    __shared__ int sidx[8][20];
    __shared__ float sdir[8][20][3];
    __shared__ unsigned cdist[8][256];
    __shared__ unsigned short cidx[8][256];
    int bx = blockIdx.x, b = blockIdx.y;
    if (bx < 128) {
        knn_body<16, true, true, 4>(bx, b, vin, knn1, ndir1, 1024, c0dir, fm0, 256, knn4_1,
                                    pts, sidx, sdir, cdist, cidx);
        return;
    }
    if (bx < 160) {
        knn_body<4, true, false, 4>(bx - 128, b, vin, knn2, ndir2, 256, nullptr, nullptr, 64, knn4_2,
                                    pts, sidx, sdir, cdist, cidx);
        return;
    }
    if (bx < 168) {
        knn_body<1, true, false, 0>(bx - 160, b, vin, knn3, ndir3, 64, nullptr, nullptr, 0, nullptr,
                                    pts, sidx, sdir, cdist, cidx);
        return;
    }
    if (b != 0) return;
    if (bx < 764) {
        int t = (bx - 168) * KNN_TPB + threadIdx.x;
        if (t < 2048) { int r = t / 32, c = t % 32; o1[c * 64 + r] = d1[t]; return; }
        int t2 = t - 2048;
        if (t2 < 8192) { int r = t2 / 64, c = t2 % 64; o2[c * 128 + r] = d2[t2]; return; }
        int t3 = t2 - 8192;
        if (t3 < 32768) { int r = t3 / 128, c = t3 % 128; o3[c * 256 + r] = d3[t3]; return; }
        int t4 = t3 - 32768;
        if (t4 < 262144) { int r = t4 / 256, c = t4 % 256; o4[c * 1024 + r] = d4[t4]; }
        return;
    }
    int t5 = (bx - 764) * KNN_TPB + threadIdx.x;
    if (t5 < 57344) pz[t5] = 0.f; // BN partial bins for fused conv_act stages
}

// ---------------- LDS-tiled GEMM 64x64, BK=32 ----------------
// MODE 0: out = A@W + bias.  MODE 1: bnrelu(conv) + A@W (BN finalized in-kernel,
// parallel over 256 threads).  MODE 2: MODE 1 + per-batch column-max -> gbuf.
template <int MODE>
__global__ __launch_bounds__(TPB) void gemm64_kernel(const float* __restrict__ A, const float* __restrict__ W,
                                                     const float* __restrict__ bias,
                                                     const float* __restrict__ conv, const float* __restrict__ partial,
                                                     float* __restrict__ out, int M, int N, int K, int nsplit) {
    __shared__ float As[64][36];
    __shared__ float Bs[32][68];
    __shared__ float smean[64], sinv[64];
    int t = threadIdx.x;
    int tx = t & 15, ty = t >> 4;
    int colbase = blockIdx.x * 64, rowbase = blockIdx.y * 64;
    int r0 = ty * 4, c0 = tx * 4;
    if constexpr (MODE >= 1) {
        __shared__ double sred[2][4][64];
        int cc = t & 63, g = t >> 6;
        double s = 0.0, ss = 0.0;
        for (int sp = g; sp < nsplit; sp += 4) {
            s += partial[(size_t)sp * 2 * N + colbase + cc];
            ss += partial[(size_t)sp * 2 * N + N + colbase + cc];
        }
        sred[0][g][cc] = s; sred[1][g][cc] = ss;
        __syncthreads();
        if (t < 64) {
            double S = sred[0][0][t] + sred[0][1][t] + sred[0][2][t] + sred[0][3][t];
            double SS = sred[1][0][t] + sred[1][1][t] + sred[1][2][t] + sred[1][3][t];
            double mean = S / M;
            double var = SS / M - mean * mean;
            if (var < 0) var = 0;
            smean[t] = (float)mean;
            sinv[t] = rsqrtf((float)var + 1e-5f);
        }
        __syncthreads();
    }
    float4 acc0, acc1, acc2, acc3;
    if (MODE == 0) {
        float4 bv = *(const float4*)(bias + colbase + c0);
        acc0 = bv; acc1 = bv; acc2 = bv; acc3 = bv;
    } else {
        acc0 = make_float4(0.f, 0.f, 0.f, 0.f); acc1 = acc0; acc2 = acc0; acc3 = acc0;
    }
    for (int kt = 0; kt < K; kt += 32) {
#pragma unroll
        for (int l = 0; l < 2; ++l) {
            int lin = t + l * 256;
            int ar = lin >> 3, ak = (lin & 7) << 2;
            *(float4*)&As[ar][ak] = *(const float4*)(A + (size_t)(rowbase + ar) * K + kt + ak);
            int br = lin >> 4, bn = (lin & 15) << 2;
            *(float4*)&Bs[br][bn] = *(const float4*)(W + (size_t)(kt + br) * N + colbase + bn);
        }
        __syncthreads();
#pragma unroll 4
        for (int k = 0; k < 32; ++k) {
            float4 bv = *(const float4*)&Bs[k][c0];
            float a0 = As[r0][k], a1 = As[r0 + 1][k], a2 = As[r0 + 2][k], a3 = As[r0 + 3][k];
            acc0.x += a0 * bv.x; acc0.y += a0 * bv.y; acc0.z += a0 * bv.z; acc0.w += a0 * bv.w;
            acc1.x += a1 * bv.x; acc1.y += a1 * bv.y; acc1.z += a1 * bv.z; acc1.w += a1 * bv.w;
            acc2.x += a2 * bv.x; acc2.y += a2 * bv.y; acc2.z += a2 * bv.z; acc2.w += a2 * bv.w;
            acc3.x += a3 * bv.x; acc3.y += a3 * bv.y; acc3.z += a3 * bv.z; acc3.w += a3 * bv.w;
        }
        __syncthreads();
    }
    float4 accs[4] = {acc0, acc1, acc2, acc3};
    if constexpr (MODE >= 1) {
        float4 mean = *(const float4*)&smean[c0];
        float4 inv = *(const float4*)&sinv[c0];
#pragma unroll
        for (int rr = 0; rr < 4; ++rr) {
            float4 cv = *(const float4*)(conv + (size_t)(rowbase + r0 + rr) * N + colbase + c0);
            accs[rr].x += fmaxf((cv.x - mean.x) * inv.x, 0.f);
            accs[rr].y += fmaxf((cv.y - mean.y) * inv.y, 0.f);
            accs[rr].z += fmaxf((cv.z - mean.z) * inv.z, 0.f);
            accs[rr].w += fmaxf((cv.w - mean.w) * inv.w, 0.f);
        }
    }
    if constexpr (MODE == 2) {
        __shared__ float redmax[16][68];
        float4 tm;
        tm.x = fmaxf(fmaxf(accs[0].x, accs[1].x), fmaxf(accs[2].x, accs[3].x));
        tm.y = fmaxf(fmaxf(accs[0].y, accs[1].y), fmaxf(accs[2].y, accs[3].y));
        tm.z = fmaxf(fmaxf(accs[0].z, accs[1].z), fmaxf(accs[2].z, accs[3].z));
        tm.w = fmaxf(fmaxf(accs[0].w, accs[1].w), fmaxf(accs[2].w, accs[3].w));
        *(float4*)&redmax[ty][c0] = tm;
        __syncthreads();
        if (t < 64) {
            float m = redmax[0][t];
#pragma unroll
            for (int g = 1; g < 16; ++g) m = fmaxf(m, redmax[g][t]);
            out[(size_t)blockIdx.y * N + colbase + t] = m;
        }
    } else {
#pragma unroll
        for (int rr = 0; rr < 4; ++rr)
            *(float4*)(out + (size_t)(rowbase + r0 + rr) * N + colbase + c0) = accs[rr];
    }
}

// ---------------- conv_layer: center + max_n(theta * support), 4 ch/thread ----------------
// FUSE: accumulate BN (sum, sumsq) per channel via LDS reduce + 64-bin global
// atomics (replaces the separate bn_partial pass; Cout <= 256, exact grids only).
template <bool FUSE>
__global__ __launch_bounds__(TPB) void conv_act_kernel(const float* __restrict__ ndir, const int* __restrict__ knn,
                                const float* __restrict__ fout, const float* __restrict__ dir,
                                float* __restrict__ out, int B, int Vst, int K, int Cout,
                                float* __restrict__ bnpart) {
    __shared__ float sAcc[2][256];
    int t = blockIdx.x * blockDim.x + threadIdx.x;
    int nc4 = Cout >> 2;
    bool active = t < B * Vst * nc4;
    float4 o = make_float4(0.f, 0.f, 0.f, 0.f);
    int c4 = 0;
    if (active) {
        int row = t / nc4; c4 = (t % nc4) * 4;
        int b = row / Vst;
        float4 D0 = *(const float4*)(dir + c4);
        float4 D1 = *(const float4*)(dir + Cout + c4);
        float4 D2 = *(const float4*)(dir + 2 * Cout + c4);
        float4 e0, e1, e2;
        {
            float i0 = 1.f / fmaxf(sqrtf(D0.x * D0.x + D1.x * D1.x + D2.x * D2.x), 1e-12f);
            float i1 = 1.f / fmaxf(sqrtf(D0.y * D0.y + D1.y * D1.y + D2.y * D2.y), 1e-12f);
            float i2 = 1.f / fmaxf(sqrtf(D0.z * D0.z + D1.z * D1.z + D2.z * D2.z), 1e-12f);
            float i3 = 1.f / fmaxf(sqrtf(D0.w * D0.w + D1.w * D1.w + D2.w * D2.w), 1e-12f);
            e0 = make_float4(D0.x * i0, D0.y * i1, D0.z * i2, D0.w * i3);
            e1 = make_float4(D1.x * i0, D1.y * i1, D1.z * i2, D1.w * i3);
            e2 = make_float4(D2.x * i0, D2.y * i1, D2.z * i2, D2.w * i3);
        }
        int Cw = 2 * Cout;
        float4 m = make_float4(-FINF, -FINF, -FINF, -FINF);
        const float* nd = ndir + (size_t)row * K * 3;
        const int* kr = knn + (size_t)row * K;
        for (int n = 0; n < K; ++n) {
            int j = kr[n];
            float n0 = nd[n * 3], n1 = nd[n * 3 + 1], n2 = nd[n * 3 + 2];
            float4 s = *(const float4*)(fout + ((size_t)(b * Vst + j)) * Cw + Cout + c4);
            float t0 = fmaxf(n0 * e0.x + n1 * e1.x + n2 * e2.x, 0.f);
            float t1 = fmaxf(n0 * e0.y + n1 * e1.y + n2 * e2.y, 0.f);
            float t2 = fmaxf(n0 * e0.z + n1 * e1.z + n2 * e2.z, 0.f);
            float t3 = fmaxf(n0 * e0.w + n1 * e1.w + n2 * e2.w, 0.f);
            m.x = fmaxf(m.x, t0 * s.x);
            m.y = fmaxf(m.y, t1 * s.y);
            m.z = fmaxf(m.z, t2 * s.z);
            m.w = fmaxf(m.w, t3 * s.w);
        }
        float4 ctr = *(const float4*)(fout + (size_t)row * Cw + c4);
        o = make_float4(ctr.x + m.x, ctr.y + m.y, ctr.z + m.z, ctr.w + m.w);
        *(float4*)(out + (size_t)row * Cout + c4) = o;
    }
    if constexpr (FUSE) {
        for (int i = threadIdx.x; i < 2 * Cout; i += TPB) ((float*)sAcc)[i < Cout ? i : 256 + (i - Cout)] = 0.f;
        __syncthreads();
        if (active) {
            atomicAdd(&sAcc[0][c4 + 0], o.x); atomicAdd(&sAcc[1][c4 + 0], o.x * o.x);
            atomicAdd(&sAcc[0][c4 + 1], o.y); atomicAdd(&sAcc[1][c4 + 1], o.y * o.y);
            atomicAdd(&sAcc[0][c4 + 2], o.z); atomicAdd(&sAcc[1][c4 + 2], o.z * o.z);
            atomicAdd(&sAcc[0][c4 + 3], o.w); atomicAdd(&sAcc[1][c4 + 3], o.w * o.w);
        }
        __syncthreads();
        int bin = blockIdx.x & 63;
        for (int i = threadIdx.x; i < Cout; i += TPB) {
            atomicAdd(&bnpart[(size_t)bin * 2 * Cout + i], sAcc[0][i]);
            atomicAdd(&bnpart[(size_t)bin * 2 * Cout + Cout + i], sAcc[1][i]);
        }
    }
}

// ---------------- BN stats pass 1 (stage 3 only): coalesced float partials ----------------
__global__ __launch_bounds__(TPB) void bn_partial_kernel(const float* __restrict__ x, float* __restrict__ partial,
                                                         int rows, int C, int nsplit) {
    int t = blockIdx.x * blockDim.x + threadIdx.x;
    if (t >= C * nsplit) return;
    int c = t % C, sp = t / C;
    int chunk = rows / nsplit;
    int r0 = sp * chunk;
    float s = 0.f, ss = 0.f;
    for (int r = r0; r < r0 + chunk; ++r) {
        float v = x[(size_t)r * C + c];
        s += v; ss += v * v;
    }
    partial[(size_t)sp * 2 * C + c] = s;
    partial[(size_t)sp * 2 * C + C + c] = ss;
}

// ---------------- pool: max over 4 NN features ----------------
__global__ __launch_bounds__(TPB) void pool_max_kernel(const float* __restrict__ fm, const int* __restrict__ knn4,
                                float* __restrict__ out, int B, int Vin, int pn, int C) {
    int t = blockIdx.x * blockDim.x + threadIdx.x;
    if (t >= B * pn * C) return;
    int row = t / C, c = t % C;
    int b = row / pn;
    const int* kr = knn4 + (size_t)row * 4;
    float m = fmaxf(fmaxf(fm[((size_t)(b * Vin + kr[0])) * C + c], fm[((size_t)(b * Vin + kr[1])) * C + c]),
                    fmaxf(fm[((size_t)(b * Vin + kr[2])) * C + c], fm[((size_t)(b * Vin + kr[3])) * C + c]));
    out[t] = m;
}

// ---------------- wave-per-output: out[r,c] = in[r,:]@w[c,:] + bias[c] ----------------
__global__ __launch_bounds__(TPB, 1) void gemm_t_wave_kernel(const float* __restrict__ in, const float* __restrict__ w,
                                   const float* __restrict__ bias, float* __restrict__ out,
                                   int rows, int Cin, int Cout) {
    int wid = (blockIdx.x * blockDim.x + threadIdx.x) >> 6;
    int lane = threadIdx.x & 63;
    if (wid >= rows * Cout) return;
    int r = wid / Cout, c = wid % Cout;
    const float4* a = (const float4*)(in + (size_t)r * Cin);
    const float4* wr = (const float4*)(w + (size_t)c * Cin);
    int n4 = Cin >> 2;
    float acc = 0.f;
    for (int k = lane; k < n4; k += 64) {
        float4 av = a[k], wv = wr[k];
        acc += av.x * wv.x + av.y * wv.y + av.z * wv.z + av.w * wv.w;
    }
#pragma unroll
    for (int off = 32; off > 0; off >>= 1) acc += __shfl_xor(acc, off, 64);
    if (lane == 0) out[wid] = acc + bias[c];
}

// ---------------- fused classifier tail ----------------
__global__ __launch_bounds__(TPB, 1) void cls_fused_kernel(const float* __restrict__ h,
                                 const float* __restrict__ gam, const float* __restrict__ beta,
                                 const float* __restrict__ w2, const float* __restrict__ b2,
                                 float* __restrict__ out) {
    __shared__ float smean[256], sa[256];
    int t = threadIdx.x;
    {
        float s = 0.f, ss = 0.f;
        for (int b = 0; b < 32; ++b) {
            float v = h[(size_t)b * 256 + t];
            s += v; ss += v * v;
        }
        float mn = s / 32.f;
        float var = ss / 32.f - mn * mn;
        if (var < 0.f) var = 0.f;
        smean[t] = mn;
        sa[t] = rsqrtf(var + 1e-5f) * gam[t];
    }
    __syncthreads();
    int wid = blockIdx.x * 4 + (t >> 6);
    int lane = t & 63;
    if (wid >= 32 * 40) return;
    int b = wid / 40, o = wid % 40;
    float acc = 0.f;
#pragma unroll
    for (int kk = 0; kk < 4; ++kk) {
        int c = lane + kk * 64;
        float v = fmaxf((h[b * 256 + c] - smean[c]) * sa[c] + beta[c], 0.f);
        acc += v * w2[o * 256 + c];
    }
#pragma unroll
    for (int off = 32; off > 0; off >>= 1) acc += __shfl_xor(acc, off, 64);
    if (lane == 0) out[wid] = acc + b2[o];
}

extern "C" void kernel_launch(void* const* d_in, const int* in_sizes, int n_in,
                              void* d_out, int out_size, void* d_ws, size_t ws_size,
                              hipStream_t stream) {
    const float* vertices = (const float*)d_in[0];
    const float* c0_dir = (const float*)d_in[1];
    const float* c1_w  = (const float*)d_in[2];
    const float* c1_b  = (const float*)d_in[3];
    const float* c1_dir = (const float*)d_in[4];
    const float* d1_w  = (const float*)d_in[5];
    const float* c2_w  = (const float*)d_in[6];
    const float* c2_b  = (const float*)d_in[7];
    const float* c2_dir = (const float*)d_in[8];
    const float* d2_w  = (const float*)d_in[9];
    const float* c3_w  = (const float*)d_in[10];
    const float* c3_b  = (const float*)d_in[11];
    const float* c3_dir = (const float*)d_in[12];
    const float* d3_w  = (const float*)d_in[13];
    const float* c4_w  = (const float*)d_in[14];
    const float* c4_b  = (const float*)d_in[15];
    const float* c4_dir = (const float*)d_in[16];
    const float* d4_w  = (const float*)d_in[17];
    const float* cls_w1 = (const float*)d_in[18];
    const float* cls_b1 = (const float*)d_in[19];
    const float* cls_g  = (const float*)d_in[20];
    const float* cls_beta = (const float*)d_in[21];
    const float* cls_w2 = (const float*)d_in[22];
    const float* cls_b2 = (const float*)d_in[23];

    const int B = 32;
    float* ws = (float*)d_ws;
    size_t off = 0;
    auto alloc = [&](size_t n) { float* p = ws + off; off += n; return p; };
    int*   knn1  = (int*)alloc(655360);     // B*1024*20
    int*   knn2  = (int*)alloc(163840);     // B*256*20
    int*   knn3  = (int*)alloc(40960);      // B*64*20
    int*   knn4_1 = (int*)alloc(32768);     // B*256*4
    int*   knn4_2 = (int*)alloc(8192);      // B*64*4
    float* ndir1 = alloc(1966080);          // B*1024*20*3
    float* ndir2 = alloc(491520);           // B*256*20*3
    float* ndir3 = alloc(122880);           // B*64*20*3
    float* fm0   = alloc(1048576);          // B*1024*32
    float* fm1   = alloc(2097152);          // B*1024*64
    float* fm1p  = alloc(524288);           // B*256*64
    float* fm2   = alloc(1048576);          // B*256*128
    float* fm3   = alloc(2097152);          // B*256*256
    float* fm3p  = alloc(524288);           // B*64*256
    float* fout  = alloc(4194304);          // max fout sizes
    float* convp = alloc(2097152);          // pre-BN conv out
    float* gbuf  = alloc(32768);            // B*1024
    float* hbuf  = alloc(8192);             // B*256
    float* d1t   = alloc(2048);             // 32 x 64
    float* d2t   = alloc(8192);             // 64 x 128
    float* d3t   = alloc(32768);            // 128 x 256
    float* d4t   = alloc(262144);           // 256 x 1024
    float* pz    = alloc(57344);            // fused BN bins: p1(8K) + p2a(16K) + p2b(32K)
    float* p1    = pz;                      // 64 bins x 2 x 64
    float* p2a   = pz + 8192;               // 64 bins x 2 x 128
    float* p2b   = pz + 24576;              // 64 bins x 2 x 256
    float* partial3 = alloc(131072);        // stage-3 two-pass partials (64 x 2 x 1024)

    // ---- prep: all knn stages + transposes + BN-bin zeroing, one launch ----
    prep_kernel<<<dim3(876, B), KNN_TPB, 0, stream>>>(
        vertices, c0_dir, knn1, ndir1, fm0, knn4_1, knn2, ndir2, knn4_2, knn3, ndir3,
        d1_w, d2_w, d3_w, d4_w, d1t, d2t, d3t, d4t, pz);

    // ---- stage 1 (V=1024) ----
    gemm64_kernel<0><<<dim3(2, 512), TPB, 0, stream>>>(fm0, c1_w, c1_b, nullptr, nullptr, fout, B * 1024, 128, 32, 0);
    conv_act_kernel<true><<<nblk((long)B * 1024 * 16), TPB, 0, stream>>>(ndir1, knn1, fout, c1_dir, convp, B, 1024, 20, 64, p1);
    gemm64_kernel<1><<<dim3(1, 512), TPB, 0, stream>>>(fm0, d1t, nullptr, convp, p1, fm1, B * 1024, 64, 32, 64);
    pool_max_kernel<<<nblk((long)B * 256 * 64), TPB, 0, stream>>>(fm1, knn4_1, fm1p, B, 1024, 256, 64);

    // ---- stage 2 (V=256) ----
    gemm64_kernel<0><<<dim3(4, 128), TPB, 0, stream>>>(fm1p, c2_w, c2_b, nullptr, nullptr, fout, B * 256, 256, 64, 0);
    conv_act_kernel<true><<<nblk((long)B * 256 * 32), TPB, 0, stream>>>(ndir2, knn2, fout, c2_dir, convp, B, 256, 20, 128, p2a);
    gemm64_kernel<1><<<dim3(2, 128), TPB, 0, stream>>>(fm1p, d2t, nullptr, convp, p2a, fm2, B * 256, 128, 64, 64);
    gemm64_kernel<0><<<dim3(8, 128), TPB, 0, stream>>>(fm2, c3_w, c3_b, nullptr, nullptr, fout, B * 256, 512, 128, 0);
    conv_act_kernel<true><<<nblk((long)B * 256 * 64), TPB, 0, stream>>>(ndir2, knn2, fout, c3_dir, convp, B, 256, 20, 256, p2b);
    gemm64_kernel<1><<<dim3(4, 128), TPB, 0, stream>>>(fm2, d3t, nullptr, convp, p2b, fm3, B * 256, 256, 128, 64);
    pool_max_kernel<<<nblk((long)B * 64 * 256), TPB, 0, stream>>>(fm3, knn4_2, fm3p, B, 256, 64, 256);

    // ---- stage 3 (V=64) ----
    gemm64_kernel<0><<<dim3(32, 32), TPB, 0, stream>>>(fm3p, c4_w, c4_b, nullptr, nullptr, fout, B * 64, 2048, 256, 0);
    conv_act_kernel<false><<<nblk((long)B * 64 * 256), TPB, 0, stream>>>(ndir3, knn3, fout, c4_dir, convp, B, 64, 20, 1024, nullptr);
    bn_partial_kernel<<<nblk(1024 * 64), TPB, 0, stream>>>(convp, partial3, B * 64, 1024, 64);
    gemm64_kernel<2><<<dim3(16, 32), TPB, 0, stream>>>(fm3p, d4t, nullptr, convp, partial3, gbuf, B * 64, 1024, 256, 64);

    // ---- classifier ----
    gemm_t_wave_kernel<<<nblk((long)32 * 256 * 64), TPB, 0, stream>>>(gbuf, cls_w1, cls_b1, hbuf, 32, 1024, 256);
    cls_fused_kernel<<<320, TPB, 0, stream>>>(hbuf, cls_g, cls_beta, cls_w2, cls_b2, (float*)d_out);
}